// Round 7
// baseline (795.860 us; speedup 1.0000x reference)
//
#include <hip/hip_runtime.h>
#include <hip/hip_bf16.h>

typedef short short8 __attribute__((ext_vector_type(8)));
typedef short short4v __attribute__((ext_vector_type(4)));
typedef float f32x4 __attribute__((ext_vector_type(4)));

static __device__ __forceinline__ short f2bf(float f){
  __hip_bfloat16 h = __float2bfloat16(f);
  return __builtin_bit_cast(short, h);
}
static __device__ __forceinline__ float b2f(short s){
  unsigned int u = ((unsigned int)(unsigned short)s) << 16;
  return __builtin_bit_cast(float, u);
}
static __device__ __forceinline__ float lrelu(float x){ return x > 0.f ? x : 0.2f*x; }
static __device__ __forceinline__ float eluf(float x){ return x > 0.f ? x : (__expf(x)-1.f); }
static __device__ __forceinline__ int imin(int a,int b){ return a<b?a:b; }

typedef const __attribute__((address_space(1))) void as1_void;
typedef __attribute__((address_space(3))) void as3_void;
static __device__ __forceinline__ void gload16(const void* g, void* l){
  __builtin_amdgcn_global_load_lds((as1_void*)g, (as3_void*)l, 16, 0, 0);
}
template<int NN> __device__ __forceinline__ void wait_vm(){
  if constexpr (NN==0) asm volatile("s_waitcnt vmcnt(0)" ::: "memory");
  else if constexpr (NN==1) asm volatile("s_waitcnt vmcnt(1)" ::: "memory");
  else if constexpr (NN==2) asm volatile("s_waitcnt vmcnt(2)" ::: "memory");
  else if constexpr (NN==3) asm volatile("s_waitcnt vmcnt(3)" ::: "memory");
  else if constexpr (NN==4) asm volatile("s_waitcnt vmcnt(4)" ::: "memory");
  else if constexpr (NN==6) asm volatile("s_waitcnt vmcnt(6)" ::: "memory");
  else if constexpr (NN==8) asm volatile("s_waitcnt vmcnt(8)" ::: "memory");
  else asm volatile("s_waitcnt vmcnt(0)" ::: "memory");
}

// ==================== x f32 -> bf16 convert (streaming) ====================
__global__ __launch_bounds__(256) void cvt_x(const float* __restrict__ x, short* __restrict__ xb, int M){
  int row = blockIdx.x*2 + (threadIdx.x>>7);
  int c8  = (threadIdx.x&127)*8;
  if (row >= M || c8 >= 1000) return;
  const float* p = x + (size_t)row*1000 + c8;
  float4 f0 = *(const float4*)p, f1 = *(const float4*)(p+4);
  short8 o;
  o[0]=f2bf(f0.x);o[1]=f2bf(f0.y);o[2]=f2bf(f0.z);o[3]=f2bf(f0.w);
  o[4]=f2bf(f1.x);o[5]=f2bf(f1.y);o[6]=f2bf(f1.z);o[7]=f2bf(f1.w);
  *(short8*)&xb[(size_t)row*1000 + c8] = o;
}

// ==================== GEMM: gload_lds ring-4, BK=32, counted vmcnt, 256 thr ====================
// A bf16 [M][lda]; Bt bf16 [NR][ldb] zero-padded. B zero for k in [K, ceil32(K)).
template<int BM, int BN, bool OBF16, bool CST, bool SMAX, bool G23S>
__global__ __launch_bounds__(256) void gemm_g(
    const short* __restrict__ A, int lda, const short* __restrict__ Bt, int ldb,
    void* __restrict__ Cv, int ldc, const float* __restrict__ bias,
    int M, int N, int K,
    float* __restrict__ o_sum, float* __restrict__ o_sq,
    float* __restrict__ s2s, float* __restrict__ s2d,
    float* __restrict__ s3s, float* __restrict__ s3d,
    const float* __restrict__ a2s, const float* __restrict__ a2d,
    const float* __restrict__ a3s, const float* __restrict__ a3d)
{
  constexpr int BK = 32, GPR = 4;
  constexpr int WM = BM/2, WN = BN/2;
  constexpr int FM = WM/16, FN = WN/16;
  constexpr int AI = (BM*GPR)/(4*64);
  constexpr int BI_T = (BN*GPR)/64;
  constexpr bool BDUP = (BI_T < 4);
  constexpr int BI = BDUP ? BI_T : BI_T/4;
  constexpr int LPT = AI + BI;
  constexpr int TS = (BM+BN)*BK;
  __shared__ short lds[4][TS];

  const int tid = threadIdx.x, wid = tid>>6, lane = tid&63;
  const int wm = wid>>1, wn = wid&1;
  const int bm = blockIdx.x*BM, bn = blockIdx.y*BN;
  const int lr = lane&15, lg = lane>>4;
  const int nt = (K + BK - 1)/BK;

  f32x4 acc[FM][FN] = {};

  auto STAGE = [&](int t){
    int buf = t & 3, k0 = t*BK;
    #pragma unroll
    for (int i=0;i<AI;i++){
      int ci = wid*AI + i;
      int c = ci*64 + lane;
      int row = c>>2, g = c&3;
      int gr = imin(bm+row, M-1);
      const short* src = A + (size_t)gr*lda + k0 + ((g ^ (row&3))<<3);
      gload16(src, &lds[buf][ci*512]);
    }
    #pragma unroll
    for (int i=0;i<BI;i++){
      int bi = BDUP ? i : wid*BI + i;
      int c = bi*64 + lane;
      int row = c>>2, g = c&3;
      const short* src = Bt + (size_t)(bn+row)*ldb + k0 + ((g ^ (row&3))<<3);
      gload16(src, &lds[buf][BM*BK + bi*512]);
    }
  };

  for (int s=0; s<3 && s<nt; ++s) STAGE(s);

  for (int t=0; t<nt; ++t){
    int newer = imin(nt, t+3) - t - 1;
    if (newer >= 2) wait_vm<2*LPT>();
    else if (newer == 1) wait_vm<LPT>();
    else wait_vm<0>();
    __builtin_amdgcn_s_barrier();
    __builtin_amdgcn_sched_barrier(0);
    if (t+3 < nt) STAGE(t+3);
    int buf = t & 3;
    short8 af[FM], bf[FN];
    #pragma unroll
    for (int m=0;m<FM;m++){
      int r = wm*WM + m*16 + lr;
      af[m] = *(short8*)&lds[buf][r*BK + ((lg ^ (r&3))<<3)];
    }
    #pragma unroll
    for (int n=0;n<FN;n++){
      int r = wn*WN + n*16 + lr;
      bf[n] = *(short8*)&lds[buf][BM*BK + r*BK + ((lg ^ (r&3))<<3)];
    }
    #pragma unroll
    for (int m=0;m<FM;m++)
      #pragma unroll
      for (int n=0;n<FN;n++)
        acc[m][n] = __builtin_amdgcn_mfma_f32_16x16x32_bf16(af[m], bf[n], acc[m][n], 0, 0, 0);
  }

  if (SMAX){
    // clu2: N=10 cols live in wn==0, n==0, lr<10. Row-softmax in-register.
    #pragma unroll
    for (int m=0;m<FM;m++)
      #pragma unroll
      for (int q=0;q<4;q++){
        int row = bm + wm*WM + m*16 + lg*4 + q;
        float v = (lr < 10) ? (acc[m][0][q] + bias[lr]) : -3e38f;
        float mx = v;
        #pragma unroll
        for (int d=1; d<16; d<<=1) mx = fmaxf(mx, __shfl_xor(mx, d));
        float e = (lr < 10) ? __expf(v - mx) : 0.f;
        float sm = e;
        #pragma unroll
        for (int d=1; d<16; d<<=1) sm += __shfl_xor(sm, d);
        if (wn == 0 && lr < 10 && row < M)
          ((float*)Cv)[(size_t)row*10 + lr] = e/sm;
      }
    return;
  }

  #pragma unroll
  for (int m=0;m<FM;m++)
    #pragma unroll
    for (int n=0;n<FN;n++)
      #pragma unroll
      for (int q=0;q<4;q++){
        int row = bm + wm*WM + m*16 + lg*4 + q;
        int col = bn + wn*WN + n*16 + lr;
        if (row < M && col < N){
          float v = acc[m][n][q];
          if (bias) v += bias[col];
          if (OBF16) ((short*)Cv)[(size_t)row*ldc + col] = f2bf(v);
          else       ((float*)Cv)[(size_t)row*ldc + col] = v;
        }
      }

  if (G23S){
    // gat23: fold score reduction. wn==0 -> s2 (cols 0-31), wn==1 -> s3 (cols 32-63).
    float a_s[FN], a_d[FN];
    #pragma unroll
    for (int n=0;n<FN;n++){
      int cl = n*16 + lr;               // local col within half
      bool valid = cl < 30;
      a_s[n] = valid ? (wn ? a3s[cl] : a2s[cl]) : 0.f;
      a_d[n] = valid ? (wn ? a3d[cl] : a2d[cl]) : 0.f;
    }
    #pragma unroll
    for (int m=0;m<FM;m++)
      #pragma unroll
      for (int q=0;q<4;q++){
        int row = bm + wm*WM + m*16 + lg*4 + q;
        float ps = 0.f, pd = 0.f;
        #pragma unroll
        for (int n=0;n<FN;n++){ ps += acc[m][n][q]*a_s[n]; pd += acc[m][n][q]*a_d[n]; }
        #pragma unroll
        for (int d=1; d<16; d<<=1){ ps += __shfl_xor(ps, d); pd += __shfl_xor(pd, d); }
        if (lr == 0 && row < M){
          if (wn){ s3s[row] = ps; s3d[row] = pd; }
          else   { s2s[row] = ps; s2d[row] = pd; }
        }
      }
  }

  if (CST){
    #pragma unroll
    for (int n=0;n<FN;n++){
      float s = 0.f, q2 = 0.f;
      #pragma unroll
      for (int m=0;m<FM;m++)
        #pragma unroll
        for (int q=0;q<4;q++){
          int row = bm + wm*WM + m*16 + lg*4 + q;
          if (row < M){ float v = acc[m][n][q]; s += v; q2 += v*v; }
        }
      s  += __shfl_xor(s, 16);  s += __shfl_xor(s, 32);
      q2 += __shfl_xor(q2, 16); q2 += __shfl_xor(q2, 32);
      if (lg == 0){
        int col = bn + wn*WN + n*16 + lr;
        if (col < N){ atomicAdd(&o_sum[col], s); atomicAdd(&o_sq[col], q2); }
      }
    }
  }
}

// ==================== weight transpose/convert ====================
struct WEnt { const float* src; short* dst; int K, N, KP, NR; };
struct WTab { WEnt e[12]; };
__global__ __launch_bounds__(256) void wtrans_all(WTab tab){
  WEnt w = tab.e[blockIdx.y];
  int gid = blockIdx.x*256 + threadIdx.x;
  if (gid >= w.NR * w.KP) return;
  int n = gid / w.KP, k = gid - n*w.KP;
  float v = (k < w.K && n < w.N) ? w.src[(size_t)k*w.N + n] : 0.f;
  w.dst[gid] = f2bf(v);
}

// ==================== BN (finalize folded) + ELU -> bf16 ====================
template<int C>
__global__ __launch_bounds__(256) void bn_elu_apply2(const float* __restrict__ H, short* __restrict__ O,
    int M, float invM,
    const float* __restrict__ ssum, const float* __restrict__ ssq,
    const float* __restrict__ g, const float* __restrict__ bt){
  __shared__ float sc[C], sh[C];
  for (int c = threadIdx.x; c < C; c += 256){
    float mn  = ssum[c]*invM;
    float var = ssq[c]*invM - mn*mn;
    float s = g[c]*rsqrtf(var + 1e-5f);
    sc[c] = s; sh[c] = bt[c] - mn*s;
  }
  __syncthreads();
  int total4 = M*(C/4);
  for (int i = blockIdx.x*256+threadIdx.x; i < total4; i += gridDim.x*256){
    float4 v = ((const float4*)H)[i];
    int cb = (i*4) & (C-1);
    short4v o;
    o[0] = f2bf(eluf(v.x*sc[cb+0]+sh[cb+0]));
    o[1] = f2bf(eluf(v.y*sc[cb+1]+sh[cb+1]));
    o[2] = f2bf(eluf(v.z*sc[cb+2]+sh[cb+2]));
    o[3] = f2bf(eluf(v.w*sc[cb+3]+sh[cb+3]));
    ((short4v*)O)[i] = o;
  }
}

__global__ __launch_bounds__(256) void bn_elu_split(const float* __restrict__ H,
    short* __restrict__ Od, short* __restrict__ Oc, int M, float invM,
    const float* __restrict__ ssum, const float* __restrict__ ssq,
    const float* __restrict__ gd, const float* __restrict__ btd,
    const float* __restrict__ gc, const float* __restrict__ btc){
  __shared__ float sc[256], sh[256];
  {
    int c = threadIdx.x;
    float mn  = ssum[c]*invM;
    float var = ssq[c]*invM - mn*mn;
    float gg = (c<128) ? gd[c] : gc[c-128];
    float bb = (c<128) ? btd[c] : btc[c-128];
    float s = gg*rsqrtf(var + 1e-5f);
    sc[c] = s; sh[c] = bb - mn*s;
  }
  __syncthreads();
  int total4 = M*64;
  for (int i = blockIdx.x*256+threadIdx.x; i < total4; i += gridDim.x*256){
    float4 v = ((const float4*)H)[i];
    int cb = (i*4) & 255;
    short4v o;
    o[0] = f2bf(eluf(v.x*sc[cb+0]+sh[cb+0]));
    o[1] = f2bf(eluf(v.y*sc[cb+1]+sh[cb+1]));
    o[2] = f2bf(eluf(v.z*sc[cb+2]+sh[cb+2]));
    o[3] = f2bf(eluf(v.w*sc[cb+3]+sh[cb+3]));
    int row = i>>6;
    short* O = (cb < 128) ? Od : Oc;
    *(short4v*)&O[(size_t)row*128 + (cb&127)] = o;
  }
}

// ==================== CSR build ====================
__global__ void hist_kernel(const int* __restrict__ d, int E, int* __restrict__ deg){
  int i = blockIdx.x*256 + threadIdx.x;
  if (i < E) atomicAdd(&deg[d[i]], 1);
}
__global__ __launch_bounds__(256) void scan1(const int* __restrict__ deg, int* __restrict__ offs,
                                             int* __restrict__ bsum, int n){
  __shared__ int sm[256];
  int tid = threadIdx.x;
  int base = blockIdx.x*1024 + tid*4;
  int v0 = base+0<n ? deg[base+0] : 0;
  int v1 = base+1<n ? deg[base+1] : 0;
  int v2 = base+2<n ? deg[base+2] : 0;
  int v3 = base+3<n ? deg[base+3] : 0;
  int ts = v0+v1+v2+v3;
  sm[tid] = ts;
  __syncthreads();
  #pragma unroll
  for (int d=1; d<256; d<<=1){
    int t = (tid>=d) ? sm[tid-d] : 0;
    __syncthreads();
    sm[tid] += t;
    __syncthreads();
  }
  int ex = sm[tid] - ts;
  if (base+0<n) offs[base+0] = ex;
  if (base+1<n) offs[base+1] = ex+v0;
  if (base+2<n) offs[base+2] = ex+v0+v1;
  if (base+3<n) offs[base+3] = ex+v0+v1+v2;
  if (tid==255) bsum[blockIdx.x] = sm[255];
}
__global__ __launch_bounds__(256) void scan3(int* __restrict__ offs, const int* __restrict__ bsum,
                      int* __restrict__ cursor, int n, int total){
  __shared__ int base_sm;
  int tgt = blockIdx.x >> 2;
  if (threadIdx.x < 64){
    int j = threadIdx.x;
    int v = (j < tgt) ? bsum[j] : 0;
    #pragma unroll
    for (int d=32; d; d>>=1) v += __shfl_xor(v, d);
    if (j == 0) base_sm = v;
  }
  __syncthreads();
  int i = blockIdx.x*256 + threadIdx.x;
  if (i < n){ int v = offs[i] + base_sm; offs[i]=v; cursor[i]=v; }
  if (i == 0) offs[n] = total;
}
__global__ void scatter_kernel(const int* __restrict__ s, const int* __restrict__ d, int E,
                               int* __restrict__ cursor, int* __restrict__ csr){
  int i = blockIdx.x*256 + threadIdx.x;
  if (i < E){ int pos = atomicAdd(&cursor[d[i]], 1); csr[pos] = s[i]; }
}

// ==================== GAT1 ====================
__global__ __launch_bounds__(256) void gat1_scores_bf(const short* __restrict__ hh,
    const float* __restrict__ as, const float* __restrict__ ad,
    float* __restrict__ ss, float* __restrict__ sd, int n){
  int w = threadIdx.x >> 6, lane = threadIdx.x & 63;
  int row = blockIdx.x*4 + w;
  if (row >= n) return;
  const short* hr = hh + (size_t)row*192;
  float ps[3], pd[3];
  #pragma unroll
  for (int h=0; h<3; h++){
    float v = b2f(hr[h*64 + lane]);
    ps[h] = v * as[h*64+lane];
    pd[h] = v * ad[h*64+lane];
  }
  #pragma unroll
  for (int m=32; m; m>>=1){
    #pragma unroll
    for (int h=0;h<3;h++){ ps[h] += __shfl_xor(ps[h], m); pd[h] += __shfl_xor(pd[h], m); }
  }
  if (lane == 0){
    #pragma unroll
    for (int h=0;h<3;h++){ ss[row*3+h]=ps[h]; sd[row*3+h]=pd[h]; }
  }
}

__global__ __launch_bounds__(256) void gat1_gather_bf(const int* __restrict__ offs, const int* __restrict__ csr,
    const short* __restrict__ hh, const float* __restrict__ ss, const float* __restrict__ sd,
    const float* __restrict__ bias, short* __restrict__ out, int n){
  int w = threadIdx.x >> 6, lane = threadIdx.x & 63;
  int dst = blockIdx.x*4 + w;
  if (dst >= n) return;
  float sd0 = sd[dst*3+0], sd1 = sd[dst*3+1], sd2 = sd[dst*3+2];
  float p0 = __expf(lrelu(ss[dst*3+0]+sd0));
  float p1 = __expf(lrelu(ss[dst*3+1]+sd1));
  float p2 = __expf(lrelu(ss[dst*3+2]+sd2));
  const short* hr = hh + (size_t)dst*192;
  float a0 = p0*b2f(hr[lane]), a1 = p1*b2f(hr[64+lane]), a2 = p2*b2f(hr[128+lane]);
  float d0 = p0, d1 = p1, d2 = p2;
  int p = offs[dst], pe = offs[dst+1];
  int n0=0,n1=0,n2=0,n3=0;
  if (p+4 <= pe){ n0=csr[p]; n1=csr[p+1]; n2=csr[p+2]; n3=csr[p+3]; }
  while (p+4 <= pe){
    int s0=n0, s1=n1, s2=n2, s3=n3;
    int pn = p+4;
    if (pn+4 <= pe){ n0=csr[pn]; n1=csr[pn+1]; n2=csr[pn+2]; n3=csr[pn+3]; }
    float e00=ss[s0*3+0], e01=ss[s0*3+1], e02=ss[s0*3+2];
    float e10=ss[s1*3+0], e11=ss[s1*3+1], e12=ss[s1*3+2];
    float e20=ss[s2*3+0], e21=ss[s2*3+1], e22=ss[s2*3+2];
    float e30=ss[s3*3+0], e31=ss[s3*3+1], e32=ss[s3*3+2];
    const short* r0 = hh + (size_t)s0*192;
    const short* r1 = hh + (size_t)s1*192;
    const short* r2 = hh + (size_t)s2*192;
    const short* r3 = hh + (size_t)s3*192;
    float v00=b2f(r0[lane]), v01=b2f(r0[64+lane]), v02=b2f(r0[128+lane]);
    float v10=b2f(r1[lane]), v11=b2f(r1[64+lane]), v12=b2f(r1[128+lane]);
    float v20=b2f(r2[lane]), v21=b2f(r2[64+lane]), v22=b2f(r2[128+lane]);
    float v30=b2f(r3[lane]), v31=b2f(r3[64+lane]), v32=b2f(r3[128+lane]);
    float q00=__expf(lrelu(e00+sd0)), q01=__expf(lrelu(e01+sd1)), q02=__expf(lrelu(e02+sd2));
    float q10=__expf(lrelu(e10+sd0)), q11=__expf(lrelu(e11+sd1)), q12=__expf(lrelu(e12+sd2));
    float q20=__expf(lrelu(e20+sd0)), q21=__expf(lrelu(e21+sd1)), q22=__expf(lrelu(e22+sd2));
    float q30=__expf(lrelu(e30+sd0)), q31=__expf(lrelu(e31+sd1)), q32=__expf(lrelu(e32+sd2));
    a0 += q00*v00 + q10*v10 + q20*v20 + q30*v30;
    a1 += q01*v01 + q11*v11 + q21*v21 + q31*v31;
    a2 += q02*v02 + q12*v12 + q22*v22 + q32*v32;
    d0 += q00+q10+q20+q30;
    d1 += q01+q11+q21+q31;
    d2 += q02+q12+q22+q32;
    p = pn;
  }
  for (; p < pe; ++p){
    int src = csr[p];
    float q0 = __expf(lrelu(ss[src*3+0]+sd0));
    float q1 = __expf(lrelu(ss[src*3+1]+sd1));
    float q2 = __expf(lrelu(ss[src*3+2]+sd2));
    const short* sr = hh + (size_t)src*192;
    a0 += q0*b2f(sr[lane]); a1 += q1*b2f(sr[64+lane]); a2 += q2*b2f(sr[128+lane]);
    d0 += q0; d1 += q1; d2 += q2;
  }
  float v0 = a0/d0 + bias[lane];
  float v1 = a1/d1 + bias[64+lane];
  float v2 = a2/d2 + bias[128+lane];
  short* orow = out + (size_t)dst*192;
  orow[lane]      = f2bf(v0 > 0.f ? v0 : 0.f);
  orow[64+lane]   = f2bf(v1 > 0.f ? v1 : 0.f);
  orow[128+lane]  = f2bf(v2 > 0.f ? v2 : 0.f);
}

// ==================== GAT2/3 gather (hh23 [N][64]: cols 0-29 = h2, 32-61 = h3) ====================
__global__ __launch_bounds__(256) void gat23_gather(const int* __restrict__ offs, const int* __restrict__ csr,
    const float* __restrict__ hh23,
    const float* __restrict__ s2s, const float* __restrict__ s2d,
    const float* __restrict__ s3s, const float* __restrict__ s3d,
    const float* __restrict__ b2, const float* __restrict__ b3,
    float* __restrict__ zs, float* __restrict__ mus, float* __restrict__ lvs,
    short* __restrict__ zbf, int n){
  int w = threadIdx.x >> 6, lane = threadIdx.x & 63;
  int dst = blockIdx.x*4 + w;
  if (dst >= n) return;
  bool lo = lane < 32;
  int c = lane & 31;
  bool valid = c < 30;
  float sdA = s2d[dst], sdB = s3d[dst];
  float sdx = lo ? sdA : sdB;
  const float* ssx = lo ? s2s : s3s;
  float p2 = __expf(lrelu(s2s[dst]+sdA));
  float p3 = __expf(lrelu(s3s[dst]+sdB));
  float val = valid ? hh23[(size_t)dst*64+lane] : 0.f;
  float acc = (lo ? p2 : p3) * val;
  float den2 = p2, den3 = p3;
  int p = offs[dst], pe = offs[dst+1];
  int n0=0,n1=0,n2=0,n3=0;
  if (p+4 <= pe){ n0=csr[p]; n1=csr[p+1]; n2=csr[p+2]; n3=csr[p+3]; }
  while (p+4 <= pe){
    int s0=n0, s1=n1, s2i=n2, s3i=n3;
    int pn = p+4;
    if (pn+4 <= pe){ n0=csr[pn]; n1=csr[pn+1]; n2=csr[pn+2]; n3=csr[pn+3]; }
    float eA0=ssx[s0], eA1=ssx[s1], eA2=ssx[s2i], eA3=ssx[s3i];
    float f20=s2s[s0], f21=s2s[s1], f22=s2s[s2i], f23=s2s[s3i];
    float f30=s3s[s0], f31=s3s[s1], f32=s3s[s2i], f33=s3s[s3i];
    float v0 = valid ? hh23[(size_t)s0*64+lane] : 0.f;
    float v1 = valid ? hh23[(size_t)s1*64+lane] : 0.f;
    float v2 = valid ? hh23[(size_t)s2i*64+lane] : 0.f;
    float v3 = valid ? hh23[(size_t)s3i*64+lane] : 0.f;
    float qx0=__expf(lrelu(eA0+sdx)), qx1=__expf(lrelu(eA1+sdx));
    float qx2=__expf(lrelu(eA2+sdx)), qx3=__expf(lrelu(eA3+sdx));
    acc += qx0*v0 + qx1*v1 + qx2*v2 + qx3*v3;
    den2 += __expf(lrelu(f20+sdA)) + __expf(lrelu(f21+sdA)) + __expf(lrelu(f22+sdA)) + __expf(lrelu(f23+sdA));
    den3 += __expf(lrelu(f30+sdB)) + __expf(lrelu(f31+sdB)) + __expf(lrelu(f32+sdB)) + __expf(lrelu(f33+sdB));
    p = pn;
  }
  for (; p < pe; ++p){
    int src = csr[p];
    float q2 = __expf(lrelu(s2s[src]+sdA));
    float q3 = __expf(lrelu(s3s[src]+sdB));
    float v = valid ? hh23[(size_t)src*64+lane] : 0.f;
    acc += (lo ? q2 : q3) * v;
    den2 += q2; den3 += q3;
  }
  if (lo){
    if (valid){
      float v = acc/den2 + b2[c];
      zs[(size_t)dst*30+c]  = v;
      mus[(size_t)dst*30+c] = v;
      zbf[(size_t)dst*32+c] = f2bf(v);
    } else {
      zbf[(size_t)dst*32+c] = 0;
    }
  } else if (valid){
    lvs[(size_t)dst*30+c] = acc/den3 + b3[c];
  }
}

// ==================== host ====================
static inline int cdiv(int a, int b){ return (a + b - 1) / b; }

extern "C" void kernel_launch(void* const* d_in, const int* in_sizes, int n_in,
                              void* d_out, int out_size, void* d_ws, size_t ws_size,
                              hipStream_t stream)
{
  const float* x        = (const float*)d_in[0];
  const int*   ei       = (const int*)  d_in[1];
  const float* enc_w1   = (const float*)d_in[2];
  const float* enc_g1   = (const float*)d_in[4];
  const float* enc_bt1  = (const float*)d_in[5];
  const float* enc_w2   = (const float*)d_in[6];
  const float* enc_g2   = (const float*)d_in[8];
  const float* enc_bt2  = (const float*)d_in[9];
  const float* gat1_w   = (const float*)d_in[10];
  const float* gat1_as  = (const float*)d_in[11];
  const float* gat1_ad  = (const float*)d_in[12];
  const float* gat1_b   = (const float*)d_in[13];
  const float* gat2_w   = (const float*)d_in[14];
  const float* gat2_as  = (const float*)d_in[15];
  const float* gat2_ad  = (const float*)d_in[16];
  const float* gat2_b   = (const float*)d_in[17];
  const float* gat3_w   = (const float*)d_in[18];
  const float* gat3_as  = (const float*)d_in[19];
  const float* gat3_ad  = (const float*)d_in[20];
  const float* gat3_b   = (const float*)d_in[21];
  const float* dec_w1   = (const float*)d_in[22];
  const float* dec_g1   = (const float*)d_in[24];
  const float* dec_bt1  = (const float*)d_in[25];
  const float* dec_w2   = (const float*)d_in[26];
  const float* dec_g2   = (const float*)d_in[28];
  const float* dec_bt2  = (const float*)d_in[29];
  const float* dec_w3   = (const float*)d_in[30];
  const float* dec_b3   = (const float*)d_in[31];
  const float* clu_w1   = (const float*)d_in[32];
  const float* clu_g1   = (const float*)d_in[34];
  const float* clu_bt1  = (const float*)d_in[35];
  const float* clu_w2   = (const float*)d_in[36];
  const float* clu_b2   = (const float*)d_in[37];

  const int N = in_sizes[0] / 1000;
  const int E = in_sizes[1] / 2;
  const int* e_src = ei;
  const int* e_dst = ei + E;
  const float invN = 1.f/(float)N;

  float* out  = (float*)d_out;
  float* pred = out;
  float* xrec = out + (size_t)N*10;
  float* zs   = xrec + (size_t)N*1000;
  float* mus  = zs  + (size_t)N*30;
  float* lvs  = mus + (size_t)N*30;

  char* ws = (char*)d_ws;
  size_t off = 0;
  auto alloc = [&](size_t bytes)->char*{
    char* p = ws + off;
    off = (off + bytes + 255) & ~(size_t)255;
    return p;
  };
  short* t_enc1  = (short*)alloc(256*1024*2);
  short* t_enc2  = (short*)alloc(128*256*2);
  short* t_gat1  = (short*)alloc(256*128*2);
  short* t_gat23 = (short*)alloc(64*192*2);
  short* t_dc1   = (short*)alloc(256*32*2);
  short* t_dec2  = (short*)alloc(256*128*2);
  short* t_dec3  = (short*)alloc(1024*256*2);
  short* t_clu2  = (short*)alloc(32*128*2);
  float* h1f  = (float*)alloc((size_t)N*256*4);
  short* h1b  = (short*)alloc((size_t)N*256*2);   // xb alias start
  float* h2f  = (float*)alloc((size_t)N*128*4);
  short* h2b  = (short*)alloc((size_t)N*128*2);
  short* hh1b = (short*)alloc((size_t)N*192*2);
  short* h3b  = (short*)alloc((size_t)N*192*2);
  float* hh23f= (float*)alloc((size_t)N*64*4);
  short* zbf  = (short*)alloc((size_t)N*32*2);
  float* ss1  = (float*)alloc((size_t)N*3*4);
  float* sd1  = (float*)alloc((size_t)N*3*4);
  float* s2s  = (float*)alloc((size_t)N*4);
  float* s2d  = (float*)alloc((size_t)N*4);
  float* s3s  = (float*)alloc((size_t)N*4);
  float* s3d  = (float*)alloc((size_t)N*4);
  float* stats= (float*)alloc(2048*4);
  int*   deg  = (int*)alloc((size_t)(N+1)*4);
  int*   offs = (int*)alloc((size_t)(N+1)*4);
  int*   curp = (int*)alloc((size_t)(N+1)*4);
  int*   bsum = (int*)alloc(256*4);
  int*   csr  = (int*)alloc((size_t)E*4);
  // aliases (lifetimes):
  short* xb   = h1b;               // spans h1b..h3b (102.4MB >= 100MB); dead after enc1 gemm
  float* dc1f = h2f;               // [N][256] f32 spans h2f+h2b+hh1b (57.6MB); live from dc1 gemm
  short* d1b  = h3b;               // h3b dead after gat23 gemm
  short* c1b  = (short*)hh23f;     // hh23f dead after gat23 gather
  float* d2f  = h1f;               // h1f dead after enc1 apply
  short* d2b  = h1b;               // h1b dead after enc2 gemm
  float* st_enc1 = stats, *st_enc2 = stats+512, *st_dc1 = stats+768, *st_dec2 = stats+1280;

  // --- weight prep + zeroing ---
  WTab tab;
  tab.e[0]  = {enc_w1, t_enc1, 1000, 256, 1024, 256};
  tab.e[1]  = {enc_w2, t_enc2, 256, 128, 256, 128};
  tab.e[2]  = {gat1_w, t_gat1, 128, 192, 128, 256};
  tab.e[3]  = {gat2_w, t_gat23, 192, 30, 192, 32};
  tab.e[4]  = {gat3_w, t_gat23 + 32*192, 192, 30, 192, 32};
  tab.e[5]  = {dec_w1, t_dc1, 30, 128, 32, 128};
  tab.e[6]  = {clu_w1, t_dc1 + 128*32, 30, 128, 32, 128};
  tab.e[7]  = {dec_w2, t_dec2, 128, 256, 128, 256};
  tab.e[8]  = {dec_w3, t_dec3, 256, 1000, 256, 1024};
  tab.e[9]  = {clu_w2, t_clu2, 128, 10, 128, 32};
  tab.e[10] = {enc_w1, t_enc1, 0, 0, 0, 0};
  tab.e[11] = {enc_w1, t_enc1, 0, 0, 0, 0};
  wtrans_all<<<dim3(1024, 12), 256, 0, stream>>>(tab);
  hipMemsetAsync(stats, 0, 2048*4, stream);
  hipMemsetAsync(deg, 0, (size_t)(N+1)*4, stream);

  // --- CSR ---
  hist_kernel<<<cdiv(E,256), 256, 0, stream>>>(e_dst, E, deg);
  int nb = cdiv(N, 1024);
  scan1<<<nb, 256, 0, stream>>>(deg, offs, bsum, N);
  scan3<<<cdiv(N,256), 256, 0, stream>>>(offs, bsum, curp, N, E);
  scatter_kernel<<<cdiv(E,256), 256, 0, stream>>>(e_src, e_dst, E, curp, csr);

  const int MB = cdiv(N, 64);   // 782

  // --- encoder L1: cvt to bf16, then GEMM (BM=64 for occupancy) ---
  cvt_x<<<cdiv(N,2), 256, 0, stream>>>(x, xb, N);
  gemm_g<64,128,false,true,false,false><<<dim3(MB,2), 256, 0, stream>>>(
      xb, 1000, t_enc1, 1024, h1f, 256, nullptr, N, 256, 1000,
      st_enc1, st_enc1+256, nullptr,nullptr,nullptr,nullptr, nullptr,nullptr,nullptr,nullptr);
  bn_elu_apply2<256><<<2048, 256, 0, stream>>>(h1f, h1b, N, invN, st_enc1, st_enc1+256, enc_g1, enc_bt1);

  // --- encoder L2 ---
  gemm_g<64,128,false,true,false,false><<<dim3(MB,1), 256, 0, stream>>>(
      h1b, 256, t_enc2, 256, h2f, 128, nullptr, N, 128, 256,
      st_enc2, st_enc2+128, nullptr,nullptr,nullptr,nullptr, nullptr,nullptr,nullptr,nullptr);
  bn_elu_apply2<128><<<2048, 256, 0, stream>>>(h2f, h2b, N, invN, st_enc2, st_enc2+128, enc_g2, enc_bt2);

  // --- GAT1 ---
  gemm_g<64,64,true,false,false,false><<<dim3(MB,3), 256, 0, stream>>>(
      h2b, 128, t_gat1, 128, hh1b, 192, nullptr, N, 192, 128,
      nullptr,nullptr, nullptr,nullptr,nullptr,nullptr, nullptr,nullptr,nullptr,nullptr);
  gat1_scores_bf<<<cdiv(N,4), 256, 0, stream>>>(hh1b, gat1_as, gat1_ad, ss1, sd1, N);
  gat1_gather_bf<<<cdiv(N,4), 256, 0, stream>>>(offs, csr, hh1b, ss1, sd1, gat1_b, h3b, N);

  // --- GAT2+GAT3 (combined weights, scores folded into epilogue) ---
  gemm_g<64,64,false,false,false,true><<<dim3(MB,1), 256, 0, stream>>>(
      h3b, 192, t_gat23, 192, hh23f, 64, nullptr, N, 64, 192,
      nullptr,nullptr, s2s,s2d,s3s,s3d, gat2_as,gat2_ad,gat3_as,gat3_ad);
  gat23_gather<<<cdiv(N,4), 256, 0, stream>>>(offs, csr, hh23f, s2s, s2d, s3s, s3d, gat2_b, gat3_b, zs, mus, lvs, zbf, N);

  // --- dec1 + clu1 combined ---
  gemm_g<64,128,false,true,false,false><<<dim3(MB,2), 256, 0, stream>>>(
      zbf, 32, t_dc1, 32, dc1f, 256, nullptr, N, 256, 32,
      st_dc1, st_dc1+256, nullptr,nullptr,nullptr,nullptr, nullptr,nullptr,nullptr,nullptr);
  bn_elu_split<<<2048, 256, 0, stream>>>(dc1f, d1b, c1b, N, invN, st_dc1, st_dc1+256, dec_g1, dec_bt1, clu_g1, clu_bt1);

  // --- dec2 ---
  gemm_g<64,128,false,true,false,false><<<dim3(MB,2), 256, 0, stream>>>(
      d1b, 128, t_dec2, 128, d2f, 256, nullptr, N, 256, 128,
      st_dec2, st_dec2+256, nullptr,nullptr,nullptr,nullptr, nullptr,nullptr,nullptr,nullptr);
  bn_elu_apply2<256><<<2048, 256, 0, stream>>>(d2f, d2b, N, invN, st_dec2, st_dec2+256, dec_g2, dec_bt2);

  // --- dec3 ---
  gemm_g<64,128,false,false,false,false><<<dim3(MB,8), 256, 0, stream>>>(
      d2b, 256, t_dec3, 256, xrec, 1000, dec_b3, N, 1000, 256,
      nullptr,nullptr, nullptr,nullptr,nullptr,nullptr, nullptr,nullptr,nullptr,nullptr);

  // --- clu2 + fused softmax ---
  gemm_g<64,32,false,false,true,false><<<dim3(MB,1), 256, 0, stream>>>(
      c1b, 128, t_clu2, 128, pred, 10, clu_b2, N, 10, 128,
      nullptr,nullptr, nullptr,nullptr,nullptr,nullptr, nullptr,nullptr,nullptr,nullptr);
}

// Round 8
// 636.614 us; speedup vs baseline: 1.2501x; 1.2501x over previous
//
#include <hip/hip_runtime.h>
#include <hip/hip_bf16.h>

typedef short short8 __attribute__((ext_vector_type(8)));
typedef short short4v __attribute__((ext_vector_type(4)));
typedef float f32x4 __attribute__((ext_vector_type(4)));

static __device__ __forceinline__ short f2bf(float f){
  __hip_bfloat16 h = __float2bfloat16(f);
  return __builtin_bit_cast(short, h);
}
static __device__ __forceinline__ float b2f(short s){
  unsigned int u = ((unsigned int)(unsigned short)s) << 16;
  return __builtin_bit_cast(float, u);
}
static __device__ __forceinline__ float lrelu(float x){ return x > 0.f ? x : 0.2f*x; }
static __device__ __forceinline__ float eluf(float x){ return x > 0.f ? x : (__expf(x)-1.f); }
static __device__ __forceinline__ int imin(int a,int b){ return a<b?a:b; }

typedef const __attribute__((address_space(1))) void as1_void;
typedef __attribute__((address_space(3))) void as3_void;
static __device__ __forceinline__ void gload16(const void* g, void* l){
  __builtin_amdgcn_global_load_lds((as1_void*)g, (as3_void*)l, 16, 0, 0);
}
template<int NN> __device__ __forceinline__ void wait_vm(){
  if constexpr (NN==0) asm volatile("s_waitcnt vmcnt(0)" ::: "memory");
  else if constexpr (NN==3) asm volatile("s_waitcnt vmcnt(3)" ::: "memory");
  else if constexpr (NN==4) asm volatile("s_waitcnt vmcnt(4)" ::: "memory");
  else if constexpr (NN==6) asm volatile("s_waitcnt vmcnt(6)" ::: "memory");
  else if constexpr (NN==8) asm volatile("s_waitcnt vmcnt(8)" ::: "memory");
  else if constexpr (NN==12) asm volatile("s_waitcnt vmcnt(12)" ::: "memory");
  else asm volatile("s_waitcnt vmcnt(0)" ::: "memory");
}

// ==================== x f32 -> bf16 convert (streaming) ====================
__global__ __launch_bounds__(256) void cvt_x(const float* __restrict__ x, short* __restrict__ xb, int M){
  int row = blockIdx.x*2 + (threadIdx.x>>7);
  int c8  = (threadIdx.x&127)*8;
  if (row >= M || c8 >= 1000) return;
  const float* p = x + (size_t)row*1000 + c8;
  float4 f0 = *(const float4*)p, f1 = *(const float4*)(p+4);
  short8 o;
  o[0]=f2bf(f0.x);o[1]=f2bf(f0.y);o[2]=f2bf(f0.z);o[3]=f2bf(f0.w);
  o[4]=f2bf(f1.x);o[5]=f2bf(f1.y);o[6]=f2bf(f1.z);o[7]=f2bf(f1.w);
  *(short8*)&xb[(size_t)row*1000 + c8] = o;
}

// ==================== GEMM: gload_lds ring-4, BK=32, counted vmcnt, 256 thr ====================
// R4-validated inner loop (best total). 1-D grid, XCD-chunk bijective swizzle (m204);
// nbn = #column tiles: consecutive work-ids share the A row-panel -> same XCD L2.
// A bf16 [M][lda]; Bt bf16 [NR][ldb] zero-padded. B zero for k in [K, ceil32(K)).
template<int BN, bool OBF16, bool CST, bool SMAX, bool G23S>
__global__ __launch_bounds__(256) void gemm_g(
    const short* __restrict__ A, int lda, const short* __restrict__ Bt, int ldb,
    void* __restrict__ Cv, int ldc, const float* __restrict__ bias,
    int M, int N, int K, int nbn,
    float* __restrict__ o_sum, float* __restrict__ o_sq,
    float* __restrict__ s2s, float* __restrict__ s2d,
    float* __restrict__ s3s, float* __restrict__ s3d,
    const float* __restrict__ a2s, const float* __restrict__ a2d,
    const float* __restrict__ a3s, const float* __restrict__ a3d)
{
  constexpr int BM = 128, BK = 32, GPR = 4;
  constexpr int WM = BM/2, WN = BN/2;
  constexpr int FM = WM/16, FN = WN/16;
  constexpr int AI = (BM*GPR)/(4*64);
  constexpr int BI_T = (BN*GPR)/64;
  constexpr bool BDUP = (BI_T < 4);
  constexpr int BI = BDUP ? BI_T : BI_T/4;
  constexpr int LPT = AI + BI;
  constexpr int TS = (BM+BN)*BK;
  __shared__ short lds[4][TS];

  const int tid = threadIdx.x, wid = tid>>6, lane = tid&63;
  const int wm = wid>>1, wn = wid&1;
  // --- XCD-chunked bijective swizzle (m204) ---
  int nwg = gridDim.x;
  int q8 = nwg >> 3, r8 = nwg & 7;
  int xcd = blockIdx.x & 7, pos = blockIdx.x >> 3;
  int wg = (xcd < r8 ? xcd*(q8+1) : r8*(q8+1) + (xcd-r8)*q8) + pos;
  int bmt = wg / nbn, bnt = wg - bmt*nbn;
  const int bm = bmt*BM, bn = bnt*BN;
  const int lr = lane&15, lg = lane>>4;
  const int nt = (K + BK - 1)/BK;

  f32x4 acc[FM][FN] = {};

  auto STAGE = [&](int t){
    int buf = t & 3, k0 = t*BK;
    #pragma unroll
    for (int i=0;i<AI;i++){
      int ci = wid*AI + i;
      int c = ci*64 + lane;
      int row = c>>2, g = c&3;
      int gr = imin(bm+row, M-1);
      const short* src = A + (size_t)gr*lda + k0 + ((g ^ (row&3))<<3);
      gload16(src, &lds[buf][ci*512]);
    }
    #pragma unroll
    for (int i=0;i<BI;i++){
      int bi = BDUP ? i : wid*BI + i;
      int c = bi*64 + lane;
      int row = c>>2, g = c&3;
      const short* src = Bt + (size_t)(bn+row)*ldb + k0 + ((g ^ (row&3))<<3);
      gload16(src, &lds[buf][BM*BK + bi*512]);
    }
  };

  for (int s=0; s<3 && s<nt; ++s) STAGE(s);

  for (int t=0; t<nt; ++t){
    int newer = imin(nt, t+3) - t - 1;
    if (newer >= 2) wait_vm<2*LPT>();
    else if (newer == 1) wait_vm<LPT>();
    else wait_vm<0>();
    __builtin_amdgcn_s_barrier();
    __builtin_amdgcn_sched_barrier(0);
    if (t+3 < nt) STAGE(t+3);
    int buf = t & 3;
    short8 af[FM], bf[FN];
    #pragma unroll
    for (int m=0;m<FM;m++){
      int r = wm*WM + m*16 + lr;
      af[m] = *(short8*)&lds[buf][r*BK + ((lg ^ (r&3))<<3)];
    }
    #pragma unroll
    for (int n=0;n<FN;n++){
      int r = wn*WN + n*16 + lr;
      bf[n] = *(short8*)&lds[buf][BM*BK + r*BK + ((lg ^ (r&3))<<3)];
    }
    #pragma unroll
    for (int m=0;m<FM;m++)
      #pragma unroll
      for (int n=0;n<FN;n++)
        acc[m][n] = __builtin_amdgcn_mfma_f32_16x16x32_bf16(af[m], bf[n], acc[m][n], 0, 0, 0);
  }

  if (SMAX){
    // clu2: N=10 cols live in wn==0, n==0, lr<10. Row-softmax in-register.
    #pragma unroll
    for (int m=0;m<FM;m++)
      #pragma unroll
      for (int q=0;q<4;q++){
        int row = bm + wm*WM + m*16 + lg*4 + q;
        float v = (lr < 10) ? (acc[m][0][q] + bias[lr]) : -3e38f;
        float mx = v;
        #pragma unroll
        for (int d=1; d<16; d<<=1) mx = fmaxf(mx, __shfl_xor(mx, d));
        float e = (lr < 10) ? __expf(v - mx) : 0.f;
        float sm = e;
        #pragma unroll
        for (int d=1; d<16; d<<=1) sm += __shfl_xor(sm, d);
        if (wn == 0 && lr < 10 && row < M)
          ((float*)Cv)[(size_t)row*10 + lr] = e/sm;
      }
    return;
  }

  #pragma unroll
  for (int m=0;m<FM;m++)
    #pragma unroll
    for (int n=0;n<FN;n++)
      #pragma unroll
      for (int q=0;q<4;q++){
        int row = bm + wm*WM + m*16 + lg*4 + q;
        int col = bn + wn*WN + n*16 + lr;
        if (row < M && col < N){
          float v = acc[m][n][q];
          if (bias) v += bias[col];
          if (OBF16) ((short*)Cv)[(size_t)row*ldc + col] = f2bf(v);
          else       ((float*)Cv)[(size_t)row*ldc + col] = v;
        }
      }

  if (G23S){
    // gat23: fold score reduction. wn==0 -> s2 (cols 0-31), wn==1 -> s3 (cols 32-63).
    float a_s[FN], a_d[FN];
    #pragma unroll
    for (int n=0;n<FN;n++){
      int cl = n*16 + lr;
      bool valid = cl < 30;
      a_s[n] = valid ? (wn ? a3s[cl] : a2s[cl]) : 0.f;
      a_d[n] = valid ? (wn ? a3d[cl] : a2d[cl]) : 0.f;
    }
    #pragma unroll
    for (int m=0;m<FM;m++)
      #pragma unroll
      for (int q=0;q<4;q++){
        int row = bm + wm*WM + m*16 + lg*4 + q;
        float ps = 0.f, pd = 0.f;
        #pragma unroll
        for (int n=0;n<FN;n++){ ps += acc[m][n][q]*a_s[n]; pd += acc[m][n][q]*a_d[n]; }
        #pragma unroll
        for (int d=1; d<16; d<<=1){ ps += __shfl_xor(ps, d); pd += __shfl_xor(pd, d); }
        if (lr == 0 && row < M){
          if (wn){ s3s[row] = ps; s3d[row] = pd; }
          else   { s2s[row] = ps; s2d[row] = pd; }
        }
      }
  }

  if (CST){
    #pragma unroll
    for (int n=0;n<FN;n++){
      float s = 0.f, q2 = 0.f;
      #pragma unroll
      for (int m=0;m<FM;m++)
        #pragma unroll
        for (int q=0;q<4;q++){
          int row = bm + wm*WM + m*16 + lg*4 + q;
          if (row < M){ float v = acc[m][n][q]; s += v; q2 += v*v; }
        }
      s  += __shfl_xor(s, 16);  s += __shfl_xor(s, 32);
      q2 += __shfl_xor(q2, 16); q2 += __shfl_xor(q2, 32);
      if (lg == 0){
        int col = bn + wn*WN + n*16 + lr;
        if (col < N){ atomicAdd(&o_sum[col], s); atomicAdd(&o_sq[col], q2); }
      }
    }
  }
}

// ==================== weight transpose/convert ====================
struct WEnt { const float* src; short* dst; int K, N, KP, NR; };
struct WTab { WEnt e[10]; };
__global__ __launch_bounds__(256) void wtrans_all(WTab tab){
  WEnt w = tab.e[blockIdx.y];
  int gid = blockIdx.x*256 + threadIdx.x;
  if (gid >= w.NR * w.KP) return;
  int n = gid / w.KP, k = gid - n*w.KP;
  float v = (k < w.K && n < w.N) ? w.src[(size_t)k*w.N + n] : 0.f;
  w.dst[gid] = f2bf(v);
}

// ==================== BN (finalize folded) + ELU -> bf16 ====================
template<int C>
__global__ __launch_bounds__(256) void bn_elu_apply2(const float* __restrict__ H, short* __restrict__ O,
    int M, float invM,
    const float* __restrict__ ssum, const float* __restrict__ ssq,
    const float* __restrict__ g, const float* __restrict__ bt){
  __shared__ float sc[C], sh[C];
  for (int c = threadIdx.x; c < C; c += 256){
    float mn  = ssum[c]*invM;
    float var = ssq[c]*invM - mn*mn;
    float s = g[c]*rsqrtf(var + 1e-5f);
    sc[c] = s; sh[c] = bt[c] - mn*s;
  }
  __syncthreads();
  int total4 = M*(C/4);
  for (int i = blockIdx.x*256+threadIdx.x; i < total4; i += gridDim.x*256){
    float4 v = ((const float4*)H)[i];
    int cb = (i*4) & (C-1);
    short4v o;
    o[0] = f2bf(eluf(v.x*sc[cb+0]+sh[cb+0]));
    o[1] = f2bf(eluf(v.y*sc[cb+1]+sh[cb+1]));
    o[2] = f2bf(eluf(v.z*sc[cb+2]+sh[cb+2]));
    o[3] = f2bf(eluf(v.w*sc[cb+3]+sh[cb+3]));
    ((short4v*)O)[i] = o;
  }
}

__global__ __launch_bounds__(256) void bn_elu_split(const float* __restrict__ H,
    short* __restrict__ Od, short* __restrict__ Oc, int M, float invM,
    const float* __restrict__ ssum, const float* __restrict__ ssq,
    const float* __restrict__ gd, const float* __restrict__ btd,
    const float* __restrict__ gc, const float* __restrict__ btc){
  __shared__ float sc[256], sh[256];
  {
    int c = threadIdx.x;
    float mn  = ssum[c]*invM;
    float var = ssq[c]*invM - mn*mn;
    float gg = (c<128) ? gd[c] : gc[c-128];
    float bb = (c<128) ? btd[c] : btc[c-128];
    float s = gg*rsqrtf(var + 1e-5f);
    sc[c] = s; sh[c] = bb - mn*s;
  }
  __syncthreads();
  int total4 = M*64;
  for (int i = blockIdx.x*256+threadIdx.x; i < total4; i += gridDim.x*256){
    float4 v = ((const float4*)H)[i];
    int cb = (i*4) & 255;
    short4v o;
    o[0] = f2bf(eluf(v.x*sc[cb+0]+sh[cb+0]));
    o[1] = f2bf(eluf(v.y*sc[cb+1]+sh[cb+1]));
    o[2] = f2bf(eluf(v.z*sc[cb+2]+sh[cb+2]));
    o[3] = f2bf(eluf(v.w*sc[cb+3]+sh[cb+3]));
    int row = i>>6;
    short* O = (cb < 128) ? Od : Oc;
    *(short4v*)&O[(size_t)row*128 + (cb&127)] = o;
  }
}

// ==================== CSR build ====================
__global__ void hist_kernel(const int* __restrict__ d, int E, int* __restrict__ deg){
  int i = blockIdx.x*256 + threadIdx.x;
  if (i < E) atomicAdd(&deg[d[i]], 1);
}
__global__ __launch_bounds__(256) void scan1(const int* __restrict__ deg, int* __restrict__ offs,
                                             int* __restrict__ bsum, int n){
  __shared__ int sm[256];
  int tid = threadIdx.x;
  int base = blockIdx.x*1024 + tid*4;
  int v0 = base+0<n ? deg[base+0] : 0;
  int v1 = base+1<n ? deg[base+1] : 0;
  int v2 = base+2<n ? deg[base+2] : 0;
  int v3 = base+3<n ? deg[base+3] : 0;
  int ts = v0+v1+v2+v3;
  sm[tid] = ts;
  __syncthreads();
  #pragma unroll
  for (int d=1; d<256; d<<=1){
    int t = (tid>=d) ? sm[tid-d] : 0;
    __syncthreads();
    sm[tid] += t;
    __syncthreads();
  }
  int ex = sm[tid] - ts;
  if (base+0<n) offs[base+0] = ex;
  if (base+1<n) offs[base+1] = ex+v0;
  if (base+2<n) offs[base+2] = ex+v0+v1;
  if (base+3<n) offs[base+3] = ex+v0+v1+v2;
  if (tid==255) bsum[blockIdx.x] = sm[255];
}
__global__ __launch_bounds__(256) void scan3(int* __restrict__ offs, const int* __restrict__ bsum,
                      int* __restrict__ cursor, int n, int total){
  __shared__ int base_sm;
  int tgt = blockIdx.x >> 2;
  if (threadIdx.x < 64){
    int j = threadIdx.x;
    int v = (j < tgt) ? bsum[j] : 0;
    #pragma unroll
    for (int d=32; d; d>>=1) v += __shfl_xor(v, d);
    if (j == 0) base_sm = v;
  }
  __syncthreads();
  int i = blockIdx.x*256 + threadIdx.x;
  if (i < n){ int v = offs[i] + base_sm; offs[i]=v; cursor[i]=v; }
  if (i == 0) offs[n] = total;
}
__global__ void scatter_kernel(const int* __restrict__ s, const int* __restrict__ d, int E,
                               int* __restrict__ cursor, int* __restrict__ csr){
  int i = blockIdx.x*256 + threadIdx.x;
  if (i < E){ int pos = atomicAdd(&cursor[d[i]], 1); csr[pos] = s[i]; }
}

// ==================== GAT1 ====================
__global__ __launch_bounds__(256) void gat1_scores_bf(const short* __restrict__ hh,
    const float* __restrict__ as, const float* __restrict__ ad,
    float* __restrict__ ss, float* __restrict__ sd, int n){
  int w = threadIdx.x >> 6, lane = threadIdx.x & 63;
  int row = blockIdx.x*4 + w;
  if (row >= n) return;
  const short* hr = hh + (size_t)row*192;
  float ps[3], pd[3];
  #pragma unroll
  for (int h=0; h<3; h++){
    float v = b2f(hr[h*64 + lane]);
    ps[h] = v * as[h*64+lane];
    pd[h] = v * ad[h*64+lane];
  }
  #pragma unroll
  for (int m=32; m; m>>=1){
    #pragma unroll
    for (int h=0;h<3;h++){ ps[h] += __shfl_xor(ps[h], m); pd[h] += __shfl_xor(pd[h], m); }
  }
  if (lane == 0){
    #pragma unroll
    for (int h=0;h<3;h++){ ss[row*3+h]=ps[h]; sd[row*3+h]=pd[h]; }
  }
}

__global__ __launch_bounds__(256) void gat1_gather_bf(const int* __restrict__ offs, const int* __restrict__ csr,
    const short* __restrict__ hh, const float* __restrict__ ss, const float* __restrict__ sd,
    const float* __restrict__ bias, short* __restrict__ out, int n){
  int w = threadIdx.x >> 6, lane = threadIdx.x & 63;
  int dst = blockIdx.x*4 + w;
  if (dst >= n) return;
  float sd0 = sd[dst*3+0], sd1 = sd[dst*3+1], sd2 = sd[dst*3+2];
  float p0 = __expf(lrelu(ss[dst*3+0]+sd0));
  float p1 = __expf(lrelu(ss[dst*3+1]+sd1));
  float p2 = __expf(lrelu(ss[dst*3+2]+sd2));
  const short* hr = hh + (size_t)dst*192;
  float a0 = p0*b2f(hr[lane]), a1 = p1*b2f(hr[64+lane]), a2 = p2*b2f(hr[128+lane]);
  float d0 = p0, d1 = p1, d2 = p2;
  int p = offs[dst], pe = offs[dst+1];
  int n0=0,n1=0,n2=0,n3=0;
  if (p+4 <= pe){ n0=csr[p]; n1=csr[p+1]; n2=csr[p+2]; n3=csr[p+3]; }
  while (p+4 <= pe){
    int s0=n0, s1=n1, s2=n2, s3=n3;
    int pn = p+4;
    if (pn+4 <= pe){ n0=csr[pn]; n1=csr[pn+1]; n2=csr[pn+2]; n3=csr[pn+3]; }
    float e00=ss[s0*3+0], e01=ss[s0*3+1], e02=ss[s0*3+2];
    float e10=ss[s1*3+0], e11=ss[s1*3+1], e12=ss[s1*3+2];
    float e20=ss[s2*3+0], e21=ss[s2*3+1], e22=ss[s2*3+2];
    float e30=ss[s3*3+0], e31=ss[s3*3+1], e32=ss[s3*3+2];
    const short* r0 = hh + (size_t)s0*192;
    const short* r1 = hh + (size_t)s1*192;
    const short* r2 = hh + (size_t)s2*192;
    const short* r3 = hh + (size_t)s3*192;
    float v00=b2f(r0[lane]), v01=b2f(r0[64+lane]), v02=b2f(r0[128+lane]);
    float v10=b2f(r1[lane]), v11=b2f(r1[64+lane]), v12=b2f(r1[128+lane]);
    float v20=b2f(r2[lane]), v21=b2f(r2[64+lane]), v22=b2f(r2[128+lane]);
    float v30=b2f(r3[lane]), v31=b2f(r3[64+lane]), v32=b2f(r3[128+lane]);
    float q00=__expf(lrelu(e00+sd0)), q01=__expf(lrelu(e01+sd1)), q02=__expf(lrelu(e02+sd2));
    float q10=__expf(lrelu(e10+sd0)), q11=__expf(lrelu(e11+sd1)), q12=__expf(lrelu(e12+sd2));
    float q20=__expf(lrelu(e20+sd0)), q21=__expf(lrelu(e21+sd1)), q22=__expf(lrelu(e22+sd2));
    float q30=__expf(lrelu(e30+sd0)), q31=__expf(lrelu(e31+sd1)), q32=__expf(lrelu(e32+sd2));
    a0 += q00*v00 + q10*v10 + q20*v20 + q30*v30;
    a1 += q01*v01 + q11*v11 + q21*v21 + q31*v31;
    a2 += q02*v02 + q12*v12 + q22*v22 + q32*v32;
    d0 += q00+q10+q20+q30;
    d1 += q01+q11+q21+q31;
    d2 += q02+q12+q22+q32;
    p = pn;
  }
  for (; p < pe; ++p){
    int src = csr[p];
    float q0 = __expf(lrelu(ss[src*3+0]+sd0));
    float q1 = __expf(lrelu(ss[src*3+1]+sd1));
    float q2 = __expf(lrelu(ss[src*3+2]+sd2));
    const short* sr = hh + (size_t)src*192;
    a0 += q0*b2f(sr[lane]); a1 += q1*b2f(sr[64+lane]); a2 += q2*b2f(sr[128+lane]);
    d0 += q0; d1 += q1; d2 += q2;
  }
  float v0 = a0/d0 + bias[lane];
  float v1 = a1/d1 + bias[64+lane];
  float v2 = a2/d2 + bias[128+lane];
  short* orow = out + (size_t)dst*192;
  orow[lane]      = f2bf(v0 > 0.f ? v0 : 0.f);
  orow[64+lane]   = f2bf(v1 > 0.f ? v1 : 0.f);
  orow[128+lane]  = f2bf(v2 > 0.f ? v2 : 0.f);
}

// ==================== GAT2/3 gather (hh23 [N][64]: cols 0-29 = h2, 32-61 = h3) ====================
__global__ __launch_bounds__(256) void gat23_gather(const int* __restrict__ offs, const int* __restrict__ csr,
    const float* __restrict__ hh23,
    const float* __restrict__ s2s, const float* __restrict__ s2d,
    const float* __restrict__ s3s, const float* __restrict__ s3d,
    const float* __restrict__ b2, const float* __restrict__ b3,
    float* __restrict__ zs, float* __restrict__ mus, float* __restrict__ lvs,
    short* __restrict__ zbf, int n){
  int w = threadIdx.x >> 6, lane = threadIdx.x & 63;
  int dst = blockIdx.x*4 + w;
  if (dst >= n) return;
  bool lo = lane < 32;
  int c = lane & 31;
  bool valid = c < 30;
  float sdA = s2d[dst], sdB = s3d[dst];
  float sdx = lo ? sdA : sdB;
  const float* ssx = lo ? s2s : s3s;
  float p2 = __expf(lrelu(s2s[dst]+sdA));
  float p3 = __expf(lrelu(s3s[dst]+sdB));
  float val = valid ? hh23[(size_t)dst*64+lane] : 0.f;
  float acc = (lo ? p2 : p3) * val;
  float den2 = p2, den3 = p3;
  int p = offs[dst], pe = offs[dst+1];
  int n0=0,n1=0,n2=0,n3=0;
  if (p+4 <= pe){ n0=csr[p]; n1=csr[p+1]; n2=csr[p+2]; n3=csr[p+3]; }
  while (p+4 <= pe){
    int s0=n0, s1=n1, s2i=n2, s3i=n3;
    int pn = p+4;
    if (pn+4 <= pe){ n0=csr[pn]; n1=csr[pn+1]; n2=csr[pn+2]; n3=csr[pn+3]; }
    float eA0=ssx[s0], eA1=ssx[s1], eA2=ssx[s2i], eA3=ssx[s3i];
    float f20=s2s[s0], f21=s2s[s1], f22=s2s[s2i], f23=s2s[s3i];
    float f30=s3s[s0], f31=s3s[s1], f32=s3s[s2i], f33=s3s[s3i];
    float v0 = valid ? hh23[(size_t)s0*64+lane] : 0.f;
    float v1 = valid ? hh23[(size_t)s1*64+lane] : 0.f;
    float v2 = valid ? hh23[(size_t)s2i*64+lane] : 0.f;
    float v3 = valid ? hh23[(size_t)s3i*64+lane] : 0.f;
    float qx0=__expf(lrelu(eA0+sdx)), qx1=__expf(lrelu(eA1+sdx));
    float qx2=__expf(lrelu(eA2+sdx)), qx3=__expf(lrelu(eA3+sdx));
    acc += qx0*v0 + qx1*v1 + qx2*v2 + qx3*v3;
    den2 += __expf(lrelu(f20+sdA)) + __expf(lrelu(f21+sdA)) + __expf(lrelu(f22+sdA)) + __expf(lrelu(f23+sdA));
    den3 += __expf(lrelu(f30+sdB)) + __expf(lrelu(f31+sdB)) + __expf(lrelu(f32+sdB)) + __expf(lrelu(f33+sdB));
    p = pn;
  }
  for (; p < pe; ++p){
    int src = csr[p];
    float q2 = __expf(lrelu(s2s[src]+sdA));
    float q3 = __expf(lrelu(s3s[src]+sdB));
    float v = valid ? hh23[(size_t)src*64+lane] : 0.f;
    acc += (lo ? q2 : q3) * v;
    den2 += q2; den3 += q3;
  }
  if (lo){
    if (valid){
      float v = acc/den2 + b2[c];
      zs[(size_t)dst*30+c]  = v;
      mus[(size_t)dst*30+c] = v;
      zbf[(size_t)dst*32+c] = f2bf(v);
    } else {
      zbf[(size_t)dst*32+c] = 0;
    }
  } else if (valid){
    lvs[(size_t)dst*30+c] = acc/den3 + b3[c];
  }
}

// ==================== host ====================
static inline int cdiv(int a, int b){ return (a + b - 1) / b; }

extern "C" void kernel_launch(void* const* d_in, const int* in_sizes, int n_in,
                              void* d_out, int out_size, void* d_ws, size_t ws_size,
                              hipStream_t stream)
{
  const float* x        = (const float*)d_in[0];
  const int*   ei       = (const int*)  d_in[1];
  const float* enc_w1   = (const float*)d_in[2];
  const float* enc_g1   = (const float*)d_in[4];
  const float* enc_bt1  = (const float*)d_in[5];
  const float* enc_w2   = (const float*)d_in[6];
  const float* enc_g2   = (const float*)d_in[8];
  const float* enc_bt2  = (const float*)d_in[9];
  const float* gat1_w   = (const float*)d_in[10];
  const float* gat1_as  = (const float*)d_in[11];
  const float* gat1_ad  = (const float*)d_in[12];
  const float* gat1_b   = (const float*)d_in[13];
  const float* gat2_w   = (const float*)d_in[14];
  const float* gat2_as  = (const float*)d_in[15];
  const float* gat2_ad  = (const float*)d_in[16];
  const float* gat2_b   = (const float*)d_in[17];
  const float* gat3_w   = (const float*)d_in[18];
  const float* gat3_as  = (const float*)d_in[19];
  const float* gat3_ad  = (const float*)d_in[20];
  const float* gat3_b   = (const float*)d_in[21];
  const float* dec_w1   = (const float*)d_in[22];
  const float* dec_g1   = (const float*)d_in[24];
  const float* dec_bt1  = (const float*)d_in[25];
  const float* dec_w2   = (const float*)d_in[26];
  const float* dec_g2   = (const float*)d_in[28];
  const float* dec_bt2  = (const float*)d_in[29];
  const float* dec_w3   = (const float*)d_in[30];
  const float* dec_b3   = (const float*)d_in[31];
  const float* clu_w1   = (const float*)d_in[32];
  const float* clu_g1   = (const float*)d_in[34];
  const float* clu_bt1  = (const float*)d_in[35];
  const float* clu_w2   = (const float*)d_in[36];
  const float* clu_b2   = (const float*)d_in[37];

  const int N = in_sizes[0] / 1000;
  const int E = in_sizes[1] / 2;
  const int* e_src = ei;
  const int* e_dst = ei + E;
  const float invN = 1.f/(float)N;

  float* out  = (float*)d_out;
  float* pred = out;
  float* xrec = out + (size_t)N*10;
  float* zs   = xrec + (size_t)N*1000;
  float* mus  = zs  + (size_t)N*30;
  float* lvs  = mus + (size_t)N*30;

  char* ws = (char*)d_ws;
  size_t off = 0;
  auto alloc = [&](size_t bytes)->char*{
    char* p = ws + off;
    off = (off + bytes + 255) & ~(size_t)255;
    return p;
  };
  short* t_enc1  = (short*)alloc(256*1024*2);
  short* t_enc2  = (short*)alloc(128*256*2);
  short* t_gat1  = (short*)alloc(256*128*2);
  short* t_gat23 = (short*)alloc(64*192*2);
  short* t_dc1   = (short*)alloc(256*32*2);
  short* t_dec2  = (short*)alloc(256*128*2);
  short* t_dec3  = (short*)alloc(1024*256*2);
  short* t_clu2  = (short*)alloc(32*128*2);
  float* h1f  = (float*)alloc((size_t)N*256*4);
  short* h1b  = (short*)alloc((size_t)N*256*2);   // xb alias start
  float* h2f  = (float*)alloc((size_t)N*128*4);
  short* h2b  = (short*)alloc((size_t)N*128*2);
  short* hh1b = (short*)alloc((size_t)N*192*2);
  short* h3b  = (short*)alloc((size_t)N*192*2);
  float* hh23f= (float*)alloc((size_t)N*64*4);
  short* zbf  = (short*)alloc((size_t)N*32*2);
  float* ss1  = (float*)alloc((size_t)N*3*4);
  float* sd1  = (float*)alloc((size_t)N*3*4);
  float* s2s  = (float*)alloc((size_t)N*4);
  float* s2d  = (float*)alloc((size_t)N*4);
  float* s3s  = (float*)alloc((size_t)N*4);
  float* s3d  = (float*)alloc((size_t)N*4);
  float* stats= (float*)alloc(2048*4);
  int*   deg  = (int*)alloc((size_t)(N+1)*4);
  int*   offs = (int*)alloc((size_t)(N+1)*4);
  int*   curp = (int*)alloc((size_t)(N+1)*4);
  int*   bsum = (int*)alloc(256*4);
  int*   csr  = (int*)alloc((size_t)E*4);
  // aliases (lifetimes):
  short* xb   = h1b;               // spans h1b..h3b (102.4MB >= 100MB); dead after enc1 gemm
  float* dc1f = h2f;               // [N][256] f32 spans h2f+h2b+hh1b (57.6MB); live from dc1 gemm
  short* d1b  = h3b;               // h3b dead after gat23 gemm
  short* c1b  = (short*)hh23f;     // hh23f dead after gat23 gather
  float* d2f  = h1f;               // h1f dead after enc1 apply
  short* d2b  = h1b;               // h1b dead after enc2 gemm
  float* st_enc1 = stats, *st_enc2 = stats+512, *st_dc1 = stats+768, *st_dec2 = stats+1280;

  // --- weight prep + zeroing ---
  WTab tab;
  tab.e[0]  = {enc_w1, t_enc1, 1000, 256, 1024, 256};
  tab.e[1]  = {enc_w2, t_enc2, 256, 128, 256, 128};
  tab.e[2]  = {gat1_w, t_gat1, 128, 192, 128, 256};
  tab.e[3]  = {gat2_w, t_gat23, 192, 30, 192, 32};
  tab.e[4]  = {gat3_w, t_gat23 + 32*192, 192, 30, 192, 32};
  tab.e[5]  = {dec_w1, t_dc1, 30, 128, 32, 128};
  tab.e[6]  = {clu_w1, t_dc1 + 128*32, 30, 128, 32, 128};
  tab.e[7]  = {dec_w2, t_dec2, 128, 256, 128, 256};
  tab.e[8]  = {dec_w3, t_dec3, 256, 1000, 256, 1024};
  tab.e[9]  = {clu_w2, t_clu2, 128, 10, 128, 32};
  wtrans_all<<<dim3(1024, 10), 256, 0, stream>>>(tab);
  hipMemsetAsync(stats, 0, 2048*4, stream);
  hipMemsetAsync(deg, 0, (size_t)(N+1)*4, stream);

  // --- CSR ---
  hist_kernel<<<cdiv(E,256), 256, 0, stream>>>(e_dst, E, deg);
  int nb = cdiv(N, 1024);
  scan1<<<nb, 256, 0, stream>>>(deg, offs, bsum, N);
  scan3<<<cdiv(N,256), 256, 0, stream>>>(offs, bsum, curp, N, E);
  scatter_kernel<<<cdiv(E,256), 256, 0, stream>>>(e_src, e_dst, E, curp, csr);

  const int MB = cdiv(N, 128);   // 391

  // --- encoder L1: cvt to bf16, then GEMM (swizzled: 2 col-tiles share A panel) ---
  cvt_x<<<cdiv(N,2), 256, 0, stream>>>(x, xb, N);
  gemm_g<128,false,true,false,false><<<MB*2, 256, 0, stream>>>(
      xb, 1000, t_enc1, 1024, h1f, 256, nullptr, N, 256, 1000, 2,
      st_enc1, st_enc1+256, nullptr,nullptr,nullptr,nullptr, nullptr,nullptr,nullptr,nullptr);
  bn_elu_apply2<256><<<2048, 256, 0, stream>>>(h1f, h1b, N, invN, st_enc1, st_enc1+256, enc_g1, enc_bt1);

  // --- encoder L2 ---
  gemm_g<128,false,true,false,false><<<MB, 256, 0, stream>>>(
      h1b, 256, t_enc2, 256, h2f, 128, nullptr, N, 128, 256, 1,
      st_enc2, st_enc2+128, nullptr,nullptr,nullptr,nullptr, nullptr,nullptr,nullptr,nullptr);
  bn_elu_apply2<128><<<2048, 256, 0, stream>>>(h2f, h2b, N, invN, st_enc2, st_enc2+128, enc_g2, enc_bt2);

  // --- GAT1 (3 col-tiles share A panel) ---
  gemm_g<64,true,false,false,false><<<MB*3, 256, 0, stream>>>(
      h2b, 128, t_gat1, 128, hh1b, 192, nullptr, N, 192, 128, 3,
      nullptr,nullptr, nullptr,nullptr,nullptr,nullptr, nullptr,nullptr,nullptr,nullptr);
  gat1_scores_bf<<<cdiv(N,4), 256, 0, stream>>>(hh1b, gat1_as, gat1_ad, ss1, sd1, N);
  gat1_gather_bf<<<cdiv(N,4), 256, 0, stream>>>(offs, csr, hh1b, ss1, sd1, gat1_b, h3b, N);

  // --- GAT2+GAT3 (combined weights, scores folded into epilogue) ---
  gemm_g<64,false,false,false,true><<<MB, 256, 0, stream>>>(
      h3b, 192, t_gat23, 192, hh23f, 64, nullptr, N, 64, 192, 1,
      nullptr,nullptr, s2s,s2d,s3s,s3d, gat2_as,gat2_ad,gat3_as,gat3_ad);
  gat23_gather<<<cdiv(N,4), 256, 0, stream>>>(offs, csr, hh23f, s2s, s2d, s3s, s3d, gat2_b, gat3_b, zs, mus, lvs, zbf, N);

  // --- dec1 + clu1 combined ---
  gemm_g<128,false,true,false,false><<<MB*2, 256, 0, stream>>>(
      zbf, 32, t_dc1, 32, dc1f, 256, nullptr, N, 256, 32, 2,
      st_dc1, st_dc1+256, nullptr,nullptr,nullptr,nullptr, nullptr,nullptr,nullptr,nullptr);
  bn_elu_split<<<2048, 256, 0, stream>>>(dc1f, d1b, c1b, N, invN, st_dc1, st_dc1+256, dec_g1, dec_bt1, clu_g1, clu_bt1);

  // --- dec2 ---
  gemm_g<128,false,true,false,false><<<MB*2, 256, 0, stream>>>(
      d1b, 128, t_dec2, 128, d2f, 256, nullptr, N, 256, 128, 2,
      st_dec2, st_dec2+256, nullptr,nullptr,nullptr,nullptr, nullptr,nullptr,nullptr,nullptr);
  bn_elu_apply2<256><<<2048, 256, 0, stream>>>(d2f, d2b, N, invN, st_dec2, st_dec2+256, dec_g2, dec_bt2);

  // --- dec3 (8 col-tiles share A panel -> L2) ---
  gemm_g<128,false,false,false,false><<<MB*8, 256, 0, stream>>>(
      d2b, 256, t_dec3, 256, xrec, 1000, dec_b3, N, 1000, 256, 8,
      nullptr,nullptr, nullptr,nullptr,nullptr,nullptr, nullptr,nullptr,nullptr,nullptr);

  // --- clu2 + fused softmax ---
  gemm_g<32,false,false,true,false><<<MB, 256, 0, stream>>>(
      c1b, 128, t_clu2, 128, pred, 10, clu_b2, N, 10, 128, 1,
      nullptr,nullptr, nullptr,nullptr,nullptr,nullptr, nullptr,nullptr,nullptr,nullptr);
}

// Round 9
// 632.711 us; speedup vs baseline: 1.2579x; 1.0062x over previous
//
#include <hip/hip_runtime.h>
#include <hip/hip_bf16.h>

typedef short short8 __attribute__((ext_vector_type(8)));
typedef short short4v __attribute__((ext_vector_type(4)));
typedef float f32x4 __attribute__((ext_vector_type(4)));

static __device__ __forceinline__ short f2bf(float f){
  __hip_bfloat16 h = __float2bfloat16(f);
  return __builtin_bit_cast(short, h);
}
static __device__ __forceinline__ float b2f(short s){
  unsigned int u = ((unsigned int)(unsigned short)s) << 16;
  return __builtin_bit_cast(float, u);
}
static __device__ __forceinline__ float lrelu(float x){ return x > 0.f ? x : 0.2f*x; }
static __device__ __forceinline__ float eluf(float x){ return x > 0.f ? x : (__expf(x)-1.f); }
static __device__ __forceinline__ int imin(int a,int b){ return a<b?a:b; }

typedef const __attribute__((address_space(1))) void as1_void;
typedef __attribute__((address_space(3))) void as3_void;
static __device__ __forceinline__ void gload16(const void* g, void* l){
  __builtin_amdgcn_global_load_lds((as1_void*)g, (as3_void*)l, 16, 0, 0);
}
template<int NN> __device__ __forceinline__ void wait_vm(){
  if constexpr (NN==0) asm volatile("s_waitcnt vmcnt(0)" ::: "memory");
  else if constexpr (NN==3) asm volatile("s_waitcnt vmcnt(3)" ::: "memory");
  else if constexpr (NN==4) asm volatile("s_waitcnt vmcnt(4)" ::: "memory");
  else if constexpr (NN==6) asm volatile("s_waitcnt vmcnt(6)" ::: "memory");
  else if constexpr (NN==8) asm volatile("s_waitcnt vmcnt(8)" ::: "memory");
  else asm volatile("s_waitcnt vmcnt(0)" ::: "memory");
}

// ==================== x f32 -> bf16 convert (streaming) ====================
__global__ __launch_bounds__(256) void cvt_x(const float* __restrict__ x, short* __restrict__ xb, int M){
  int row = blockIdx.x*2 + (threadIdx.x>>7);
  int c8  = (threadIdx.x&127)*8;
  if (row >= M || c8 >= 1000) return;
  const float* p = x + (size_t)row*1000 + c8;
  float4 f0 = *(const float4*)p, f1 = *(const float4*)(p+4);
  short8 o;
  o[0]=f2bf(f0.x);o[1]=f2bf(f0.y);o[2]=f2bf(f0.z);o[3]=f2bf(f0.w);
  o[4]=f2bf(f1.x);o[5]=f2bf(f1.y);o[6]=f2bf(f1.z);o[7]=f2bf(f1.w);
  *(short8*)&xb[(size_t)row*1000 + c8] = o;
}

// ==================== GEMM: gload_lds ring-4, BK=32, counted vmcnt, XCD swizzle ====================
// A bf16 [M][lda]; Bt bf16 [NR][ldb] zero-padded. B zero for k in [K, ceil32(K)).
template<int BN, bool OBF16, bool CST, bool SMAX, bool G23S, bool G1S>
__global__ __launch_bounds__(256) void gemm_g(
    const short* __restrict__ A, int lda, const short* __restrict__ Bt, int ldb,
    void* __restrict__ Cv, int ldc, const float* __restrict__ bias,
    int M, int N, int K, int nbn,
    float* __restrict__ o_sum, float* __restrict__ o_sq,
    float* __restrict__ s2s, float* __restrict__ s2d,
    float* __restrict__ s3s, float* __restrict__ s3d,
    const float* __restrict__ a2s, const float* __restrict__ a2d,
    const float* __restrict__ a3s, const float* __restrict__ a3d)
{
  constexpr int BM = 128, BK = 32, GPR = 4;
  constexpr int WM = BM/2, WN = BN/2;
  constexpr int FM = WM/16, FN = WN/16;
  constexpr int AI = (BM*GPR)/(4*64);
  constexpr int BI_T = (BN*GPR)/64;
  constexpr bool BDUP = (BI_T < 4);
  constexpr int BI = BDUP ? BI_T : BI_T/4;
  constexpr int LPT = AI + BI;
  constexpr int TS = (BM+BN)*BK;
  __shared__ short lds[4][TS];

  const int tid = threadIdx.x, wid = tid>>6, lane = tid&63;
  const int wm = wid>>1, wn = wid&1;
  // XCD-chunked bijective swizzle (m204)
  int nwg = gridDim.x;
  int q8 = nwg >> 3, r8 = nwg & 7;
  int xcd = blockIdx.x & 7, pos = blockIdx.x >> 3;
  int wg = (xcd < r8 ? xcd*(q8+1) : r8*(q8+1) + (xcd-r8)*q8) + pos;
  int bmt = wg / nbn, bnt = wg - bmt*nbn;
  const int bm = bmt*BM, bn = bnt*BN;
  const int lr = lane&15, lg = lane>>4;
  const int nt = (K + BK - 1)/BK;

  f32x4 acc[FM][FN] = {};

  auto STAGE = [&](int t){
    int buf = t & 3, k0 = t*BK;
    #pragma unroll
    for (int i=0;i<AI;i++){
      int ci = wid*AI + i;
      int c = ci*64 + lane;
      int row = c>>2, g = c&3;
      int gr = imin(bm+row, M-1);
      const short* src = A + (size_t)gr*lda + k0 + ((g ^ (row&3))<<3);
      gload16(src, &lds[buf][ci*512]);
    }
    #pragma unroll
    for (int i=0;i<BI;i++){
      int bi = BDUP ? i : wid*BI + i;
      int c = bi*64 + lane;
      int row = c>>2, g = c&3;
      const short* src = Bt + (size_t)(bn+row)*ldb + k0 + ((g ^ (row&3))<<3);
      gload16(src, &lds[buf][BM*BK + bi*512]);
    }
  };

  for (int s=0; s<3 && s<nt; ++s) STAGE(s);

  for (int t=0; t<nt; ++t){
    int newer = imin(nt, t+3) - t - 1;
    if (newer >= 2) wait_vm<2*LPT>();
    else if (newer == 1) wait_vm<LPT>();
    else wait_vm<0>();
    __builtin_amdgcn_s_barrier();
    __builtin_amdgcn_sched_barrier(0);
    if (t+3 < nt) STAGE(t+3);
    int buf = t & 3;
    short8 af[FM], bf[FN];
    #pragma unroll
    for (int m=0;m<FM;m++){
      int r = wm*WM + m*16 + lr;
      af[m] = *(short8*)&lds[buf][r*BK + ((lg ^ (r&3))<<3)];
    }
    #pragma unroll
    for (int n=0;n<FN;n++){
      int r = wn*WN + n*16 + lr;
      bf[n] = *(short8*)&lds[buf][BM*BK + r*BK + ((lg ^ (r&3))<<3)];
    }
    #pragma unroll
    for (int m=0;m<FM;m++)
      #pragma unroll
      for (int n=0;n<FN;n++)
        acc[m][n] = __builtin_amdgcn_mfma_f32_16x16x32_bf16(af[m], bf[n], acc[m][n], 0, 0, 0);
  }

  if (SMAX){
    // clu2: N=10 cols live in wn==0, n==0, lr<10. Row-softmax in-register.
    #pragma unroll
    for (int m=0;m<FM;m++)
      #pragma unroll
      for (int q=0;q<4;q++){
        int row = bm + wm*WM + m*16 + lg*4 + q;
        float v = (lr < 10) ? (acc[m][0][q] + bias[lr]) : -3e38f;
        float mx = v;
        #pragma unroll
        for (int d=1; d<16; d<<=1) mx = fmaxf(mx, __shfl_xor(mx, d));
        float e = (lr < 10) ? __expf(v - mx) : 0.f;
        float sm = e;
        #pragma unroll
        for (int d=1; d<16; d<<=1) sm += __shfl_xor(sm, d);
        if (wn == 0 && lr < 10 && row < M)
          ((float*)Cv)[(size_t)row*10 + lr] = e/sm;
      }
    return;
  }

  #pragma unroll
  for (int m=0;m<FM;m++)
    #pragma unroll
    for (int n=0;n<FN;n++)
      #pragma unroll
      for (int q=0;q<4;q++){
        int row = bm + wm*WM + m*16 + lg*4 + q;
        int col = bn + wn*WN + n*16 + lr;
        if (row < M && col < N){
          float v = acc[m][n][q];
          if (bias) v += bias[col];
          if (OBF16) ((short*)Cv)[(size_t)row*ldc + col] = f2bf(v);
          else       ((float*)Cv)[(size_t)row*ldc + col] = v;
        }
      }

  if (G1S){
    // gat1: fold score reduction; bnt == head (nbn==3, BN==64).
    int h = bnt;
    float a_s[FN], a_d[FN];
    #pragma unroll
    for (int n=0;n<FN;n++){
      int cl = wn*WN + n*16 + lr;           // head-local col (0..63)
      a_s[n] = a2s[h*64 + cl];
      a_d[n] = a2d[h*64 + cl];
    }
    #pragma unroll
    for (int m=0;m<FM;m++)
      #pragma unroll
      for (int q=0;q<4;q++){
        int row = bm + wm*WM + m*16 + lg*4 + q;
        float ps = 0.f, pd = 0.f;
        #pragma unroll
        for (int n=0;n<FN;n++){ ps += acc[m][n][q]*a_s[n]; pd += acc[m][n][q]*a_d[n]; }
        #pragma unroll
        for (int d=1; d<16; d<<=1){ ps += __shfl_xor(ps, d); pd += __shfl_xor(pd, d); }
        if (lr == 0 && row < M){
          atomicAdd(&s2s[row*3+h], ps);
          atomicAdd(&s2d[row*3+h], pd);
        }
      }
  }

  if (G23S){
    // gat23: fold score reduction. wn==0 -> s2 (cols 0-31), wn==1 -> s3 (cols 32-63).
    float a_s[FN], a_d[FN];
    #pragma unroll
    for (int n=0;n<FN;n++){
      int cl = n*16 + lr;
      bool valid = cl < 30;
      a_s[n] = valid ? (wn ? a3s[cl] : a2s[cl]) : 0.f;
      a_d[n] = valid ? (wn ? a3d[cl] : a2d[cl]) : 0.f;
    }
    #pragma unroll
    for (int m=0;m<FM;m++)
      #pragma unroll
      for (int q=0;q<4;q++){
        int row = bm + wm*WM + m*16 + lg*4 + q;
        float ps = 0.f, pd = 0.f;
        #pragma unroll
        for (int n=0;n<FN;n++){ ps += acc[m][n][q]*a_s[n]; pd += acc[m][n][q]*a_d[n]; }
        #pragma unroll
        for (int d=1; d<16; d<<=1){ ps += __shfl_xor(ps, d); pd += __shfl_xor(pd, d); }
        if (lr == 0 && row < M){
          if (wn){ s3s[row] = ps; s3d[row] = pd; }
          else   { s2s[row] = ps; s2d[row] = pd; }
        }
      }
  }

  if (CST){
    #pragma unroll
    for (int n=0;n<FN;n++){
      float s = 0.f, q2 = 0.f;
      #pragma unroll
      for (int m=0;m<FM;m++)
        #pragma unroll
        for (int q=0;q<4;q++){
          int row = bm + wm*WM + m*16 + lg*4 + q;
          if (row < M){ float v = acc[m][n][q]; s += v; q2 += v*v; }
        }
      s  += __shfl_xor(s, 16);  s += __shfl_xor(s, 32);
      q2 += __shfl_xor(q2, 16); q2 += __shfl_xor(q2, 32);
      if (lg == 0){
        int col = bn + wn*WN + n*16 + lr;
        if (col < N){ atomicAdd(&o_sum[col], s); atomicAdd(&o_sq[col], q2); }
      }
    }
  }
}

// ==================== weight transpose/convert ====================
struct WEnt { const float* src; short* dst; int K, N, KP, NR; };
struct WTab { WEnt e[10]; };
__global__ __launch_bounds__(256) void wtrans_all(WTab tab){
  WEnt w = tab.e[blockIdx.y];
  int gid = blockIdx.x*256 + threadIdx.x;
  if (gid >= w.NR * w.KP) return;
  int n = gid / w.KP, k = gid - n*w.KP;
  float v = (k < w.K && n < w.N) ? w.src[(size_t)k*w.N + n] : 0.f;
  w.dst[gid] = f2bf(v);
}

// ==================== BN (finalize folded) + ELU: bf16 in -> bf16 out ====================
template<int C>
__global__ __launch_bounds__(256) void bn_elu_apply2(const short* __restrict__ H, short* __restrict__ O,
    int M, float invM,
    const float* __restrict__ ssum, const float* __restrict__ ssq,
    const float* __restrict__ g, const float* __restrict__ bt){
  __shared__ float sc[C], sh[C];
  for (int c = threadIdx.x; c < C; c += 256){
    float mn  = ssum[c]*invM;
    float var = ssq[c]*invM - mn*mn;
    float s = g[c]*rsqrtf(var + 1e-5f);
    sc[c] = s; sh[c] = bt[c] - mn*s;
  }
  __syncthreads();
  int total8 = M*(C/8);
  for (int i = blockIdx.x*256+threadIdx.x; i < total8; i += gridDim.x*256){
    short8 v = ((const short8*)H)[i];
    int cb = (i*8) & (C-1);
    short8 o;
    #pragma unroll
    for (int j=0;j<8;j++) o[j] = f2bf(eluf(b2f(v[j])*sc[cb+j]+sh[cb+j]));
    ((short8*)O)[i] = o;
  }
}

__global__ __launch_bounds__(256) void bn_elu_split(const short* __restrict__ H,
    short* __restrict__ Od, short* __restrict__ Oc, int M, float invM,
    const float* __restrict__ ssum, const float* __restrict__ ssq,
    const float* __restrict__ gd, const float* __restrict__ btd,
    const float* __restrict__ gc, const float* __restrict__ btc){
  __shared__ float sc[256], sh[256];
  {
    int c = threadIdx.x;
    float mn  = ssum[c]*invM;
    float var = ssq[c]*invM - mn*mn;
    float gg = (c<128) ? gd[c] : gc[c-128];
    float bb = (c<128) ? btd[c] : btc[c-128];
    float s = gg*rsqrtf(var + 1e-5f);
    sc[c] = s; sh[c] = bb - mn*s;
  }
  __syncthreads();
  int total8 = M*32;               // 256 cols / 8
  for (int i = blockIdx.x*256+threadIdx.x; i < total8; i += gridDim.x*256){
    short8 v = ((const short8*)H)[i];
    int cb = (i*8) & 255;
    short8 o;
    #pragma unroll
    for (int j=0;j<8;j++) o[j] = f2bf(eluf(b2f(v[j])*sc[cb+j]+sh[cb+j]));
    int row = i>>5;
    short* O = (cb < 128) ? Od : Oc;
    *(short8*)&O[(size_t)row*128 + (cb&127)] = o;
  }
}

// ==================== CSR build ====================
__global__ void hist_kernel(const int* __restrict__ d, int E, int* __restrict__ deg){
  int i = blockIdx.x*256 + threadIdx.x;
  if (i < E) atomicAdd(&deg[d[i]], 1);
}
__global__ __launch_bounds__(256) void scan1(const int* __restrict__ deg, int* __restrict__ offs,
                                             int* __restrict__ bsum, int n){
  __shared__ int sm[256];
  int tid = threadIdx.x;
  int base = blockIdx.x*1024 + tid*4;
  int v0 = base+0<n ? deg[base+0] : 0;
  int v1 = base+1<n ? deg[base+1] : 0;
  int v2 = base+2<n ? deg[base+2] : 0;
  int v3 = base+3<n ? deg[base+3] : 0;
  int ts = v0+v1+v2+v3;
  sm[tid] = ts;
  __syncthreads();
  #pragma unroll
  for (int d=1; d<256; d<<=1){
    int t = (tid>=d) ? sm[tid-d] : 0;
    __syncthreads();
    sm[tid] += t;
    __syncthreads();
  }
  int ex = sm[tid] - ts;
  if (base+0<n) offs[base+0] = ex;
  if (base+1<n) offs[base+1] = ex+v0;
  if (base+2<n) offs[base+2] = ex+v0+v1;
  if (base+3<n) offs[base+3] = ex+v0+v1+v2;
  if (tid==255) bsum[blockIdx.x] = sm[255];
}
__global__ __launch_bounds__(256) void scan3(int* __restrict__ offs, const int* __restrict__ bsum,
                      int* __restrict__ cursor, int n, int total){
  __shared__ int base_sm;
  int tgt = blockIdx.x >> 2;
  if (threadIdx.x < 64){
    int j = threadIdx.x;
    int v = (j < tgt) ? bsum[j] : 0;
    #pragma unroll
    for (int d=32; d; d>>=1) v += __shfl_xor(v, d);
    if (j == 0) base_sm = v;
  }
  __syncthreads();
  int i = blockIdx.x*256 + threadIdx.x;
  if (i < n){ int v = offs[i] + base_sm; offs[i]=v; cursor[i]=v; }
  if (i == 0) offs[n] = total;
}
__global__ void scatter_kernel(const int* __restrict__ s, const int* __restrict__ d, int E,
                               int* __restrict__ cursor, int* __restrict__ csr){
  int i = blockIdx.x*256 + threadIdx.x;
  if (i < E){ int pos = atomicAdd(&cursor[d[i]], 1); csr[pos] = s[i]; }
}

// ==================== GAT1 gather ====================
__global__ __launch_bounds__(256) void gat1_gather_bf(const int* __restrict__ offs, const int* __restrict__ csr,
    const short* __restrict__ hh, const float* __restrict__ ss, const float* __restrict__ sd,
    const float* __restrict__ bias, short* __restrict__ out, int n){
  int w = threadIdx.x >> 6, lane = threadIdx.x & 63;
  int dst = blockIdx.x*4 + w;
  if (dst >= n) return;
  float sd0 = sd[dst*3+0], sd1 = sd[dst*3+1], sd2 = sd[dst*3+2];
  float p0 = __expf(lrelu(ss[dst*3+0]+sd0));
  float p1 = __expf(lrelu(ss[dst*3+1]+sd1));
  float p2 = __expf(lrelu(ss[dst*3+2]+sd2));
  const short* hr = hh + (size_t)dst*192;
  float a0 = p0*b2f(hr[lane]), a1 = p1*b2f(hr[64+lane]), a2 = p2*b2f(hr[128+lane]);
  float d0 = p0, d1 = p1, d2 = p2;
  int p = offs[dst], pe = offs[dst+1];
  int n0=0,n1=0,n2=0,n3=0;
  if (p+4 <= pe){ n0=csr[p]; n1=csr[p+1]; n2=csr[p+2]; n3=csr[p+3]; }
  while (p+4 <= pe){
    int s0=n0, s1=n1, s2=n2, s3=n3;
    int pn = p+4;
    if (pn+4 <= pe){ n0=csr[pn]; n1=csr[pn+1]; n2=csr[pn+2]; n3=csr[pn+3]; }
    float e00=ss[s0*3+0], e01=ss[s0*3+1], e02=ss[s0*3+2];
    float e10=ss[s1*3+0], e11=ss[s1*3+1], e12=ss[s1*3+2];
    float e20=ss[s2*3+0], e21=ss[s2*3+1], e22=ss[s2*3+2];
    float e30=ss[s3*3+0], e31=ss[s3*3+1], e32=ss[s3*3+2];
    const short* r0 = hh + (size_t)s0*192;
    const short* r1 = hh + (size_t)s1*192;
    const short* r2 = hh + (size_t)s2*192;
    const short* r3 = hh + (size_t)s3*192;
    float v00=b2f(r0[lane]), v01=b2f(r0[64+lane]), v02=b2f(r0[128+lane]);
    float v10=b2f(r1[lane]), v11=b2f(r1[64+lane]), v12=b2f(r1[128+lane]);
    float v20=b2f(r2[lane]), v21=b2f(r2[64+lane]), v22=b2f(r2[128+lane]);
    float v30=b2f(r3[lane]), v31=b2f(r3[64+lane]), v32=b2f(r3[128+lane]);
    float q00=__expf(lrelu(e00+sd0)), q01=__expf(lrelu(e01+sd1)), q02=__expf(lrelu(e02+sd2));
    float q10=__expf(lrelu(e10+sd0)), q11=__expf(lrelu(e11+sd1)), q12=__expf(lrelu(e12+sd2));
    float q20=__expf(lrelu(e20+sd0)), q21=__expf(lrelu(e21+sd1)), q22=__expf(lrelu(e22+sd2));
    float q30=__expf(lrelu(e30+sd0)), q31=__expf(lrelu(e31+sd1)), q32=__expf(lrelu(e32+sd2));
    a0 += q00*v00 + q10*v10 + q20*v20 + q30*v30;
    a1 += q01*v01 + q11*v11 + q21*v21 + q31*v31;
    a2 += q02*v02 + q12*v12 + q22*v22 + q32*v32;
    d0 += q00+q10+q20+q30;
    d1 += q01+q11+q21+q31;
    d2 += q02+q12+q22+q32;
    p = pn;
  }
  for (; p < pe; ++p){
    int src = csr[p];
    float q0 = __expf(lrelu(ss[src*3+0]+sd0));
    float q1 = __expf(lrelu(ss[src*3+1]+sd1));
    float q2 = __expf(lrelu(ss[src*3+2]+sd2));
    const short* sr = hh + (size_t)src*192;
    a0 += q0*b2f(sr[lane]); a1 += q1*b2f(sr[64+lane]); a2 += q2*b2f(sr[128+lane]);
    d0 += q0; d1 += q1; d2 += q2;
  }
  float v0 = a0/d0 + bias[lane];
  float v1 = a1/d1 + bias[64+lane];
  float v2 = a2/d2 + bias[128+lane];
  short* orow = out + (size_t)dst*192;
  orow[lane]      = f2bf(v0 > 0.f ? v0 : 0.f);
  orow[64+lane]   = f2bf(v1 > 0.f ? v1 : 0.f);
  orow[128+lane]  = f2bf(v2 > 0.f ? v2 : 0.f);
}

// ==================== GAT2/3 gather (hh23 bf16 [N][64]: cols 0-29 = h2, 32-61 = h3) ====================
__global__ __launch_bounds__(256) void gat23_gather(const int* __restrict__ offs, const int* __restrict__ csr,
    const short* __restrict__ hh23,
    const float* __restrict__ s2s, const float* __restrict__ s2d,
    const float* __restrict__ s3s, const float* __restrict__ s3d,
    const float* __restrict__ b2, const float* __restrict__ b3,
    float* __restrict__ zs, float* __restrict__ mus, float* __restrict__ lvs,
    short* __restrict__ zbf, int n){
  int w = threadIdx.x >> 6, lane = threadIdx.x & 63;
  int dst = blockIdx.x*4 + w;
  if (dst >= n) return;
  bool lo = lane < 32;
  int c = lane & 31;
  bool valid = c < 30;
  float sdA = s2d[dst], sdB = s3d[dst];
  float sdx = lo ? sdA : sdB;
  const float* ssx = lo ? s2s : s3s;
  float p2 = __expf(lrelu(s2s[dst]+sdA));
  float p3 = __expf(lrelu(s3s[dst]+sdB));
  float val = valid ? b2f(hh23[(size_t)dst*64+lane]) : 0.f;
  float acc = (lo ? p2 : p3) * val;
  float den2 = p2, den3 = p3;
  int p = offs[dst], pe = offs[dst+1];
  int n0=0,n1=0,n2=0,n3=0;
  if (p+4 <= pe){ n0=csr[p]; n1=csr[p+1]; n2=csr[p+2]; n3=csr[p+3]; }
  while (p+4 <= pe){
    int s0=n0, s1=n1, s2i=n2, s3i=n3;
    int pn = p+4;
    if (pn+4 <= pe){ n0=csr[pn]; n1=csr[pn+1]; n2=csr[pn+2]; n3=csr[pn+3]; }
    float eA0=ssx[s0], eA1=ssx[s1], eA2=ssx[s2i], eA3=ssx[s3i];
    float f20=s2s[s0], f21=s2s[s1], f22=s2s[s2i], f23=s2s[s3i];
    float f30=s3s[s0], f31=s3s[s1], f32=s3s[s2i], f33=s3s[s3i];
    float v0 = valid ? b2f(hh23[(size_t)s0*64+lane]) : 0.f;
    float v1 = valid ? b2f(hh23[(size_t)s1*64+lane]) : 0.f;
    float v2 = valid ? b2f(hh23[(size_t)s2i*64+lane]) : 0.f;
    float v3 = valid ? b2f(hh23[(size_t)s3i*64+lane]) : 0.f;
    float qx0=__expf(lrelu(eA0+sdx)), qx1=__expf(lrelu(eA1+sdx));
    float qx2=__expf(lrelu(eA2+sdx)), qx3=__expf(lrelu(eA3+sdx));
    acc += qx0*v0 + qx1*v1 + qx2*v2 + qx3*v3;
    den2 += __expf(lrelu(f20+sdA)) + __expf(lrelu(f21+sdA)) + __expf(lrelu(f22+sdA)) + __expf(lrelu(f23+sdA));
    den3 += __expf(lrelu(f30+sdB)) + __expf(lrelu(f31+sdB)) + __expf(lrelu(f32+sdB)) + __expf(lrelu(f33+sdB));
    p = pn;
  }
  for (; p < pe; ++p){
    int src = csr[p];
    float q2 = __expf(lrelu(s2s[src]+sdA));
    float q3 = __expf(lrelu(s3s[src]+sdB));
    float v = valid ? b2f(hh23[(size_t)src*64+lane]) : 0.f;
    acc += (lo ? q2 : q3) * v;
    den2 += q2; den3 += q3;
  }
  if (lo){
    if (valid){
      float v = acc/den2 + b2[c];
      zs[(size_t)dst*30+c]  = v;
      mus[(size_t)dst*30+c] = v;
      zbf[(size_t)dst*32+c] = f2bf(v);
    } else {
      zbf[(size_t)dst*32+c] = 0;
    }
  } else if (valid){
    lvs[(size_t)dst*30+c] = acc/den3 + b3[c];
  }
}

// ==================== host ====================
static inline int cdiv(int a, int b){ return (a + b - 1) / b; }

extern "C" void kernel_launch(void* const* d_in, const int* in_sizes, int n_in,
                              void* d_out, int out_size, void* d_ws, size_t ws_size,
                              hipStream_t stream)
{
  const float* x        = (const float*)d_in[0];
  const int*   ei       = (const int*)  d_in[1];
  const float* enc_w1   = (const float*)d_in[2];
  const float* enc_g1   = (const float*)d_in[4];
  const float* enc_bt1  = (const float*)d_in[5];
  const float* enc_w2   = (const float*)d_in[6];
  const float* enc_g2   = (const float*)d_in[8];
  const float* enc_bt2  = (const float*)d_in[9];
  const float* gat1_w   = (const float*)d_in[10];
  const float* gat1_as  = (const float*)d_in[11];
  const float* gat1_ad  = (const float*)d_in[12];
  const float* gat1_b   = (const float*)d_in[13];
  const float* gat2_w   = (const float*)d_in[14];
  const float* gat2_as  = (const float*)d_in[15];
  const float* gat2_ad  = (const float*)d_in[16];
  const float* gat2_b   = (const float*)d_in[17];
  const float* gat3_w   = (const float*)d_in[18];
  const float* gat3_as  = (const float*)d_in[19];
  const float* gat3_ad  = (const float*)d_in[20];
  const float* gat3_b   = (const float*)d_in[21];
  const float* dec_w1   = (const float*)d_in[22];
  const float* dec_g1   = (const float*)d_in[24];
  const float* dec_bt1  = (const float*)d_in[25];
  const float* dec_w2   = (const float*)d_in[26];
  const float* dec_g2   = (const float*)d_in[28];
  const float* dec_bt2  = (const float*)d_in[29];
  const float* dec_w3   = (const float*)d_in[30];
  const float* dec_b3   = (const float*)d_in[31];
  const float* clu_w1   = (const float*)d_in[32];
  const float* clu_g1   = (const float*)d_in[34];
  const float* clu_bt1  = (const float*)d_in[35];
  const float* clu_w2   = (const float*)d_in[36];
  const float* clu_b2   = (const float*)d_in[37];

  const int N = in_sizes[0] / 1000;
  const int E = in_sizes[1] / 2;
  const int* e_src = ei;
  const int* e_dst = ei + E;
  const float invN = 1.f/(float)N;

  float* out  = (float*)d_out;
  float* pred = out;
  float* xrec = out + (size_t)N*10;
  float* zs   = xrec + (size_t)N*1000;
  float* mus  = zs  + (size_t)N*30;
  float* lvs  = mus + (size_t)N*30;

  char* ws = (char*)d_ws;
  size_t off = 0;
  auto alloc = [&](size_t bytes)->char*{
    char* p = ws + off;
    off = (off + bytes + 255) & ~(size_t)255;
    return p;
  };
  short* t_enc1  = (short*)alloc(256*1024*2);
  short* t_enc2  = (short*)alloc(128*256*2);
  short* t_gat1  = (short*)alloc(256*128*2);
  short* t_gat23 = (short*)alloc(64*192*2);
  short* t_dc1   = (short*)alloc(256*32*2);
  short* t_dec2  = (short*)alloc(256*128*2);
  short* t_dec3  = (short*)alloc(1024*256*2);
  short* t_clu2  = (short*)alloc(32*128*2);
  float* h1f  = (float*)alloc((size_t)N*256*4);
  short* h1b  = (short*)alloc((size_t)N*256*2);   // xb alias start
  float* h2f  = (float*)alloc((size_t)N*128*4);
  short* h2b  = (short*)alloc((size_t)N*128*2);
  short* hh1b = (short*)alloc((size_t)N*192*2);
  short* h3b  = (short*)alloc((size_t)N*192*2);
  float* hh23f= (float*)alloc((size_t)N*64*4);
  short* zbf  = (short*)alloc((size_t)N*32*2);
  // stats + gat1 scores: one contiguous zeroed region
  float* stats= (float*)alloc((2048 + (size_t)6*N)*4);
  float* ss1  = stats + 2048;
  float* sd1  = ss1 + (size_t)3*N;
  float* s2s  = (float*)alloc((size_t)N*4);
  float* s2d  = (float*)alloc((size_t)N*4);
  float* s3s  = (float*)alloc((size_t)N*4);
  float* s3d  = (float*)alloc((size_t)N*4);
  int*   deg  = (int*)alloc((size_t)(N+1)*4);
  int*   offs = (int*)alloc((size_t)(N+1)*4);
  int*   curp = (int*)alloc((size_t)(N+1)*4);
  int*   bsum = (int*)alloc(256*4);
  int*   csr  = (int*)alloc((size_t)E*4);
  // aliases (lifetimes):
  short* xb     = h1b;               // spans h1b..h3b (102.4MB >= 100MB); dead after enc1 gemm
  short* h1pre  = (short*)h1f;       // [N][256] bf16 pre-act; dead after enc1 apply
  short* h2pre  = (short*)h2f;       // [N][128] bf16 pre-act; dead after enc2 apply
  short* hh23b  = (short*)hh23f;     // [N][64] bf16
  short* dc1pre = (short*)h2f;       // [N][256] bf16 spans h2f+h2b (38.4MB >= 25.6MB); after gat1_gather
  short* d1b    = h3b;               // [N][128] bf16; h3b dead after gat23 gemm
  short* c1b    = hh1b;              // [N][128] bf16; hh1b dead after gat1_gather (25.6<=19.2? NO)
  // c1b needs 12.8MB; hh1b is 19.2MB ✓
  short* d2pre  = (short*)h1f;       // [N][256] bf16; h1pre dead after enc1 apply
  short* d2b    = h1b;               // [N][256] bf16; h1b dead after enc2 gemm
  float* st_enc1 = stats, *st_enc2 = stats+512, *st_dc1 = stats+768, *st_dec2 = stats+1280;

  // --- weight prep + zeroing ---
  WTab tab;
  tab.e[0]  = {enc_w1, t_enc1, 1000, 256, 1024, 256};
  tab.e[1]  = {enc_w2, t_enc2, 256, 128, 256, 128};
  tab.e[2]  = {gat1_w, t_gat1, 128, 192, 128, 256};
  tab.e[3]  = {gat2_w, t_gat23, 192, 30, 192, 32};
  tab.e[4]  = {gat3_w, t_gat23 + 32*192, 192, 30, 192, 32};
  tab.e[5]  = {dec_w1, t_dc1, 30, 128, 32, 128};
  tab.e[6]  = {clu_w1, t_dc1 + 128*32, 30, 128, 32, 128};
  tab.e[7]  = {dec_w2, t_dec2, 128, 256, 128, 256};
  tab.e[8]  = {dec_w3, t_dec3, 256, 1000, 256, 1024};
  tab.e[9]  = {clu_w2, t_clu2, 128, 10, 128, 32};
  wtrans_all<<<dim3(1024, 10), 256, 0, stream>>>(tab);
  hipMemsetAsync(stats, 0, (2048 + (size_t)6*N)*4, stream);
  hipMemsetAsync(deg, 0, (size_t)(N+1)*4, stream);

  // --- CSR ---
  hist_kernel<<<cdiv(E,256), 256, 0, stream>>>(e_dst, E, deg);
  int nb = cdiv(N, 1024);
  scan1<<<nb, 256, 0, stream>>>(deg, offs, bsum, N);
  scan3<<<cdiv(N,256), 256, 0, stream>>>(offs, bsum, curp, N, E);
  scatter_kernel<<<cdiv(E,256), 256, 0, stream>>>(e_src, e_dst, E, curp, csr);

  const int MB = cdiv(N, 128);   // 391

  // --- encoder L1 ---
  cvt_x<<<cdiv(N,2), 256, 0, stream>>>(x, xb, N);
  gemm_g<128,true,true,false,false,false><<<MB*2, 256, 0, stream>>>(
      xb, 1000, t_enc1, 1024, h1pre, 256, nullptr, N, 256, 1000, 2,
      st_enc1, st_enc1+256, nullptr,nullptr,nullptr,nullptr, nullptr,nullptr,nullptr,nullptr);
  bn_elu_apply2<256><<<2048, 256, 0, stream>>>(h1pre, h1b, N, invN, st_enc1, st_enc1+256, enc_g1, enc_bt1);

  // --- encoder L2 ---
  gemm_g<128,true,true,false,false,false><<<MB, 256, 0, stream>>>(
      h1b, 256, t_enc2, 256, h2pre, 128, nullptr, N, 128, 256, 1,
      st_enc2, st_enc2+128, nullptr,nullptr,nullptr,nullptr, nullptr,nullptr,nullptr,nullptr);
  bn_elu_apply2<128><<<2048, 256, 0, stream>>>(h2pre, h2b, N, invN, st_enc2, st_enc2+128, enc_g2, enc_bt2);

  // --- GAT1 (scores folded into epilogue; head = col-tile) ---
  gemm_g<64,true,false,false,false,true><<<MB*3, 256, 0, stream>>>(
      h2b, 128, t_gat1, 128, hh1b, 192, nullptr, N, 192, 128, 3,
      nullptr,nullptr, ss1,sd1,nullptr,nullptr, gat1_as,gat1_ad,nullptr,nullptr);
  gat1_gather_bf<<<cdiv(N,4), 256, 0, stream>>>(offs, csr, hh1b, ss1, sd1, gat1_b, h3b, N);

  // --- GAT2+GAT3 (combined weights; scores folded; bf16 out) ---
  gemm_g<64,true,false,false,true,false><<<MB, 256, 0, stream>>>(
      h3b, 192, t_gat23, 192, hh23b, 64, nullptr, N, 64, 192, 1,
      nullptr,nullptr, s2s,s2d,s3s,s3d, gat2_as,gat2_ad,gat3_as,gat3_ad);
  gat23_gather<<<cdiv(N,4), 256, 0, stream>>>(offs, csr, hh23b, s2s, s2d, s3s, s3d, gat2_b, gat3_b, zs, mus, lvs, zbf, N);

  // --- dec1 + clu1 combined ---
  gemm_g<128,true,true,false,false,false><<<MB*2, 256, 0, stream>>>(
      zbf, 32, t_dc1, 32, dc1pre, 256, nullptr, N, 256, 32, 2,
      st_dc1, st_dc1+256, nullptr,nullptr,nullptr,nullptr, nullptr,nullptr,nullptr,nullptr);
  bn_elu_split<<<2048, 256, 0, stream>>>(dc1pre, d1b, c1b, N, invN, st_dc1, st_dc1+256, dec_g1, dec_bt1, clu_g1, clu_bt1);

  // --- dec2 ---
  gemm_g<128,true,true,false,false,false><<<MB*2, 256, 0, stream>>>(
      d1b, 128, t_dec2, 128, d2pre, 256, nullptr, N, 256, 128, 2,
      st_dec2, st_dec2+256, nullptr,nullptr,nullptr,nullptr, nullptr,nullptr,nullptr,nullptr);
  bn_elu_apply2<256><<<2048, 256, 0, stream>>>(d2pre, d2b, N, invN, st_dec2, st_dec2+256, dec_g2, dec_bt2);

  // --- dec3 (8 col-tiles share A panel via swizzle) ---
  gemm_g<128,false,false,false,false,false><<<MB*8, 256, 0, stream>>>(
      d2b, 256, t_dec3, 256, xrec, 1000, dec_b3, N, 1000, 256, 8,
      nullptr,nullptr, nullptr,nullptr,nullptr,nullptr, nullptr,nullptr,nullptr,nullptr);

  // --- clu2 + fused softmax ---
  gemm_g<32,false,false,true,false,false><<<MB, 256, 0, stream>>>(
      c1b, 128, t_clu2, 128, pred, 10, clu_b2, N, 10, 128, 1,
      nullptr,nullptr, nullptr,nullptr,nullptr,nullptr, nullptr,nullptr,nullptr,nullptr);
}

// Round 10
// 629.524 us; speedup vs baseline: 1.2642x; 1.0051x over previous
//
#include <hip/hip_runtime.h>
#include <hip/hip_bf16.h>

typedef short short8 __attribute__((ext_vector_type(8)));
typedef short short4v __attribute__((ext_vector_type(4)));
typedef float f32x4 __attribute__((ext_vector_type(4)));

static __device__ __forceinline__ short f2bf(float f){
  __hip_bfloat16 h = __float2bfloat16(f);
  return __builtin_bit_cast(short, h);
}
static __device__ __forceinline__ float b2f(short s){
  unsigned int u = ((unsigned int)(unsigned short)s) << 16;
  return __builtin_bit_cast(float, u);
}
static __device__ __forceinline__ float lrelu(float x){ return x > 0.f ? x : 0.2f*x; }
static __device__ __forceinline__ float eluf(float x){ return x > 0.f ? x : (__expf(x)-1.f); }
static __device__ __forceinline__ int imin(int a,int b){ return a<b?a:b; }

typedef const __attribute__((address_space(1))) void as1_void;
typedef __attribute__((address_space(3))) void as3_void;
static __device__ __forceinline__ void gload16(const void* g, void* l){
  __builtin_amdgcn_global_load_lds((as1_void*)g, (as3_void*)l, 16, 0, 0);
}
template<int NN> __device__ __forceinline__ void wait_vm(){
  if constexpr (NN==0) asm volatile("s_waitcnt vmcnt(0)" ::: "memory");
  else if constexpr (NN==3) asm volatile("s_waitcnt vmcnt(3)" ::: "memory");
  else if constexpr (NN==4) asm volatile("s_waitcnt vmcnt(4)" ::: "memory");
  else if constexpr (NN==6) asm volatile("s_waitcnt vmcnt(6)" ::: "memory");
  else if constexpr (NN==8) asm volatile("s_waitcnt vmcnt(8)" ::: "memory");
  else asm volatile("s_waitcnt vmcnt(0)" ::: "memory");
}

// ==================== GEMM core (R4/R8-validated inner loop, body extracted verbatim) ====================
// A bf16 [M][lda]; Bt bf16 [NR][ldb] zero-padded. B zero for k in [K, ceil32(K)).
template<int BN, bool OBF16, bool CST, bool SMAX, bool G23S, bool G1S>
static __device__ __forceinline__ void gemm_core(int wg, short* lds,
    const short* __restrict__ A, int lda, const short* __restrict__ Bt, int ldb,
    void* __restrict__ Cv, int ldc, const float* __restrict__ bias,
    int M, int N, int K, int nbn,
    float* __restrict__ o_sum, float* __restrict__ o_sq,
    float* __restrict__ s2s, float* __restrict__ s2d,
    float* __restrict__ s3s, float* __restrict__ s3d,
    const float* __restrict__ a2s, const float* __restrict__ a2d,
    const float* __restrict__ a3s, const float* __restrict__ a3d)
{
  constexpr int BM = 128, BK = 32, GPR = 4;
  constexpr int WM = BM/2, WN = BN/2;
  constexpr int FM = WM/16, FN = WN/16;
  constexpr int AI = (BM*GPR)/(4*64);
  constexpr int BI_T = (BN*GPR)/64;
  constexpr bool BDUP = (BI_T < 4);
  constexpr int BI = BDUP ? BI_T : BI_T/4;
  constexpr int LPT = AI + BI;
  constexpr int TS = (BM+BN)*BK;

  const int tid = threadIdx.x, wid = tid>>6, lane = tid&63;
  const int wm = wid>>1, wn = wid&1;
  int bmt = wg / nbn, bnt = wg - bmt*nbn;
  const int bm = bmt*BM, bn = bnt*BN;
  const int lr = lane&15, lg = lane>>4;
  const int nt = (K + BK - 1)/BK;

  f32x4 acc[FM][FN] = {};

  auto STAGE = [&](int t){
    int buf = t & 3, k0 = t*BK;
    #pragma unroll
    for (int i=0;i<AI;i++){
      int ci = wid*AI + i;
      int c = ci*64 + lane;
      int row = c>>2, g = c&3;
      int gr = imin(bm+row, M-1);
      const short* src = A + (size_t)gr*lda + k0 + ((g ^ (row&3))<<3);
      gload16(src, &lds[buf*TS + ci*512]);
    }
    #pragma unroll
    for (int i=0;i<BI;i++){
      int bi = BDUP ? i : wid*BI + i;
      int c = bi*64 + lane;
      int row = c>>2, g = c&3;
      const short* src = Bt + (size_t)(bn+row)*ldb + k0 + ((g ^ (row&3))<<3);
      gload16(src, &lds[buf*TS + BM*BK + bi*512]);
    }
  };

  for (int s=0; s<3 && s<nt; ++s) STAGE(s);

  for (int t=0; t<nt; ++t){
    int newer = imin(nt, t+3) - t - 1;
    if (newer >= 2) wait_vm<2*LPT>();
    else if (newer == 1) wait_vm<LPT>();
    else wait_vm<0>();
    __builtin_amdgcn_s_barrier();
    __builtin_amdgcn_sched_barrier(0);
    if (t+3 < nt) STAGE(t+3);
    int buf = t & 3;
    short8 af[FM], bf[FN];
    #pragma unroll
    for (int m=0;m<FM;m++){
      int r = wm*WM + m*16 + lr;
      af[m] = *(short8*)&lds[buf*TS + r*BK + ((lg ^ (r&3))<<3)];
    }
    #pragma unroll
    for (int n=0;n<FN;n++){
      int r = wn*WN + n*16 + lr;
      bf[n] = *(short8*)&lds[buf*TS + BM*BK + r*BK + ((lg ^ (r&3))<<3)];
    }
    #pragma unroll
    for (int m=0;m<FM;m++)
      #pragma unroll
      for (int n=0;n<FN;n++)
        acc[m][n] = __builtin_amdgcn_mfma_f32_16x16x32_bf16(af[m], bf[n], acc[m][n], 0, 0, 0);
  }

  if (SMAX){
    #pragma unroll
    for (int m=0;m<FM;m++)
      #pragma unroll
      for (int q=0;q<4;q++){
        int row = bm + wm*WM + m*16 + lg*4 + q;
        float v = (lr < 10) ? (acc[m][0][q] + bias[lr]) : -3e38f;
        float mx = v;
        #pragma unroll
        for (int d=1; d<16; d<<=1) mx = fmaxf(mx, __shfl_xor(mx, d));
        float e = (lr < 10) ? __expf(v - mx) : 0.f;
        float sm = e;
        #pragma unroll
        for (int d=1; d<16; d<<=1) sm += __shfl_xor(sm, d);
        if (wn == 0 && lr < 10 && row < M)
          ((float*)Cv)[(size_t)row*10 + lr] = e/sm;
      }
    return;
  }

  #pragma unroll
  for (int m=0;m<FM;m++)
    #pragma unroll
    for (int n=0;n<FN;n++)
      #pragma unroll
      for (int q=0;q<4;q++){
        int row = bm + wm*WM + m*16 + lg*4 + q;
        int col = bn + wn*WN + n*16 + lr;
        if (row < M && col < N){
          float v = acc[m][n][q];
          if (bias) v += bias[col];
          if (OBF16) ((short*)Cv)[(size_t)row*ldc + col] = f2bf(v);
          else       ((float*)Cv)[(size_t)row*ldc + col] = v;
        }
      }

  if (G1S){
    int h = bnt;
    float a_s[FN], a_d[FN];
    #pragma unroll
    for (int n=0;n<FN;n++){
      int cl = wn*WN + n*16 + lr;
      a_s[n] = a2s[h*64 + cl];
      a_d[n] = a2d[h*64 + cl];
    }
    #pragma unroll
    for (int m=0;m<FM;m++)
      #pragma unroll
      for (int q=0;q<4;q++){
        int row = bm + wm*WM + m*16 + lg*4 + q;
        float ps = 0.f, pd = 0.f;
        #pragma unroll
        for (int n=0;n<FN;n++){ ps += acc[m][n][q]*a_s[n]; pd += acc[m][n][q]*a_d[n]; }
        #pragma unroll
        for (int d=1; d<16; d<<=1){ ps += __shfl_xor(ps, d); pd += __shfl_xor(pd, d); }
        if (lr == 0 && row < M){
          atomicAdd(&s2s[row*3+h], ps);
          atomicAdd(&s2d[row*3+h], pd);
        }
      }
  }

  if (G23S){
    float a_s[FN], a_d[FN];
    #pragma unroll
    for (int n=0;n<FN;n++){
      int cl = n*16 + lr;
      bool valid = cl < 30;
      a_s[n] = valid ? (wn ? a3s[cl] : a2s[cl]) : 0.f;
      a_d[n] = valid ? (wn ? a3d[cl] : a2d[cl]) : 0.f;
    }
    #pragma unroll
    for (int m=0;m<FM;m++)
      #pragma unroll
      for (int q=0;q<4;q++){
        int row = bm + wm*WM + m*16 + lg*4 + q;
        float ps = 0.f, pd = 0.f;
        #pragma unroll
        for (int n=0;n<FN;n++){ ps += acc[m][n][q]*a_s[n]; pd += acc[m][n][q]*a_d[n]; }
        #pragma unroll
        for (int d=1; d<16; d<<=1){ ps += __shfl_xor(ps, d); pd += __shfl_xor(pd, d); }
        if (lr == 0 && row < M){
          if (wn){ s3s[row] = ps; s3d[row] = pd; }
          else   { s2s[row] = ps; s2d[row] = pd; }
        }
      }
  }

  if (CST){
    #pragma unroll
    for (int n=0;n<FN;n++){
      float s = 0.f, q2 = 0.f;
      #pragma unroll
      for (int m=0;m<FM;m++)
        #pragma unroll
        for (int q=0;q<4;q++){
          int row = bm + wm*WM + m*16 + lg*4 + q;
          if (row < M){ float v = acc[m][n][q]; s += v; q2 += v*v; }
        }
      s  += __shfl_xor(s, 16);  s += __shfl_xor(s, 32);
      q2 += __shfl_xor(q2, 16); q2 += __shfl_xor(q2, 32);
      if (lg == 0){
        int col = bn + wn*WN + n*16 + lr;
        if (col < N){ atomicAdd(&o_sum[col], s); atomicAdd(&o_sq[col], q2); }
      }
    }
  }
}

static __device__ __forceinline__ int xcd_swz(int bid, int nwg){
  int q8 = nwg >> 3, r8 = nwg & 7;
  int xcd = bid & 7, pos = bid >> 3;
  return (xcd < r8 ? xcd*(q8+1) : r8*(q8+1) + (xcd-r8)*q8) + pos;
}

template<int BN, bool OBF16, bool CST, bool SMAX, bool G23S, bool G1S>
__global__ __launch_bounds__(256) void gemm_g(
    const short* __restrict__ A, int lda, const short* __restrict__ Bt, int ldb,
    void* __restrict__ Cv, int ldc, const float* __restrict__ bias,
    int M, int N, int K, int nbn,
    float* __restrict__ o_sum, float* __restrict__ o_sq,
    float* __restrict__ s2s, float* __restrict__ s2d,
    float* __restrict__ s3s, float* __restrict__ s3d,
    const float* __restrict__ a2s, const float* __restrict__ a2d,
    const float* __restrict__ a3s, const float* __restrict__ a3d)
{
  __shared__ short lds[4*(128+BN)*32];
  int wg = xcd_swz(blockIdx.x, gridDim.x);
  gemm_core<BN,OBF16,CST,SMAX,G23S,G1S>(wg, lds, A, lda, Bt, ldb, Cv, ldc, bias,
      M, N, K, nbn, o_sum, o_sq, s2s, s2d, s3s, s3d, a2s, a2d, a3s, a3d);
}

// dec3 (plain, BN=128) + clu2 (SMAX, BN=32) in one dispatch
__global__ __launch_bounds__(256) void gemm_dual(
    const short* __restrict__ A1, int lda1, const short* __restrict__ B1, int ldb1,
    void* __restrict__ C1, int ldc1, const float* __restrict__ bias1, int N1, int K1,
    const short* __restrict__ A2, int lda2, const short* __restrict__ B2, int ldb2,
    void* __restrict__ C2, const float* __restrict__ bias2, int N2, int K2,
    int M, int split)
{
  __shared__ short lds[4*(128+128)*32];
  int wg = xcd_swz(blockIdx.x, gridDim.x);
  if (wg < split){
    gemm_core<128,false,false,false,false,false>(wg, lds, A1, lda1, B1, ldb1, C1, ldc1, bias1,
        M, N1, K1, 8, nullptr,nullptr, nullptr,nullptr,nullptr,nullptr, nullptr,nullptr,nullptr,nullptr);
  } else {
    gemm_core<32,false,false,true,false,false>(wg - split, lds, A2, lda2, B2, ldb2, C2, 10, bias2,
        M, N2, K2, 1, nullptr,nullptr, nullptr,nullptr,nullptr,nullptr, nullptr,nullptr,nullptr,nullptr);
  }
}

// ==================== cvt_x + hist merged ====================
__global__ __launch_bounds__(256) void cvt_hist(const float* __restrict__ x, short* __restrict__ xb, int M,
                                                int CB, const int* __restrict__ d, int E, int* __restrict__ deg){
  int b = blockIdx.x;
  if (b < CB){
    int row = b*2 + (threadIdx.x>>7);
    int c8  = (threadIdx.x&127)*8;
    if (row >= M || c8 >= 1000) return;
    const float* p = x + (size_t)row*1000 + c8;
    float4 f0 = *(const float4*)p, f1 = *(const float4*)(p+4);
    short8 o;
    o[0]=f2bf(f0.x);o[1]=f2bf(f0.y);o[2]=f2bf(f0.z);o[3]=f2bf(f0.w);
    o[4]=f2bf(f1.x);o[5]=f2bf(f1.y);o[6]=f2bf(f1.z);o[7]=f2bf(f1.w);
    *(short8*)&xb[(size_t)row*1000 + c8] = o;
  } else {
    int i = (b - CB)*256 + threadIdx.x;
    if (i < E) atomicAdd(&deg[d[i]], 1);
  }
}

// ==================== weight transpose/convert ====================
struct WEnt { const float* src; short* dst; int K, N, KP, NR; };
struct WTab { WEnt e[10]; };
__global__ __launch_bounds__(256) void wtrans_all(WTab tab){
  WEnt w = tab.e[blockIdx.y];
  int gid = blockIdx.x*256 + threadIdx.x;
  if (gid >= w.NR * w.KP) return;
  int n = gid / w.KP, k = gid - n*w.KP;
  float v = (k < w.K && n < w.N) ? w.src[(size_t)k*w.N + n] : 0.f;
  w.dst[gid] = f2bf(v);
}

// ==================== BN (finalize folded) + ELU: bf16 in -> bf16 out ====================
template<int C>
__global__ __launch_bounds__(256) void bn_elu_apply2(const short* __restrict__ H, short* __restrict__ O,
    int M, float invM,
    const float* __restrict__ ssum, const float* __restrict__ ssq,
    const float* __restrict__ g, const float* __restrict__ bt){
  __shared__ float sc[C], sh[C];
  for (int c = threadIdx.x; c < C; c += 256){
    float mn  = ssum[c]*invM;
    float var = ssq[c]*invM - mn*mn;
    float s = g[c]*rsqrtf(var + 1e-5f);
    sc[c] = s; sh[c] = bt[c] - mn*s;
  }
  __syncthreads();
  int total8 = M*(C/8);
  for (int i = blockIdx.x*256+threadIdx.x; i < total8; i += gridDim.x*256){
    short8 v = ((const short8*)H)[i];
    int cb = (i*8) & (C-1);
    short8 o;
    #pragma unroll
    for (int j=0;j<8;j++) o[j] = f2bf(eluf(b2f(v[j])*sc[cb+j]+sh[cb+j]));
    ((short8*)O)[i] = o;
  }
}

__global__ __launch_bounds__(256) void bn_elu_split(const short* __restrict__ H,
    short* __restrict__ Od, short* __restrict__ Oc, int M, float invM,
    const float* __restrict__ ssum, const float* __restrict__ ssq,
    const float* __restrict__ gd, const float* __restrict__ btd,
    const float* __restrict__ gc, const float* __restrict__ btc){
  __shared__ float sc[256], sh[256];
  {
    int c = threadIdx.x;
    float mn  = ssum[c]*invM;
    float var = ssq[c]*invM - mn*mn;
    float gg = (c<128) ? gd[c] : gc[c-128];
    float bb = (c<128) ? btd[c] : btc[c-128];
    float s = gg*rsqrtf(var + 1e-5f);
    sc[c] = s; sh[c] = bb - mn*s;
  }
  __syncthreads();
  int total8 = M*32;
  for (int i = blockIdx.x*256+threadIdx.x; i < total8; i += gridDim.x*256){
    short8 v = ((const short8*)H)[i];
    int cb = (i*8) & 255;
    short8 o;
    #pragma unroll
    for (int j=0;j<8;j++) o[j] = f2bf(eluf(b2f(v[j])*sc[cb+j]+sh[cb+j]));
    int row = i>>5;
    short* O = (cb < 128) ? Od : Oc;
    *(short8*)&O[(size_t)row*128 + (cb&127)] = o;
  }
}

// ==================== CSR build ====================
__global__ __launch_bounds__(256) void scan1(const int* __restrict__ deg, int* __restrict__ offs,
                                             int* __restrict__ bsum, int n){
  __shared__ int sm[256];
  int tid = threadIdx.x;
  int base = blockIdx.x*1024 + tid*4;
  int v0 = base+0<n ? deg[base+0] : 0;
  int v1 = base+1<n ? deg[base+1] : 0;
  int v2 = base+2<n ? deg[base+2] : 0;
  int v3 = base+3<n ? deg[base+3] : 0;
  int ts = v0+v1+v2+v3;
  sm[tid] = ts;
  __syncthreads();
  #pragma unroll
  for (int d=1; d<256; d<<=1){
    int t = (tid>=d) ? sm[tid-d] : 0;
    __syncthreads();
    sm[tid] += t;
    __syncthreads();
  }
  int ex = sm[tid] - ts;
  if (base+0<n) offs[base+0] = ex;
  if (base+1<n) offs[base+1] = ex+v0;
  if (base+2<n) offs[base+2] = ex+v0+v1;
  if (base+3<n) offs[base+3] = ex+v0+v1+v2;
  if (tid==255) bsum[blockIdx.x] = sm[255];
}
__global__ __launch_bounds__(256) void scan3(int* __restrict__ offs, const int* __restrict__ bsum,
                      int* __restrict__ cursor, int n, int total){
  __shared__ int base_sm;
  int tgt = blockIdx.x >> 2;
  if (threadIdx.x < 64){
    int j = threadIdx.x;
    int v = (j < tgt) ? bsum[j] : 0;
    #pragma unroll
    for (int d=32; d; d>>=1) v += __shfl_xor(v, d);
    if (j == 0) base_sm = v;
  }
  __syncthreads();
  int i = blockIdx.x*256 + threadIdx.x;
  if (i < n){ int v = offs[i] + base_sm; offs[i]=v; cursor[i]=v; }
  if (i == 0) offs[n] = total;
}
__global__ void scatter_kernel(const int* __restrict__ s, const int* __restrict__ d, int E,
                               int* __restrict__ cursor, int* __restrict__ csr){
  int i = blockIdx.x*256 + threadIdx.x;
  if (i < E){ int pos = atomicAdd(&cursor[d[i]], 1); csr[pos] = s[i]; }
}

// ==================== GAT1 gather ====================
__global__ __launch_bounds__(256) void gat1_gather_bf(const int* __restrict__ offs, const int* __restrict__ csr,
    const short* __restrict__ hh, const float* __restrict__ ss, const float* __restrict__ sd,
    const float* __restrict__ bias, short* __restrict__ out, int n){
  int w = threadIdx.x >> 6, lane = threadIdx.x & 63;
  int dst = blockIdx.x*4 + w;
  if (dst >= n) return;
  float sd0 = sd[dst*3+0], sd1 = sd[dst*3+1], sd2 = sd[dst*3+2];
  float p0 = __expf(lrelu(ss[dst*3+0]+sd0));
  float p1 = __expf(lrelu(ss[dst*3+1]+sd1));
  float p2 = __expf(lrelu(ss[dst*3+2]+sd2));
  const short* hr = hh + (size_t)dst*192;
  float a0 = p0*b2f(hr[lane]), a1 = p1*b2f(hr[64+lane]), a2 = p2*b2f(hr[128+lane]);
  float d0 = p0, d1 = p1, d2 = p2;
  int p = offs[dst], pe = offs[dst+1];
  int n0=0,n1=0,n2=0,n3=0;
  if (p+4 <= pe){ n0=csr[p]; n1=csr[p+1]; n2=csr[p+2]; n3=csr[p+3]; }
  while (p+4 <= pe){
    int s0=n0, s1=n1, s2=n2, s3=n3;
    int pn = p+4;
    if (pn+4 <= pe){ n0=csr[pn]; n1=csr[pn+1]; n2=csr[pn+2]; n3=csr[pn+3]; }
    float e00=ss[s0*3+0], e01=ss[s0*3+1], e02=ss[s0*3+2];
    float e10=ss[s1*3+0], e11=ss[s1*3+1], e12=ss[s1*3+2];
    float e20=ss[s2*3+0], e21=ss[s2*3+1], e22=ss[s2*3+2];
    float e30=ss[s3*3+0], e31=ss[s3*3+1], e32=ss[s3*3+2];
    const short* r0 = hh + (size_t)s0*192;
    const short* r1 = hh + (size_t)s1*192;
    const short* r2 = hh + (size_t)s2*192;
    const short* r3 = hh + (size_t)s3*192;
    float v00=b2f(r0[lane]), v01=b2f(r0[64+lane]), v02=b2f(r0[128+lane]);
    float v10=b2f(r1[lane]), v11=b2f(r1[64+lane]), v12=b2f(r1[128+lane]);
    float v20=b2f(r2[lane]), v21=b2f(r2[64+lane]), v22=b2f(r2[128+lane]);
    float v30=b2f(r3[lane]), v31=b2f(r3[64+lane]), v32=b2f(r3[128+lane]);
    float q00=__expf(lrelu(e00+sd0)), q01=__expf(lrelu(e01+sd1)), q02=__expf(lrelu(e02+sd2));
    float q10=__expf(lrelu(e10+sd0)), q11=__expf(lrelu(e11+sd1)), q12=__expf(lrelu(e12+sd2));
    float q20=__expf(lrelu(e20+sd0)), q21=__expf(lrelu(e21+sd1)), q22=__expf(lrelu(e22+sd2));
    float q30=__expf(lrelu(e30+sd0)), q31=__expf(lrelu(e31+sd1)), q32=__expf(lrelu(e32+sd2));
    a0 += q00*v00 + q10*v10 + q20*v20 + q30*v30;
    a1 += q01*v01 + q11*v11 + q21*v21 + q31*v31;
    a2 += q02*v02 + q12*v12 + q22*v22 + q32*v32;
    d0 += q00+q10+q20+q30;
    d1 += q01+q11+q21+q31;
    d2 += q02+q12+q22+q32;
    p = pn;
  }
  for (; p < pe; ++p){
    int src = csr[p];
    float q0 = __expf(lrelu(ss[src*3+0]+sd0));
    float q1 = __expf(lrelu(ss[src*3+1]+sd1));
    float q2 = __expf(lrelu(ss[src*3+2]+sd2));
    const short* sr = hh + (size_t)src*192;
    a0 += q0*b2f(sr[lane]); a1 += q1*b2f(sr[64+lane]); a2 += q2*b2f(sr[128+lane]);
    d0 += q0; d1 += q1; d2 += q2;
  }
  float v0 = a0/d0 + bias[lane];
  float v1 = a1/d1 + bias[64+lane];
  float v2 = a2/d2 + bias[128+lane];
  short* orow = out + (size_t)dst*192;
  orow[lane]      = f2bf(v0 > 0.f ? v0 : 0.f);
  orow[64+lane]   = f2bf(v1 > 0.f ? v1 : 0.f);
  orow[128+lane]  = f2bf(v2 > 0.f ? v2 : 0.f);
}

// ==================== GAT2/3 gather (hh23 bf16 [N][64]) ====================
__global__ __launch_bounds__(256) void gat23_gather(const int* __restrict__ offs, const int* __restrict__ csr,
    const short* __restrict__ hh23,
    const float* __restrict__ s2s, const float* __restrict__ s2d,
    const float* __restrict__ s3s, const float* __restrict__ s3d,
    const float* __restrict__ b2, const float* __restrict__ b3,
    float* __restrict__ zs, float* __restrict__ mus, float* __restrict__ lvs,
    short* __restrict__ zbf, int n){
  int w = threadIdx.x >> 6, lane = threadIdx.x & 63;
  int dst = blockIdx.x*4 + w;
  if (dst >= n) return;
  bool lo = lane < 32;
  int c = lane & 31;
  bool valid = c < 30;
  float sdA = s2d[dst], sdB = s3d[dst];
  float sdx = lo ? sdA : sdB;
  const float* ssx = lo ? s2s : s3s;
  float p2 = __expf(lrelu(s2s[dst]+sdA));
  float p3 = __expf(lrelu(s3s[dst]+sdB));
  float val = valid ? b2f(hh23[(size_t)dst*64+lane]) : 0.f;
  float acc = (lo ? p2 : p3) * val;
  float den2 = p2, den3 = p3;
  int p = offs[dst], pe = offs[dst+1];
  int n0=0,n1=0,n2=0,n3=0;
  if (p+4 <= pe){ n0=csr[p]; n1=csr[p+1]; n2=csr[p+2]; n3=csr[p+3]; }
  while (p+4 <= pe){
    int s0=n0, s1=n1, s2i=n2, s3i=n3;
    int pn = p+4;
    if (pn+4 <= pe){ n0=csr[pn]; n1=csr[pn+1]; n2=csr[pn+2]; n3=csr[pn+3]; }
    float eA0=ssx[s0], eA1=ssx[s1], eA2=ssx[s2i], eA3=ssx[s3i];
    float f20=s2s[s0], f21=s2s[s1], f22=s2s[s2i], f23=s2s[s3i];
    float f30=s3s[s0], f31=s3s[s1], f32=s3s[s2i], f33=s3s[s3i];
    float v0 = valid ? b2f(hh23[(size_t)s0*64+lane]) : 0.f;
    float v1 = valid ? b2f(hh23[(size_t)s1*64+lane]) : 0.f;
    float v2 = valid ? b2f(hh23[(size_t)s2i*64+lane]) : 0.f;
    float v3 = valid ? b2f(hh23[(size_t)s3i*64+lane]) : 0.f;
    float qx0=__expf(lrelu(eA0+sdx)), qx1=__expf(lrelu(eA1+sdx));
    float qx2=__expf(lrelu(eA2+sdx)), qx3=__expf(lrelu(eA3+sdx));
    acc += qx0*v0 + qx1*v1 + qx2*v2 + qx3*v3;
    den2 += __expf(lrelu(f20+sdA)) + __expf(lrelu(f21+sdA)) + __expf(lrelu(f22+sdA)) + __expf(lrelu(f23+sdA));
    den3 += __expf(lrelu(f30+sdB)) + __expf(lrelu(f31+sdB)) + __expf(lrelu(f32+sdB)) + __expf(lrelu(f33+sdB));
    p = pn;
  }
  for (; p < pe; ++p){
    int src = csr[p];
    float q2 = __expf(lrelu(s2s[src]+sdA));
    float q3 = __expf(lrelu(s3s[src]+sdB));
    float v = valid ? b2f(hh23[(size_t)src*64+lane]) : 0.f;
    acc += (lo ? q2 : q3) * v;
    den2 += q2; den3 += q3;
  }
  if (lo){
    if (valid){
      float v = acc/den2 + b2[c];
      zs[(size_t)dst*30+c]  = v;
      mus[(size_t)dst*30+c] = v;
      zbf[(size_t)dst*32+c] = f2bf(v);
    } else {
      zbf[(size_t)dst*32+c] = 0;
    }
  } else if (valid){
    lvs[(size_t)dst*30+c] = acc/den3 + b3[c];
  }
}

// ==================== host ====================
static inline int cdiv(int a, int b){ return (a + b - 1) / b; }

extern "C" void kernel_launch(void* const* d_in, const int* in_sizes, int n_in,
                              void* d_out, int out_size, void* d_ws, size_t ws_size,
                              hipStream_t stream)
{
  const float* x        = (const float*)d_in[0];
  const int*   ei       = (const int*)  d_in[1];
  const float* enc_w1   = (const float*)d_in[2];
  const float* enc_g1   = (const float*)d_in[4];
  const float* enc_bt1  = (const float*)d_in[5];
  const float* enc_w2   = (const float*)d_in[6];
  const float* enc_g2   = (const float*)d_in[8];
  const float* enc_bt2  = (const float*)d_in[9];
  const float* gat1_w   = (const float*)d_in[10];
  const float* gat1_as  = (const float*)d_in[11];
  const float* gat1_ad  = (const float*)d_in[12];
  const float* gat1_b   = (const float*)d_in[13];
  const float* gat2_w   = (const float*)d_in[14];
  const float* gat2_as  = (const float*)d_in[15];
  const float* gat2_ad  = (const float*)d_in[16];
  const float* gat2_b   = (const float*)d_in[17];
  const float* gat3_w   = (const float*)d_in[18];
  const float* gat3_as  = (const float*)d_in[19];
  const float* gat3_ad  = (const float*)d_in[20];
  const float* gat3_b   = (const float*)d_in[21];
  const float* dec_w1   = (const float*)d_in[22];
  const float* dec_g1   = (const float*)d_in[24];
  const float* dec_bt1  = (const float*)d_in[25];
  const float* dec_w2   = (const float*)d_in[26];
  const float* dec_g2   = (const float*)d_in[28];
  const float* dec_bt2  = (const float*)d_in[29];
  const float* dec_w3   = (const float*)d_in[30];
  const float* dec_b3   = (const float*)d_in[31];
  const float* clu_w1   = (const float*)d_in[32];
  const float* clu_g1   = (const float*)d_in[34];
  const float* clu_bt1  = (const float*)d_in[35];
  const float* clu_w2   = (const float*)d_in[36];
  const float* clu_b2   = (const float*)d_in[37];

  const int N = in_sizes[0] / 1000;
  const int E = in_sizes[1] / 2;
  const int* e_src = ei;
  const int* e_dst = ei + E;
  const float invN = 1.f/(float)N;

  float* out  = (float*)d_out;
  float* pred = out;
  float* xrec = out + (size_t)N*10;
  float* zs   = xrec + (size_t)N*1000;
  float* mus  = zs  + (size_t)N*30;
  float* lvs  = mus + (size_t)N*30;

  char* ws = (char*)d_ws;
  size_t off = 0;
  auto alloc = [&](size_t bytes)->char*{
    char* p = ws + off;
    off = (off + bytes + 255) & ~(size_t)255;
    return p;
  };
  short* t_enc1  = (short*)alloc(256*1024*2);
  short* t_enc2  = (short*)alloc(128*256*2);
  short* t_gat1  = (short*)alloc(256*128*2);
  short* t_gat23 = (short*)alloc(64*192*2);
  short* t_dc1   = (short*)alloc(256*32*2);
  short* t_dec2  = (short*)alloc(256*128*2);
  short* t_dec3  = (short*)alloc(1024*256*2);
  short* t_clu2  = (short*)alloc(32*128*2);
  float* h1f  = (float*)alloc((size_t)N*256*4);
  short* h1b  = (short*)alloc((size_t)N*256*2);   // xb alias start
  float* h2f  = (float*)alloc((size_t)N*128*4);
  short* h2b  = (short*)alloc((size_t)N*128*2);
  short* hh1b = (short*)alloc((size_t)N*192*2);
  short* h3b  = (short*)alloc((size_t)N*192*2);
  float* hh23f= (float*)alloc((size_t)N*64*4);
  short* zbf  = (short*)alloc((size_t)N*32*2);
  // single zeroed region: stats(2048) | ss1(3N) | sd1(3N) | deg(N+1)
  size_t zcnt = 2048 + (size_t)6*N + (N+1);
  float* stats= (float*)alloc(zcnt*4);
  float* ss1  = stats + 2048;
  float* sd1  = ss1 + (size_t)3*N;
  int*   deg  = (int*)(sd1 + (size_t)3*N);
  float* s2s  = (float*)alloc((size_t)N*4);
  float* s2d  = (float*)alloc((size_t)N*4);
  float* s3s  = (float*)alloc((size_t)N*4);
  float* s3d  = (float*)alloc((size_t)N*4);
  int*   offs = (int*)alloc((size_t)(N+1)*4);
  int*   curp = (int*)alloc((size_t)(N+1)*4);
  int*   bsum = (int*)alloc(256*4);
  int*   csr  = (int*)alloc((size_t)E*4);
  // aliases (lifetimes):
  short* xb     = h1b;               // spans h1b..h3b (102.4MB >= 100MB); dead after enc1 gemm
  short* h1pre  = (short*)h1f;       // dead after enc1 apply
  short* h2pre  = (short*)h2f;       // dead after enc2 apply
  short* hh23b  = (short*)hh23f;
  short* dc1pre = (short*)h2f;       // spans h2f+h2b (38.4MB >= 25.6MB); after gat1_gather
  short* d1b    = h3b;               // h3b dead after gat23 gemm
  short* c1b    = hh1b;              // hh1b dead after gat1_gather (19.2MB >= 12.8MB)
  short* d2pre  = (short*)h1f;
  short* d2b    = h1b;
  float* st_enc1 = stats, *st_enc2 = stats+512, *st_dc1 = stats+768, *st_dec2 = stats+1280;

  // --- weight prep + single zeroing ---
  WTab tab;
  tab.e[0]  = {enc_w1, t_enc1, 1000, 256, 1024, 256};
  tab.e[1]  = {enc_w2, t_enc2, 256, 128, 256, 128};
  tab.e[2]  = {gat1_w, t_gat1, 128, 192, 128, 256};
  tab.e[3]  = {gat2_w, t_gat23, 192, 30, 192, 32};
  tab.e[4]  = {gat3_w, t_gat23 + 32*192, 192, 30, 192, 32};
  tab.e[5]  = {dec_w1, t_dc1, 30, 128, 32, 128};
  tab.e[6]  = {clu_w1, t_dc1 + 128*32, 30, 128, 32, 128};
  tab.e[7]  = {dec_w2, t_dec2, 128, 256, 128, 256};
  tab.e[8]  = {dec_w3, t_dec3, 256, 1000, 256, 1024};
  tab.e[9]  = {clu_w2, t_clu2, 128, 10, 128, 32};
  wtrans_all<<<dim3(1024, 10), 256, 0, stream>>>(tab);
  hipMemsetAsync(stats, 0, zcnt*4, stream);

  // --- cvt_x + hist merged ---
  int CB = cdiv(N, 2);
  cvt_hist<<<CB + cdiv(E,256), 256, 0, stream>>>(x, xb, N, CB, e_dst, E, deg);

  // --- CSR scan + scatter ---
  int nb = cdiv(N, 1024);
  scan1<<<nb, 256, 0, stream>>>(deg, offs, bsum, N);
  scan3<<<cdiv(N,256), 256, 0, stream>>>(offs, bsum, curp, N, E);
  scatter_kernel<<<cdiv(E,256), 256, 0, stream>>>(e_src, e_dst, E, curp, csr);

  const int MB = cdiv(N, 128);   // 391

  // --- encoder L1 ---
  gemm_g<128,true,true,false,false,false><<<MB*2, 256, 0, stream>>>(
      xb, 1000, t_enc1, 1024, h1pre, 256, nullptr, N, 256, 1000, 2,
      st_enc1, st_enc1+256, nullptr,nullptr,nullptr,nullptr, nullptr,nullptr,nullptr,nullptr);
  bn_elu_apply2<256><<<2048, 256, 0, stream>>>(h1pre, h1b, N, invN, st_enc1, st_enc1+256, enc_g1, enc_bt1);

  // --- encoder L2 ---
  gemm_g<128,true,true,false,false,false><<<MB, 256, 0, stream>>>(
      h1b, 256, t_enc2, 256, h2pre, 128, nullptr, N, 128, 256, 1,
      st_enc2, st_enc2+128, nullptr,nullptr,nullptr,nullptr, nullptr,nullptr,nullptr,nullptr);
  bn_elu_apply2<128><<<2048, 256, 0, stream>>>(h2pre, h2b, N, invN, st_enc2, st_enc2+128, enc_g2, enc_bt2);

  // --- GAT1 (scores folded; head = col-tile) ---
  gemm_g<64,true,false,false,false,true><<<MB*3, 256, 0, stream>>>(
      h2b, 128, t_gat1, 128, hh1b, 192, nullptr, N, 192, 128, 3,
      nullptr,nullptr, ss1,sd1,nullptr,nullptr, gat1_as,gat1_ad,nullptr,nullptr);
  gat1_gather_bf<<<cdiv(N,4), 256, 0, stream>>>(offs, csr, hh1b, ss1, sd1, gat1_b, h3b, N);

  // --- GAT2+GAT3 (combined weights; scores folded; bf16 out) ---
  gemm_g<64,true,false,false,true,false><<<MB, 256, 0, stream>>>(
      h3b, 192, t_gat23, 192, hh23b, 64, nullptr, N, 64, 192, 1,
      nullptr,nullptr, s2s,s2d,s3s,s3d, gat2_as,gat2_ad,gat3_as,gat3_ad);
  gat23_gather<<<cdiv(N,4), 256, 0, stream>>>(offs, csr, hh23b, s2s, s2d, s3s, s3d, gat2_b, gat3_b, zs, mus, lvs, zbf, N);

  // --- dec1 + clu1 combined ---
  gemm_g<128,true,true,false,false,false><<<MB*2, 256, 0, stream>>>(
      zbf, 32, t_dc1, 32, dc1pre, 256, nullptr, N, 256, 32, 2,
      st_dc1, st_dc1+256, nullptr,nullptr,nullptr,nullptr, nullptr,nullptr,nullptr,nullptr);
  bn_elu_split<<<2048, 256, 0, stream>>>(dc1pre, d1b, c1b, N, invN, st_dc1, st_dc1+256, dec_g1, dec_bt1, clu_g1, clu_bt1);

  // --- dec2 ---
  gemm_g<128,true,true,false,false,false><<<MB*2, 256, 0, stream>>>(
      d1b, 128, t_dec2, 128, d2pre, 256, nullptr, N, 256, 128, 2,
      st_dec2, st_dec2+256, nullptr,nullptr,nullptr,nullptr, nullptr,nullptr,nullptr,nullptr);
  bn_elu_apply2<256><<<2048, 256, 0, stream>>>(d2pre, d2b, N, invN, st_dec2, st_dec2+256, dec_g2, dec_bt2);

  // --- dec3 + clu2(softmax) in one dispatch ---
  gemm_dual<<<MB*8 + MB, 256, 0, stream>>>(
      d2b, 256, t_dec3, 256, xrec, 1000, dec_b3, 1000, 256,
      c1b, 128, t_clu2, 128, pred, clu_b2, 10, 128,
      N, MB*8);
}

// Round 11
// 616.004 us; speedup vs baseline: 1.2920x; 1.0219x over previous
//
#include <hip/hip_runtime.h>
#include <hip/hip_bf16.h>

typedef short short8 __attribute__((ext_vector_type(8)));
typedef short short4v __attribute__((ext_vector_type(4)));
typedef float f32x4 __attribute__((ext_vector_type(4)));

static __device__ __forceinline__ short f2bf(float f){
  __hip_bfloat16 h = __float2bfloat16(f);
  return __builtin_bit_cast(short, h);
}
static __device__ __forceinline__ float b2f(short s){
  unsigned int u = ((unsigned int)(unsigned short)s) << 16;
  return __builtin_bit_cast(float, u);
}
static __device__ __forceinline__ float lrelu(float x){ return x > 0.f ? x : 0.2f*x; }
static __device__ __forceinline__ float eluf(float x){ return x > 0.f ? x : (__expf(x)-1.f); }
static __device__ __forceinline__ int imin(int a,int b){ return a<b?a:b; }

typedef const __attribute__((address_space(1))) void as1_void;
typedef __attribute__((address_space(3))) void as3_void;
static __device__ __forceinline__ void gload16(const void* g, void* l){
  __builtin_amdgcn_global_load_lds((as1_void*)g, (as3_void*)l, 16, 0, 0);
}
template<int NN> __device__ __forceinline__ void wait_vm(){
  if constexpr (NN==0) asm volatile("s_waitcnt vmcnt(0)" ::: "memory");
  else if constexpr (NN==3) asm volatile("s_waitcnt vmcnt(3)" ::: "memory");
  else if constexpr (NN==4) asm volatile("s_waitcnt vmcnt(4)" ::: "memory");
  else if constexpr (NN==6) asm volatile("s_waitcnt vmcnt(6)" ::: "memory");
  else if constexpr (NN==8) asm volatile("s_waitcnt vmcnt(8)" ::: "memory");
  else asm volatile("s_waitcnt vmcnt(0)" ::: "memory");
}

// ==================== GEMM core: ring-3 (48KB LDS -> 3 blocks/CU), depth-2 counted vmcnt ====================
// Identical schedule form to the validated R4/R8 loop; only ring depth changed 4->3.
// A bf16 [M][lda]; Bt bf16 [NR][ldb] zero-padded. B zero for k in [K, ceil32(K)).
template<int BN, bool OBF16, bool CST, bool SMAX, bool G23S, bool G1S>
static __device__ __forceinline__ void gemm_core(int wg, short* lds,
    const short* __restrict__ A, int lda, const short* __restrict__ Bt, int ldb,
    void* __restrict__ Cv, int ldc, const float* __restrict__ bias,
    int M, int N, int K, int nbn,
    float* __restrict__ o_sum, float* __restrict__ o_sq,
    float* __restrict__ s2s, float* __restrict__ s2d,
    float* __restrict__ s3s, float* __restrict__ s3d,
    const float* __restrict__ a2s, const float* __restrict__ a2d,
    const float* __restrict__ a3s, const float* __restrict__ a3d)
{
  constexpr int BM = 128, BK = 32, GPR = 4;
  constexpr int WM = BM/2, WN = BN/2;
  constexpr int FM = WM/16, FN = WN/16;
  constexpr int AI = (BM*GPR)/(4*64);
  constexpr int BI_T = (BN*GPR)/64;
  constexpr bool BDUP = (BI_T < 4);
  constexpr int BI = BDUP ? BI_T : BI_T/4;
  constexpr int LPT = AI + BI;
  constexpr int TS = (BM+BN)*BK;

  const int tid = threadIdx.x, wid = tid>>6, lane = tid&63;
  const int wm = wid>>1, wn = wid&1;
  int bmt = wg / nbn, bnt = wg - bmt*nbn;
  const int bm = bmt*BM, bn = bnt*BN;
  const int lr = lane&15, lg = lane>>4;
  const int nt = (K + BK - 1)/BK;

  f32x4 acc[FM][FN] = {};

  auto STAGE = [&](int t){
    int buf = t % 3, k0 = t*BK;
    #pragma unroll
    for (int i=0;i<AI;i++){
      int ci = wid*AI + i;
      int c = ci*64 + lane;
      int row = c>>2, g = c&3;
      int gr = imin(bm+row, M-1);
      const short* src = A + (size_t)gr*lda + k0 + ((g ^ (row&3))<<3);
      gload16(src, &lds[buf*TS + ci*512]);
    }
    #pragma unroll
    for (int i=0;i<BI;i++){
      int bi = BDUP ? i : wid*BI + i;
      int c = bi*64 + lane;
      int row = c>>2, g = c&3;
      const short* src = Bt + (size_t)(bn+row)*ldb + k0 + ((g ^ (row&3))<<3);
      gload16(src, &lds[buf*TS + BM*BK + bi*512]);
    }
  };

  for (int s=0; s<2 && s<nt; ++s) STAGE(s);

  for (int t=0; t<nt; ++t){
    int newer = imin(nt, t+2) - t - 1;
    if (newer >= 1) wait_vm<LPT>();
    else wait_vm<0>();
    __builtin_amdgcn_s_barrier();
    __builtin_amdgcn_sched_barrier(0);
    if (t+2 < nt) STAGE(t+2);
    int buf = t % 3;
    short8 af[FM], bf[FN];
    #pragma unroll
    for (int m=0;m<FM;m++){
      int r = wm*WM + m*16 + lr;
      af[m] = *(short8*)&lds[buf*TS + r*BK + ((lg ^ (r&3))<<3)];
    }
    #pragma unroll
    for (int n=0;n<FN;n++){
      int r = wn*WN + n*16 + lr;
      bf[n] = *(short8*)&lds[buf*TS + BM*BK + r*BK + ((lg ^ (r&3))<<3)];
    }
    #pragma unroll
    for (int m=0;m<FM;m++)
      #pragma unroll
      for (int n=0;n<FN;n++)
        acc[m][n] = __builtin_amdgcn_mfma_f32_16x16x32_bf16(af[m], bf[n], acc[m][n], 0, 0, 0);
  }

  if (SMAX){
    #pragma unroll
    for (int m=0;m<FM;m++)
      #pragma unroll
      for (int q=0;q<4;q++){
        int row = bm + wm*WM + m*16 + lg*4 + q;
        float v = (lr < 10) ? (acc[m][0][q] + bias[lr]) : -3e38f;
        float mx = v;
        #pragma unroll
        for (int d=1; d<16; d<<=1) mx = fmaxf(mx, __shfl_xor(mx, d));
        float e = (lr < 10) ? __expf(v - mx) : 0.f;
        float sm = e;
        #pragma unroll
        for (int d=1; d<16; d<<=1) sm += __shfl_xor(sm, d);
        if (wn == 0 && lr < 10 && row < M)
          ((float*)Cv)[(size_t)row*10 + lr] = e/sm;
      }
    return;
  }

  #pragma unroll
  for (int m=0;m<FM;m++)
    #pragma unroll
    for (int n=0;n<FN;n++)
      #pragma unroll
      for (int q=0;q<4;q++){
        int row = bm + wm*WM + m*16 + lg*4 + q;
        int col = bn + wn*WN + n*16 + lr;
        if (row < M && col < N){
          float v = acc[m][n][q];
          if (bias) v += bias[col];
          if (OBF16) ((short*)Cv)[(size_t)row*ldc + col] = f2bf(v);
          else       ((float*)Cv)[(size_t)row*ldc + col] = v;
        }
      }

  if (G1S){
    int h = bnt;
    float a_s[FN], a_d[FN];
    #pragma unroll
    for (int n=0;n<FN;n++){
      int cl = wn*WN + n*16 + lr;
      a_s[n] = a2s[h*64 + cl];
      a_d[n] = a2d[h*64 + cl];
    }
    #pragma unroll
    for (int m=0;m<FM;m++)
      #pragma unroll
      for (int q=0;q<4;q++){
        int row = bm + wm*WM + m*16 + lg*4 + q;
        float ps = 0.f, pd = 0.f;
        #pragma unroll
        for (int n=0;n<FN;n++){ ps += acc[m][n][q]*a_s[n]; pd += acc[m][n][q]*a_d[n]; }
        #pragma unroll
        for (int d=1; d<16; d<<=1){ ps += __shfl_xor(ps, d); pd += __shfl_xor(pd, d); }
        if (lr == 0 && row < M){
          atomicAdd(&s2s[row*3+h], ps);
          atomicAdd(&s2d[row*3+h], pd);
        }
      }
  }

  if (G23S){
    float a_s[FN], a_d[FN];
    #pragma unroll
    for (int n=0;n<FN;n++){
      int cl = n*16 + lr;
      bool valid = cl < 30;
      a_s[n] = valid ? (wn ? a3s[cl] : a2s[cl]) : 0.f;
      a_d[n] = valid ? (wn ? a3d[cl] : a2d[cl]) : 0.f;
    }
    #pragma unroll
    for (int m=0;m<FM;m++)
      #pragma unroll
      for (int q=0;q<4;q++){
        int row = bm + wm*WM + m*16 + lg*4 + q;
        float ps = 0.f, pd = 0.f;
        #pragma unroll
        for (int n=0;n<FN;n++){ ps += acc[m][n][q]*a_s[n]; pd += acc[m][n][q]*a_d[n]; }
        #pragma unroll
        for (int d=1; d<16; d<<=1){ ps += __shfl_xor(ps, d); pd += __shfl_xor(pd, d); }
        if (lr == 0 && row < M){
          if (wn){ s3s[row] = ps; s3d[row] = pd; }
          else   { s2s[row] = ps; s2d[row] = pd; }
        }
      }
  }

  if (CST){
    #pragma unroll
    for (int n=0;n<FN;n++){
      float s = 0.f, q2 = 0.f;
      #pragma unroll
      for (int m=0;m<FM;m++)
        #pragma unroll
        for (int q=0;q<4;q++){
          int row = bm + wm*WM + m*16 + lg*4 + q;
          if (row < M){ float v = acc[m][n][q]; s += v; q2 += v*v; }
        }
      s  += __shfl_xor(s, 16);  s += __shfl_xor(s, 32);
      q2 += __shfl_xor(q2, 16); q2 += __shfl_xor(q2, 32);
      if (lg == 0){
        int col = bn + wn*WN + n*16 + lr;
        if (col < N){ atomicAdd(&o_sum[col], s); atomicAdd(&o_sq[col], q2); }
      }
    }
  }
}

static __device__ __forceinline__ int xcd_swz(int bid, int nwg){
  int q8 = nwg >> 3, r8 = nwg & 7;
  int xcd = bid & 7, pos = bid >> 3;
  return (xcd < r8 ? xcd*(q8+1) : r8*(q8+1) + (xcd-r8)*q8) + pos;
}

template<int BN, bool OBF16, bool CST, bool SMAX, bool G23S, bool G1S>
__global__ __launch_bounds__(256) void gemm_g(
    const short* __restrict__ A, int lda, const short* __restrict__ Bt, int ldb,
    void* __restrict__ Cv, int ldc, const float* __restrict__ bias,
    int M, int N, int K, int nbn,
    float* __restrict__ o_sum, float* __restrict__ o_sq,
    float* __restrict__ s2s, float* __restrict__ s2d,
    float* __restrict__ s3s, float* __restrict__ s3d,
    const float* __restrict__ a2s, const float* __restrict__ a2d,
    const float* __restrict__ a3s, const float* __restrict__ a3d)
{
  __shared__ short lds[3*(128+BN)*32];
  int wg = xcd_swz(blockIdx.x, gridDim.x);
  gemm_core<BN,OBF16,CST,SMAX,G23S,G1S>(wg, lds, A, lda, Bt, ldb, Cv, ldc, bias,
      M, N, K, nbn, o_sum, o_sq, s2s, s2d, s3s, s3d, a2s, a2d, a3s, a3d);
}

// dec3 (plain, BN=128) + clu2 (SMAX, BN=32) in one dispatch
__global__ __launch_bounds__(256) void gemm_dual(
    const short* __restrict__ A1, int lda1, const short* __restrict__ B1, int ldb1,
    void* __restrict__ C1, int ldc1, const float* __restrict__ bias1, int N1, int K1,
    const short* __restrict__ A2, int lda2, const short* __restrict__ B2, int ldb2,
    void* __restrict__ C2, const float* __restrict__ bias2, int N2, int K2,
    int M, int split)
{
  __shared__ short lds[3*(128+128)*32];
  int wg = xcd_swz(blockIdx.x, gridDim.x);
  if (wg < split){
    gemm_core<128,false,false,false,false,false>(wg, lds, A1, lda1, B1, ldb1, C1, ldc1, bias1,
        M, N1, K1, 8, nullptr,nullptr, nullptr,nullptr,nullptr,nullptr, nullptr,nullptr,nullptr,nullptr);
  } else {
    gemm_core<32,false,false,true,false,false>(wg - split, lds, A2, lda2, B2, ldb2, C2, 10, bias2,
        M, N2, K2, 1, nullptr,nullptr, nullptr,nullptr,nullptr,nullptr, nullptr,nullptr,nullptr,nullptr);
  }
}

// ==================== cvt_x + hist merged ====================
__global__ __launch_bounds__(256) void cvt_hist(const float* __restrict__ x, short* __restrict__ xb, int M,
                                                int CB, const int* __restrict__ d, int E, int* __restrict__ deg){
  int b = blockIdx.x;
  if (b < CB){
    int row = b*2 + (threadIdx.x>>7);
    int c8  = (threadIdx.x&127)*8;
    if (row >= M || c8 >= 1000) return;
    const float* p = x + (size_t)row*1000 + c8;
    float4 f0 = *(const float4*)p, f1 = *(const float4*)(p+4);
    short8 o;
    o[0]=f2bf(f0.x);o[1]=f2bf(f0.y);o[2]=f2bf(f0.z);o[3]=f2bf(f0.w);
    o[4]=f2bf(f1.x);o[5]=f2bf(f1.y);o[6]=f2bf(f1.z);o[7]=f2bf(f1.w);
    *(short8*)&xb[(size_t)row*1000 + c8] = o;
  } else {
    int i = (b - CB)*256 + threadIdx.x;
    if (i < E) atomicAdd(&deg[d[i]], 1);
  }
}

// ==================== weight transpose/convert ====================
struct WEnt { const float* src; short* dst; int K, N, KP, NR; };
struct WTab { WEnt e[10]; };
__global__ __launch_bounds__(256) void wtrans_all(WTab tab){
  WEnt w = tab.e[blockIdx.y];
  int gid = blockIdx.x*256 + threadIdx.x;
  if (gid >= w.NR * w.KP) return;
  int n = gid / w.KP, k = gid - n*w.KP;
  float v = (k < w.K && n < w.N) ? w.src[(size_t)k*w.N + n] : 0.f;
  w.dst[gid] = f2bf(v);
}

// ==================== BN (finalize folded) + ELU: bf16 in -> bf16 out ====================
template<int C>
__global__ __launch_bounds__(256) void bn_elu_apply2(const short* __restrict__ H, short* __restrict__ O,
    int M, float invM,
    const float* __restrict__ ssum, const float* __restrict__ ssq,
    const float* __restrict__ g, const float* __restrict__ bt){
  __shared__ float sc[C], sh[C];
  for (int c = threadIdx.x; c < C; c += 256){
    float mn  = ssum[c]*invM;
    float var = ssq[c]*invM - mn*mn;
    float s = g[c]*rsqrtf(var + 1e-5f);
    sc[c] = s; sh[c] = bt[c] - mn*s;
  }
  __syncthreads();
  int total8 = M*(C/8);
  for (int i = blockIdx.x*256+threadIdx.x; i < total8; i += gridDim.x*256){
    short8 v = ((const short8*)H)[i];
    int cb = (i*8) & (C-1);
    short8 o;
    #pragma unroll
    for (int j=0;j<8;j++) o[j] = f2bf(eluf(b2f(v[j])*sc[cb+j]+sh[cb+j]));
    ((short8*)O)[i] = o;
  }
}

__global__ __launch_bounds__(256) void bn_elu_split(const short* __restrict__ H,
    short* __restrict__ Od, short* __restrict__ Oc, int M, float invM,
    const float* __restrict__ ssum, const float* __restrict__ ssq,
    const float* __restrict__ gd, const float* __restrict__ btd,
    const float* __restrict__ gc, const float* __restrict__ btc){
  __shared__ float sc[256], sh[256];
  {
    int c = threadIdx.x;
    float mn  = ssum[c]*invM;
    float var = ssq[c]*invM - mn*mn;
    float gg = (c<128) ? gd[c] : gc[c-128];
    float bb = (c<128) ? btd[c] : btc[c-128];
    float s = gg*rsqrtf(var + 1e-5f);
    sc[c] = s; sh[c] = bb - mn*s;
  }
  __syncthreads();
  int total8 = M*32;
  for (int i = blockIdx.x*256+threadIdx.x; i < total8; i += gridDim.x*256){
    short8 v = ((const short8*)H)[i];
    int cb = (i*8) & 255;
    short8 o;
    #pragma unroll
    for (int j=0;j<8;j++) o[j] = f2bf(eluf(b2f(v[j])*sc[cb+j]+sh[cb+j]));
    int row = i>>5;
    short* O = (cb < 128) ? Od : Oc;
    *(short8*)&O[(size_t)row*128 + (cb&127)] = o;
  }
}

// ==================== CSR build ====================
__global__ __launch_bounds__(256) void scan1(const int* __restrict__ deg, int* __restrict__ offs,
                                             int* __restrict__ bsum, int n){
  __shared__ int sm[256];
  int tid = threadIdx.x;
  int base = blockIdx.x*1024 + tid*4;
  int v0 = base+0<n ? deg[base+0] : 0;
  int v1 = base+1<n ? deg[base+1] : 0;
  int v2 = base+2<n ? deg[base+2] : 0;
  int v3 = base+3<n ? deg[base+3] : 0;
  int ts = v0+v1+v2+v3;
  sm[tid] = ts;
  __syncthreads();
  #pragma unroll
  for (int d=1; d<256; d<<=1){
    int t = (tid>=d) ? sm[tid-d] : 0;
    __syncthreads();
    sm[tid] += t;
    __syncthreads();
  }
  int ex = sm[tid] - ts;
  if (base+0<n) offs[base+0] = ex;
  if (base+1<n) offs[base+1] = ex+v0;
  if (base+2<n) offs[base+2] = ex+v0+v1;
  if (base+3<n) offs[base+3] = ex+v0+v1+v2;
  if (tid==255) bsum[blockIdx.x] = sm[255];
}
__global__ __launch_bounds__(256) void scan3(int* __restrict__ offs, const int* __restrict__ bsum,
                      int* __restrict__ cursor, int n, int total){
  __shared__ int base_sm;
  int tgt = blockIdx.x >> 2;
  if (threadIdx.x < 64){
    int j = threadIdx.x;
    int v = (j < tgt) ? bsum[j] : 0;
    #pragma unroll
    for (int d=32; d; d>>=1) v += __shfl_xor(v, d);
    if (j == 0) base_sm = v;
  }
  __syncthreads();
  int i = blockIdx.x*256 + threadIdx.x;
  if (i < n){ int v = offs[i] + base_sm; offs[i]=v; cursor[i]=v; }
  if (i == 0) offs[n] = total;
}
__global__ void scatter_kernel(const int* __restrict__ s, const int* __restrict__ d, int E,
                               int* __restrict__ cursor, int* __restrict__ csr){
  int i = blockIdx.x*256 + threadIdx.x;
  if (i < E){ int pos = atomicAdd(&cursor[d[i]], 1); csr[pos] = s[i]; }
}

// ==================== GAT1 gather ====================
__global__ __launch_bounds__(256) void gat1_gather_bf(const int* __restrict__ offs, const int* __restrict__ csr,
    const short* __restrict__ hh, const float* __restrict__ ss, const float* __restrict__ sd,
    const float* __restrict__ bias, short* __restrict__ out, int n){
  int w = threadIdx.x >> 6, lane = threadIdx.x & 63;
  int dst = blockIdx.x*4 + w;
  if (dst >= n) return;
  float sd0 = sd[dst*3+0], sd1 = sd[dst*3+1], sd2 = sd[dst*3+2];
  float p0 = __expf(lrelu(ss[dst*3+0]+sd0));
  float p1 = __expf(lrelu(ss[dst*3+1]+sd1));
  float p2 = __expf(lrelu(ss[dst*3+2]+sd2));
  const short* hr = hh + (size_t)dst*192;
  float a0 = p0*b2f(hr[lane]), a1 = p1*b2f(hr[64+lane]), a2 = p2*b2f(hr[128+lane]);
  float d0 = p0, d1 = p1, d2 = p2;
  int p = offs[dst], pe = offs[dst+1];
  int n0=0,n1=0,n2=0,n3=0;
  if (p+4 <= pe){ n0=csr[p]; n1=csr[p+1]; n2=csr[p+2]; n3=csr[p+3]; }
  while (p+4 <= pe){
    int s0=n0, s1=n1, s2=n2, s3=n3;
    int pn = p+4;
    if (pn+4 <= pe){ n0=csr[pn]; n1=csr[pn+1]; n2=csr[pn+2]; n3=csr[pn+3]; }
    float e00=ss[s0*3+0], e01=ss[s0*3+1], e02=ss[s0*3+2];
    float e10=ss[s1*3+0], e11=ss[s1*3+1], e12=ss[s1*3+2];
    float e20=ss[s2*3+0], e21=ss[s2*3+1], e22=ss[s2*3+2];
    float e30=ss[s3*3+0], e31=ss[s3*3+1], e32=ss[s3*3+2];
    const short* r0 = hh + (size_t)s0*192;
    const short* r1 = hh + (size_t)s1*192;
    const short* r2 = hh + (size_t)s2*192;
    const short* r3 = hh + (size_t)s3*192;
    float v00=b2f(r0[lane]), v01=b2f(r0[64+lane]), v02=b2f(r0[128+lane]);
    float v10=b2f(r1[lane]), v11=b2f(r1[64+lane]), v12=b2f(r1[128+lane]);
    float v20=b2f(r2[lane]), v21=b2f(r2[64+lane]), v22=b2f(r2[128+lane]);
    float v30=b2f(r3[lane]), v31=b2f(r3[64+lane]), v32=b2f(r3[128+lane]);
    float q00=__expf(lrelu(e00+sd0)), q01=__expf(lrelu(e01+sd1)), q02=__expf(lrelu(e02+sd2));
    float q10=__expf(lrelu(e10+sd0)), q11=__expf(lrelu(e11+sd1)), q12=__expf(lrelu(e12+sd2));
    float q20=__expf(lrelu(e20+sd0)), q21=__expf(lrelu(e21+sd1)), q22=__expf(lrelu(e22+sd2));
    float q30=__expf(lrelu(e30+sd0)), q31=__expf(lrelu(e31+sd1)), q32=__expf(lrelu(e32+sd2));
    a0 += q00*v00 + q10*v10 + q20*v20 + q30*v30;
    a1 += q01*v01 + q11*v11 + q21*v21 + q31*v31;
    a2 += q02*v02 + q12*v12 + q22*v22 + q32*v32;
    d0 += q00+q10+q20+q30;
    d1 += q01+q11+q21+q31;
    d2 += q02+q12+q22+q32;
    p = pn;
  }
  for (; p < pe; ++p){
    int src = csr[p];
    float q0 = __expf(lrelu(ss[src*3+0]+sd0));
    float q1 = __expf(lrelu(ss[src*3+1]+sd1));
    float q2 = __expf(lrelu(ss[src*3+2]+sd2));
    const short* sr = hh + (size_t)src*192;
    a0 += q0*b2f(sr[lane]); a1 += q1*b2f(sr[64+lane]); a2 += q2*b2f(sr[128+lane]);
    d0 += q0; d1 += q1; d2 += q2;
  }
  float v0 = a0/d0 + bias[lane];
  float v1 = a1/d1 + bias[64+lane];
  float v2 = a2/d2 + bias[128+lane];
  short* orow = out + (size_t)dst*192;
  orow[lane]      = f2bf(v0 > 0.f ? v0 : 0.f);
  orow[64+lane]   = f2bf(v1 > 0.f ? v1 : 0.f);
  orow[128+lane]  = f2bf(v2 > 0.f ? v2 : 0.f);
}

// ==================== GAT2/3 gather (hh23 bf16 [N][64]) ====================
__global__ __launch_bounds__(256) void gat23_gather(const int* __restrict__ offs, const int* __restrict__ csr,
    const short* __restrict__ hh23,
    const float* __restrict__ s2s, const float* __restrict__ s2d,
    const float* __restrict__ s3s, const float* __restrict__ s3d,
    const float* __restrict__ b2, const float* __restrict__ b3,
    float* __restrict__ zs, float* __restrict__ mus, float* __restrict__ lvs,
    short* __restrict__ zbf, int n){
  int w = threadIdx.x >> 6, lane = threadIdx.x & 63;
  int dst = blockIdx.x*4 + w;
  if (dst >= n) return;
  bool lo = lane < 32;
  int c = lane & 31;
  bool valid = c < 30;
  float sdA = s2d[dst], sdB = s3d[dst];
  float sdx = lo ? sdA : sdB;
  const float* ssx = lo ? s2s : s3s;
  float p2 = __expf(lrelu(s2s[dst]+sdA));
  float p3 = __expf(lrelu(s3s[dst]+sdB));
  float val = valid ? b2f(hh23[(size_t)dst*64+lane]) : 0.f;
  float acc = (lo ? p2 : p3) * val;
  float den2 = p2, den3 = p3;
  int p = offs[dst], pe = offs[dst+1];
  int n0=0,n1=0,n2=0,n3=0;
  if (p+4 <= pe){ n0=csr[p]; n1=csr[p+1]; n2=csr[p+2]; n3=csr[p+3]; }
  while (p+4 <= pe){
    int s0=n0, s1=n1, s2i=n2, s3i=n3;
    int pn = p+4;
    if (pn+4 <= pe){ n0=csr[pn]; n1=csr[pn+1]; n2=csr[pn+2]; n3=csr[pn+3]; }
    float eA0=ssx[s0], eA1=ssx[s1], eA2=ssx[s2i], eA3=ssx[s3i];
    float f20=s2s[s0], f21=s2s[s1], f22=s2s[s2i], f23=s2s[s3i];
    float f30=s3s[s0], f31=s3s[s1], f32=s3s[s2i], f33=s3s[s3i];
    float v0 = valid ? b2f(hh23[(size_t)s0*64+lane]) : 0.f;
    float v1 = valid ? b2f(hh23[(size_t)s1*64+lane]) : 0.f;
    float v2 = valid ? b2f(hh23[(size_t)s2i*64+lane]) : 0.f;
    float v3 = valid ? b2f(hh23[(size_t)s3i*64+lane]) : 0.f;
    float qx0=__expf(lrelu(eA0+sdx)), qx1=__expf(lrelu(eA1+sdx));
    float qx2=__expf(lrelu(eA2+sdx)), qx3=__expf(lrelu(eA3+sdx));
    acc += qx0*v0 + qx1*v1 + qx2*v2 + qx3*v3;
    den2 += __expf(lrelu(f20+sdA)) + __expf(lrelu(f21+sdA)) + __expf(lrelu(f22+sdA)) + __expf(lrelu(f23+sdA));
    den3 += __expf(lrelu(f30+sdB)) + __expf(lrelu(f31+sdB)) + __expf(lrelu(f32+sdB)) + __expf(lrelu(f33+sdB));
    p = pn;
  }
  for (; p < pe; ++p){
    int src = csr[p];
    float q2 = __expf(lrelu(s2s[src]+sdA));
    float q3 = __expf(lrelu(s3s[src]+sdB));
    float v = valid ? b2f(hh23[(size_t)src*64+lane]) : 0.f;
    acc += (lo ? q2 : q3) * v;
    den2 += q2; den3 += q3;
  }
  if (lo){
    if (valid){
      float v = acc/den2 + b2[c];
      zs[(size_t)dst*30+c]  = v;
      mus[(size_t)dst*30+c] = v;
      zbf[(size_t)dst*32+c] = f2bf(v);
    } else {
      zbf[(size_t)dst*32+c] = 0;
    }
  } else if (valid){
    lvs[(size_t)dst*30+c] = acc/den3 + b3[c];
  }
}

// ==================== host ====================
static inline int cdiv(int a, int b){ return (a + b - 1) / b; }

extern "C" void kernel_launch(void* const* d_in, const int* in_sizes, int n_in,
                              void* d_out, int out_size, void* d_ws, size_t ws_size,
                              hipStream_t stream)
{
  const float* x        = (const float*)d_in[0];
  const int*   ei       = (const int*)  d_in[1];
  const float* enc_w1   = (const float*)d_in[2];
  const float* enc_g1   = (const float*)d_in[4];
  const float* enc_bt1  = (const float*)d_in[5];
  const float* enc_w2   = (const float*)d_in[6];
  const float* enc_g2   = (const float*)d_in[8];
  const float* enc_bt2  = (const float*)d_in[9];
  const float* gat1_w   = (const float*)d_in[10];
  const float* gat1_as  = (const float*)d_in[11];
  const float* gat1_ad  = (const float*)d_in[12];
  const float* gat1_b   = (const float*)d_in[13];
  const float* gat2_w   = (const float*)d_in[14];
  const float* gat2_as  = (const float*)d_in[15];
  const float* gat2_ad  = (const float*)d_in[16];
  const float* gat2_b   = (const float*)d_in[17];
  const float* gat3_w   = (const float*)d_in[18];
  const float* gat3_as  = (const float*)d_in[19];
  const float* gat3_ad  = (const float*)d_in[20];
  const float* gat3_b   = (const float*)d_in[21];
  const float* dec_w1   = (const float*)d_in[22];
  const float* dec_g1   = (const float*)d_in[24];
  const float* dec_bt1  = (const float*)d_in[25];
  const float* dec_w2   = (const float*)d_in[26];
  const float* dec_g2   = (const float*)d_in[28];
  const float* dec_bt2  = (const float*)d_in[29];
  const float* dec_w3   = (const float*)d_in[30];
  const float* dec_b3   = (const float*)d_in[31];
  const float* clu_w1   = (const float*)d_in[32];
  const float* clu_g1   = (const float*)d_in[34];
  const float* clu_bt1  = (const float*)d_in[35];
  const float* clu_w2   = (const float*)d_in[36];
  const float* clu_b2   = (const float*)d_in[37];

  const int N = in_sizes[0] / 1000;
  const int E = in_sizes[1] / 2;
  const int* e_src = ei;
  const int* e_dst = ei + E;
  const float invN = 1.f/(float)N;

  float* out  = (float*)d_out;
  float* pred = out;
  float* xrec = out + (size_t)N*10;
  float* zs   = xrec + (size_t)N*1000;
  float* mus  = zs  + (size_t)N*30;
  float* lvs  = mus + (size_t)N*30;

  char* ws = (char*)d_ws;
  size_t off = 0;
  auto alloc = [&](size_t bytes)->char*{
    char* p = ws + off;
    off = (off + bytes + 255) & ~(size_t)255;
    return p;
  };
  short* t_enc1  = (short*)alloc(256*1024*2);
  short* t_enc2  = (short*)alloc(128*256*2);
  short* t_gat1  = (short*)alloc(256*128*2);
  short* t_gat23 = (short*)alloc(64*192*2);
  short* t_dc1   = (short*)alloc(256*32*2);
  short* t_dec2  = (short*)alloc(256*128*2);
  short* t_dec3  = (short*)alloc(1024*256*2);
  short* t_clu2  = (short*)alloc(32*128*2);
  float* h1f  = (float*)alloc((size_t)N*256*4);
  short* h1b  = (short*)alloc((size_t)N*256*2);   // xb alias start
  float* h2f  = (float*)alloc((size_t)N*128*4);
  short* h2b  = (short*)alloc((size_t)N*128*2);
  short* hh1b = (short*)alloc((size_t)N*192*2);
  short* h3b  = (short*)alloc((size_t)N*192*2);
  float* hh23f= (float*)alloc((size_t)N*64*4);
  short* zbf  = (short*)alloc((size_t)N*32*2);
  // single zeroed region: stats(2048) | ss1(3N) | sd1(3N) | deg(N+1)
  size_t zcnt = 2048 + (size_t)6*N + (N+1);
  float* stats= (float*)alloc(zcnt*4);
  float* ss1  = stats + 2048;
  float* sd1  = ss1 + (size_t)3*N;
  int*   deg  = (int*)(sd1 + (size_t)3*N);
  float* s2s  = (float*)alloc((size_t)N*4);
  float* s2d  = (float*)alloc((size_t)N*4);
  float* s3s  = (float*)alloc((size_t)N*4);
  float* s3d  = (float*)alloc((size_t)N*4);
  int*   offs = (int*)alloc((size_t)(N+1)*4);
  int*   curp = (int*)alloc((size_t)(N+1)*4);
  int*   bsum = (int*)alloc(256*4);
  int*   csr  = (int*)alloc((size_t)E*4);
  // aliases (lifetimes):
  short* xb     = h1b;               // spans h1b..h3b (102.4MB >= 100MB); dead after enc1 gemm
  short* h1pre  = (short*)h1f;       // dead after enc1 apply
  short* h2pre  = (short*)h2f;       // dead after enc2 apply
  short* hh23b  = (short*)hh23f;
  short* dc1pre = (short*)h2f;       // spans h2f+h2b (38.4MB >= 25.6MB); after gat1_gather
  short* d1b    = h3b;               // h3b dead after gat23 gemm
  short* c1b    = hh1b;              // hh1b dead after gat1_gather (19.2MB >= 12.8MB)
  short* d2pre  = (short*)h1f;
  short* d2b    = h1b;
  float* st_enc1 = stats, *st_enc2 = stats+512, *st_dc1 = stats+768, *st_dec2 = stats+1280;

  // --- weight prep + single zeroing ---
  WTab tab;
  tab.e[0]  = {enc_w1, t_enc1, 1000, 256, 1024, 256};
  tab.e[1]  = {enc_w2, t_enc2, 256, 128, 256, 128};
  tab.e[2]  = {gat1_w, t_gat1, 128, 192, 128, 256};
  tab.e[3]  = {gat2_w, t_gat23, 192, 30, 192, 32};
  tab.e[4]  = {gat3_w, t_gat23 + 32*192, 192, 30, 192, 32};
  tab.e[5]  = {dec_w1, t_dc1, 30, 128, 32, 128};
  tab.e[6]  = {clu_w1, t_dc1 + 128*32, 30, 128, 32, 128};
  tab.e[7]  = {dec_w2, t_dec2, 128, 256, 128, 256};
  tab.e[8]  = {dec_w3, t_dec3, 256, 1000, 256, 1024};
  tab.e[9]  = {clu_w2, t_clu2, 128, 10, 128, 32};
  wtrans_all<<<dim3(1024, 10), 256, 0, stream>>>(tab);
  hipMemsetAsync(stats, 0, zcnt*4, stream);

  // --- cvt_x + hist merged ---
  int CB = cdiv(N, 2);
  cvt_hist<<<CB + cdiv(E,256), 256, 0, stream>>>(x, xb, N, CB, e_dst, E, deg);

  // --- CSR scan + scatter ---
  int nb = cdiv(N, 1024);
  scan1<<<nb, 256, 0, stream>>>(deg, offs, bsum, N);
  scan3<<<cdiv(N,256), 256, 0, stream>>>(offs, bsum, curp, N, E);
  scatter_kernel<<<cdiv(E,256), 256, 0, stream>>>(e_src, e_dst, E, curp, csr);

  const int MB = cdiv(N, 128);   // 391

  // --- encoder L1 ---
  gemm_g<128,true,true,false,false,false><<<MB*2, 256, 0, stream>>>(
      xb, 1000, t_enc1, 1024, h1pre, 256, nullptr, N, 256, 1000, 2,
      st_enc1, st_enc1+256, nullptr,nullptr,nullptr,nullptr, nullptr,nullptr,nullptr,nullptr);
  bn_elu_apply2<256><<<2048, 256, 0, stream>>>(h1pre, h1b, N, invN, st_enc1, st_enc1+256, enc_g1, enc_bt1);

  // --- encoder L2 ---
  gemm_g<128,true,true,false,false,false><<<MB, 256, 0, stream>>>(
      h1b, 256, t_enc2, 256, h2pre, 128, nullptr, N, 128, 256, 1,
      st_enc2, st_enc2+128, nullptr,nullptr,nullptr,nullptr, nullptr,nullptr,nullptr,nullptr);
  bn_elu_apply2<128><<<2048, 256, 0, stream>>>(h2pre, h2b, N, invN, st_enc2, st_enc2+128, enc_g2, enc_bt2);

  // --- GAT1 (scores folded; head = col-tile) ---
  gemm_g<64,true,false,false,false,true><<<MB*3, 256, 0, stream>>>(
      h2b, 128, t_gat1, 128, hh1b, 192, nullptr, N, 192, 128, 3,
      nullptr,nullptr, ss1,sd1,nullptr,nullptr, gat1_as,gat1_ad,nullptr,nullptr);
  gat1_gather_bf<<<cdiv(N,4), 256, 0, stream>>>(offs, csr, hh1b, ss1, sd1, gat1_b, h3b, N);

  // --- GAT2+GAT3 (combined weights; scores folded; bf16 out) ---
  gemm_g<64,true,false,false,true,false><<<MB, 256, 0, stream>>>(
      h3b, 192, t_gat23, 192, hh23b, 64, nullptr, N, 64, 192, 1,
      nullptr,nullptr, s2s,s2d,s3s,s3d, gat2_as,gat2_ad,gat3_as,gat3_ad);
  gat23_gather<<<cdiv(N,4), 256, 0, stream>>>(offs, csr, hh23b, s2s, s2d, s3s, s3d, gat2_b, gat3_b, zs, mus, lvs, zbf, N);

  // --- dec1 + clu1 combined ---
  gemm_g<128,true,true,false,false,false><<<MB*2, 256, 0, stream>>>(
      zbf, 32, t_dc1, 32, dc1pre, 256, nullptr, N, 256, 32, 2,
      st_dc1, st_dc1+256, nullptr,nullptr,nullptr,nullptr, nullptr,nullptr,nullptr,nullptr);
  bn_elu_split<<<2048, 256, 0, stream>>>(dc1pre, d1b, c1b, N, invN, st_dc1, st_dc1+256, dec_g1, dec_bt1, clu_g1, clu_bt1);

  // --- dec2 ---
  gemm_g<128,true,true,false,false,false><<<MB*2, 256, 0, stream>>>(
      d1b, 128, t_dec2, 128, d2pre, 256, nullptr, N, 256, 128, 2,
      st_dec2, st_dec2+256, nullptr,nullptr,nullptr,nullptr, nullptr,nullptr,nullptr,nullptr);
  bn_elu_apply2<256><<<2048, 256, 0, stream>>>(d2pre, d2b, N, invN, st_dec2, st_dec2+256, dec_g2, dec_bt2);

  // --- dec3 + clu2(softmax) in one dispatch ---
  gemm_dual<<<MB*8 + MB, 256, 0, stream>>>(
      d2b, 256, t_dec3, 256, xrec, 1000, dec_b3, 1000, 256,
      c1b, 128, t_clu2, 128, pred, clu_b2, 10, 128,
      N, MB*8);
}

// Round 12
// 601.750 us; speedup vs baseline: 1.3226x; 1.0237x over previous
//
#include <hip/hip_runtime.h>
#include <hip/hip_bf16.h>

typedef short short8 __attribute__((ext_vector_type(8)));
typedef short short4v __attribute__((ext_vector_type(4)));
typedef float f32x4 __attribute__((ext_vector_type(4)));

static __device__ __forceinline__ short f2bf(float f){
  __hip_bfloat16 h = __float2bfloat16(f);
  return __builtin_bit_cast(short, h);
}
static __device__ __forceinline__ float b2f(short s){
  unsigned int u = ((unsigned int)(unsigned short)s) << 16;
  return __builtin_bit_cast(float, u);
}
static __device__ __forceinline__ float lrelu(float x){ return x > 0.f ? x : 0.2f*x; }
static __device__ __forceinline__ float eluf(float x){ return x > 0.f ? x : (__expf(x)-1.f); }
static __device__ __forceinline__ int imin(int a,int b){ return a<b?a:b; }

typedef const __attribute__((address_space(1))) void as1_void;
typedef __attribute__((address_space(3))) void as3_void;
static __device__ __forceinline__ void gload16(const void* g, void* l){
  __builtin_amdgcn_global_load_lds((as1_void*)g, (as3_void*)l, 16, 0, 0);
}
template<int NN> __device__ __forceinline__ void wait_vm(){
  if constexpr (NN==0) asm volatile("s_waitcnt vmcnt(0)" ::: "memory");
  else if constexpr (NN==3) asm volatile("s_waitcnt vmcnt(3)" ::: "memory");
  else if constexpr (NN==4) asm volatile("s_waitcnt vmcnt(4)" ::: "memory");
  else if constexpr (NN==6) asm volatile("s_waitcnt vmcnt(6)" ::: "memory");
  else if constexpr (NN==8) asm volatile("s_waitcnt vmcnt(8)" ::: "memory");
  else asm volatile("s_waitcnt vmcnt(0)" ::: "memory");
}

static __device__ __forceinline__ int xcd_swz(int bid, int nwg){
  int q8 = nwg >> 3, r8 = nwg & 7;
  int xcd = bid & 7, pos = bid >> 3;
  return (xcd < r8 ? xcd*(q8+1) : r8*(q8+1) + (xcd-r8)*q8) + pos;
}

// ==================== GEMM core: ring-3, depth-2 counted vmcnt (validated R11) ====================
// A bf16 [M][lda]; Bt bf16 [NR][ldb] zero-padded. B zero for k in [K, ceil32(K)).
template<int BN, bool OBF16, bool CST, bool SMAX, bool G23S, bool G1S>
static __device__ __forceinline__ void gemm_core(int wg, short* lds,
    const short* __restrict__ A, int lda, const short* __restrict__ Bt, int ldb,
    void* __restrict__ Cv, int ldc, const float* __restrict__ bias,
    int M, int N, int K, int nbn,
    float* __restrict__ o_sum, float* __restrict__ o_sq,
    float* __restrict__ s2s, float* __restrict__ s2d,
    float* __restrict__ s3s, float* __restrict__ s3d,
    const float* __restrict__ a2s, const float* __restrict__ a2d,
    const float* __restrict__ a3s, const float* __restrict__ a3d)
{
  constexpr int BM = 128, BK = 32, GPR = 4;
  constexpr int WM = BM/2, WN = BN/2;
  constexpr int FM = WM/16, FN = WN/16;
  constexpr int AI = (BM*GPR)/(4*64);
  constexpr int BI_T = (BN*GPR)/64;
  constexpr bool BDUP = (BI_T < 4);
  constexpr int BI = BDUP ? BI_T : BI_T/4;
  constexpr int LPT = AI + BI;
  constexpr int TS = (BM+BN)*BK;

  const int tid = threadIdx.x, wid = tid>>6, lane = tid&63;
  const int wm = wid>>1, wn = wid&1;
  int bmt = wg / nbn, bnt = wg - bmt*nbn;
  const int bm = bmt*BM, bn = bnt*BN;
  const int lr = lane&15, lg = lane>>4;
  const int nt = (K + BK - 1)/BK;

  f32x4 acc[FM][FN] = {};

  auto STAGE = [&](int t){
    int buf = t % 3, k0 = t*BK;
    #pragma unroll
    for (int i=0;i<AI;i++){
      int ci = wid*AI + i;
      int c = ci*64 + lane;
      int row = c>>2, g = c&3;
      int gr = imin(bm+row, M-1);
      const short* src = A + (size_t)gr*lda + k0 + ((g ^ (row&3))<<3);
      gload16(src, &lds[buf*TS + ci*512]);
    }
    #pragma unroll
    for (int i=0;i<BI;i++){
      int bi = BDUP ? i : wid*BI + i;
      int c = bi*64 + lane;
      int row = c>>2, g = c&3;
      const short* src = Bt + (size_t)(bn+row)*ldb + k0 + ((g ^ (row&3))<<3);
      gload16(src, &lds[buf*TS + BM*BK + bi*512]);
    }
  };

  for (int s=0; s<2 && s<nt; ++s) STAGE(s);

  for (int t=0; t<nt; ++t){
    int newer = imin(nt, t+2) - t - 1;
    if (newer >= 1) wait_vm<LPT>();
    else wait_vm<0>();
    __builtin_amdgcn_s_barrier();
    __builtin_amdgcn_sched_barrier(0);
    if (t+2 < nt) STAGE(t+2);
    int buf = t % 3;
    short8 af[FM], bf[FN];
    #pragma unroll
    for (int m=0;m<FM;m++){
      int r = wm*WM + m*16 + lr;
      af[m] = *(short8*)&lds[buf*TS + r*BK + ((lg ^ (r&3))<<3)];
    }
    #pragma unroll
    for (int n=0;n<FN;n++){
      int r = wn*WN + n*16 + lr;
      bf[n] = *(short8*)&lds[buf*TS + BM*BK + r*BK + ((lg ^ (r&3))<<3)];
    }
    #pragma unroll
    for (int m=0;m<FM;m++)
      #pragma unroll
      for (int n=0;n<FN;n++)
        acc[m][n] = __builtin_amdgcn_mfma_f32_16x16x32_bf16(af[m], bf[n], acc[m][n], 0, 0, 0);
  }

  if (SMAX){
    #pragma unroll
    for (int m=0;m<FM;m++)
      #pragma unroll
      for (int q=0;q<4;q++){
        int row = bm + wm*WM + m*16 + lg*4 + q;
        float v = (lr < 10) ? (acc[m][0][q] + bias[lr]) : -3e38f;
        float mx = v;
        #pragma unroll
        for (int d=1; d<16; d<<=1) mx = fmaxf(mx, __shfl_xor(mx, d));
        float e = (lr < 10) ? __expf(v - mx) : 0.f;
        float sm = e;
        #pragma unroll
        for (int d=1; d<16; d<<=1) sm += __shfl_xor(sm, d);
        if (wn == 0 && lr < 10 && row < M)
          ((float*)Cv)[(size_t)row*10 + lr] = e/sm;
      }
    return;
  }

  #pragma unroll
  for (int m=0;m<FM;m++)
    #pragma unroll
    for (int n=0;n<FN;n++)
      #pragma unroll
      for (int q=0;q<4;q++){
        int row = bm + wm*WM + m*16 + lg*4 + q;
        int col = bn + wn*WN + n*16 + lr;
        if (row < M && col < N){
          float v = acc[m][n][q];
          if (bias) v += bias[col];
          if (OBF16) ((short*)Cv)[(size_t)row*ldc + col] = f2bf(v);
          else       ((float*)Cv)[(size_t)row*ldc + col] = v;
        }
      }

  if (G1S){
    int h = bnt;
    float a_s[FN], a_d[FN];
    #pragma unroll
    for (int n=0;n<FN;n++){
      int cl = wn*WN + n*16 + lr;
      a_s[n] = a2s[h*64 + cl];
      a_d[n] = a2d[h*64 + cl];
    }
    #pragma unroll
    for (int m=0;m<FM;m++)
      #pragma unroll
      for (int q=0;q<4;q++){
        int row = bm + wm*WM + m*16 + lg*4 + q;
        float ps = 0.f, pd = 0.f;
        #pragma unroll
        for (int n=0;n<FN;n++){ ps += acc[m][n][q]*a_s[n]; pd += acc[m][n][q]*a_d[n]; }
        #pragma unroll
        for (int d=1; d<16; d<<=1){ ps += __shfl_xor(ps, d); pd += __shfl_xor(pd, d); }
        if (lr == 0 && row < M){
          atomicAdd(&s2s[row*3+h], ps);
          atomicAdd(&s2d[row*3+h], pd);
        }
      }
  }

  if (G23S){
    float a_s[FN], a_d[FN];
    #pragma unroll
    for (int n=0;n<FN;n++){
      int cl = n*16 + lr;
      bool valid = cl < 30;
      a_s[n] = valid ? (wn ? a3s[cl] : a2s[cl]) : 0.f;
      a_d[n] = valid ? (wn ? a3d[cl] : a2d[cl]) : 0.f;
    }
    #pragma unroll
    for (int m=0;m<FM;m++)
      #pragma unroll
      for (int q=0;q<4;q++){
        int row = bm + wm*WM + m*16 + lg*4 + q;
        float ps = 0.f, pd = 0.f;
        #pragma unroll
        for (int n=0;n<FN;n++){ ps += acc[m][n][q]*a_s[n]; pd += acc[m][n][q]*a_d[n]; }
        #pragma unroll
        for (int d=1; d<16; d<<=1){ ps += __shfl_xor(ps, d); pd += __shfl_xor(pd, d); }
        if (lr == 0 && row < M){
          if (wn){ s3s[row] = ps; s3d[row] = pd; }
          else   { s2s[row] = ps; s2d[row] = pd; }
        }
      }
  }

  if (CST){
    #pragma unroll
    for (int n=0;n<FN;n++){
      float s = 0.f, q2 = 0.f;
      #pragma unroll
      for (int m=0;m<FM;m++)
        #pragma unroll
        for (int q=0;q<4;q++){
          int row = bm + wm*WM + m*16 + lg*4 + q;
          if (row < M){ float v = acc[m][n][q]; s += v; q2 += v*v; }
        }
      s  += __shfl_xor(s, 16);  s += __shfl_xor(s, 32);
      q2 += __shfl_xor(q2, 16); q2 += __shfl_xor(q2, 32);
      if (lg == 0){
        int col = bn + wn*WN + n*16 + lr;
        if (col < N){ atomicAdd(&o_sum[col], s); atomicAdd(&o_sq[col], q2); }
      }
    }
  }
}

template<int BN, bool OBF16, bool CST, bool SMAX, bool G23S, bool G1S>
__global__ __launch_bounds__(256) void gemm_g(
    const short* __restrict__ A, int lda, const short* __restrict__ Bt, int ldb,
    void* __restrict__ Cv, int ldc, const float* __restrict__ bias,
    int M, int N, int K, int nbn,
    float* __restrict__ o_sum, float* __restrict__ o_sq,
    float* __restrict__ s2s, float* __restrict__ s2d,
    float* __restrict__ s3s, float* __restrict__ s3d,
    const float* __restrict__ a2s, const float* __restrict__ a2d,
    const float* __restrict__ a3s, const float* __restrict__ a3d)
{
  __shared__ short lds[3*(128+BN)*32];
  int wg = xcd_swz(blockIdx.x, gridDim.x);
  gemm_core<BN,OBF16,CST,SMAX,G23S,G1S>(wg, lds, A, lda, Bt, ldb, Cv, ldc, bias,
      M, N, K, nbn, o_sum, o_sq, s2s, s2d, s3s, s3d, a2s, a2d, a3s, a3d);
}

// dec3 (plain, BN=128) + clu2 (SMAX, BN=32) in one dispatch
__global__ __launch_bounds__(256) void gemm_dual(
    const short* __restrict__ A1, int lda1, const short* __restrict__ B1, int ldb1,
    void* __restrict__ C1, int ldc1, const float* __restrict__ bias1, int N1, int K1,
    const short* __restrict__ A2, int lda2, const short* __restrict__ B2, int ldb2,
    void* __restrict__ C2, const float* __restrict__ bias2, int N2, int K2,
    int M, int split)
{
  __shared__ short lds[3*(128+128)*32];
  int wg = xcd_swz(blockIdx.x, gridDim.x);
  if (wg < split){
    gemm_core<128,false,false,false,false,false>(wg, lds, A1, lda1, B1, ldb1, C1, ldc1, bias1,
        M, N1, K1, 8, nullptr,nullptr, nullptr,nullptr,nullptr,nullptr, nullptr,nullptr,nullptr,nullptr);
  } else {
    gemm_core<32,false,false,true,false,false>(wg - split, lds, A2, lda2, B2, ldb2, C2, 10, bias2,
        M, N2, K2, 1, nullptr,nullptr, nullptr,nullptr,nullptr,nullptr, nullptr,nullptr,nullptr,nullptr);
  }
}

// ==================== enc1: f32-A GEMM (in-register cvt; deletes the cvt_x pass) ====================
// A f32 [M][lda]; Bt bf16 [NR][ldb] zero-padded (rows >= K are zero so A k-overread is harmless).
__global__ __launch_bounds__(256) void gemm_f32a(
    const float* __restrict__ A, int lda, const short* __restrict__ Bt, int ldb,
    short* __restrict__ C, int ldc,
    int M, int N, int K, int nbn,
    float* __restrict__ o_sum, float* __restrict__ o_sq)
{
  constexpr int BM=128, BN=128, BK=32;
  constexpr int ATS = BM*64;            // A tile in shorts (f32: 64 shorts/row)
  constexpr int TSH = ATS + BN*32;      // + B tile (bf16)
  __shared__ short lds[3*TSH];          // 72 KB
  const int tid=threadIdx.x, wid=tid>>6, lane=tid&63;
  const int wm=wid>>1, wn=wid&1;
  int wg = xcd_swz(blockIdx.x, gridDim.x);
  int bmt = wg/nbn, bnt = wg - bmt*nbn;
  const int bm=bmt*BM, bn=bnt*BN;
  const int lr=lane&15, lg=lane>>4;
  const int nt=(K+BK-1)/BK;
  f32x4 acc[4][4]={};

  auto STAGE=[&](int t){
    int buf=t%3, k0=t*BK;
    #pragma unroll
    for (int i=0;i<4;i++){              // A: 4 instrs/wave (1024 granules of 4 floats)
      int ci = wid*4+i;
      int c = ci*64+lane;
      int row=c>>3, g=c&7;
      int gr=imin(bm+row, M-1);
      const float* src = A + (size_t)gr*lda + k0 + ((g ^ (row&7))<<2);
      gload16(src, &lds[buf*TSH + ci*512]);
    }
    #pragma unroll
    for (int i=0;i<2;i++){              // B: 2 instrs/wave
      int bi = wid*2+i;
      int c = bi*64+lane;
      int row=c>>2, g=c&3;
      const short* src = Bt + (size_t)(bn+row)*ldb + k0 + ((g ^ (row&3))<<3);
      gload16(src, &lds[buf*TSH + ATS + bi*512]);
    }
  };

  STAGE(0); if (nt>1) STAGE(1);
  for (int t=0;t<nt;++t){
    int newer = imin(nt,t+2)-t-1;
    if (newer>=1) wait_vm<6>(); else wait_vm<0>();
    __builtin_amdgcn_s_barrier();
    __builtin_amdgcn_sched_barrier(0);
    if (t+2<nt) STAGE(t+2);
    int buf=t%3;
    short8 af[4], bf[4];
    #pragma unroll
    for (int m=0;m<4;m++){
      int r = wm*64 + m*16 + lr;
      int g0 = (2*lg) ^ (r&7), g1 = (2*lg+1) ^ (r&7);
      float4 fa = *(float4*)&lds[buf*TSH + r*64 + g0*8];
      float4 fb = *(float4*)&lds[buf*TSH + r*64 + g1*8];
      af[m][0]=f2bf(fa.x); af[m][1]=f2bf(fa.y); af[m][2]=f2bf(fa.z); af[m][3]=f2bf(fa.w);
      af[m][4]=f2bf(fb.x); af[m][5]=f2bf(fb.y); af[m][6]=f2bf(fb.z); af[m][7]=f2bf(fb.w);
    }
    #pragma unroll
    for (int n=0;n<4;n++){
      int r = wn*64 + n*16 + lr;
      bf[n] = *(short8*)&lds[buf*TSH + ATS + r*32 + ((lg ^ (r&3))<<3)];
    }
    #pragma unroll
    for (int m=0;m<4;m++)
      #pragma unroll
      for (int n=0;n<4;n++)
        acc[m][n] = __builtin_amdgcn_mfma_f32_16x16x32_bf16(af[m], bf[n], acc[m][n], 0, 0, 0);
  }

  #pragma unroll
  for (int m=0;m<4;m++)
    #pragma unroll
    for (int n=0;n<4;n++)
      #pragma unroll
      for (int q=0;q<4;q++){
        int row = bm + wm*64 + m*16 + lg*4 + q;
        int col = bn + wn*64 + n*16 + lr;
        if (row < M && col < N)
          C[(size_t)row*ldc + col] = f2bf(acc[m][n][q]);
      }
  #pragma unroll
  for (int n=0;n<4;n++){
    float s = 0.f, q2 = 0.f;
    #pragma unroll
    for (int m=0;m<4;m++)
      #pragma unroll
      for (int q=0;q<4;q++){
        int row = bm + wm*64 + m*16 + lg*4 + q;
        if (row < M){ float v = acc[m][n][q]; s += v; q2 += v*v; }
      }
    s  += __shfl_xor(s, 16);  s += __shfl_xor(s, 32);
    q2 += __shfl_xor(q2, 16); q2 += __shfl_xor(q2, 32);
    if (lg == 0){
      int col = bn + wn*64 + n*16 + lr;
      if (col < N){ atomicAdd(&o_sum[col], s); atomicAdd(&o_sq[col], q2); }
    }
  }
}

// ==================== hist ====================
__global__ void hist_kernel(const int* __restrict__ d, int E, int* __restrict__ deg){
  int i = blockIdx.x*256 + threadIdx.x;
  if (i < E) atomicAdd(&deg[d[i]], 1);
}

// ==================== weight transpose/convert ====================
struct WEnt { const float* src; short* dst; int K, N, KP, NR; };
struct WTab { WEnt e[10]; };
__global__ __launch_bounds__(256) void wtrans_all(WTab tab){
  WEnt w = tab.e[blockIdx.y];
  int gid = blockIdx.x*256 + threadIdx.x;
  if (gid >= w.NR * w.KP) return;
  int n = gid / w.KP, k = gid - n*w.KP;
  float v = (k < w.K && n < w.N) ? w.src[(size_t)k*w.N + n] : 0.f;
  w.dst[gid] = f2bf(v);
}

// ==================== BN (finalize folded) + ELU: bf16 in -> bf16 out ====================
template<int C>
__global__ __launch_bounds__(256) void bn_elu_apply2(const short* __restrict__ H, short* __restrict__ O,
    int M, float invM,
    const float* __restrict__ ssum, const float* __restrict__ ssq,
    const float* __restrict__ g, const float* __restrict__ bt){
  __shared__ float sc[C], sh[C];
  for (int c = threadIdx.x; c < C; c += 256){
    float mn  = ssum[c]*invM;
    float var = ssq[c]*invM - mn*mn;
    float s = g[c]*rsqrtf(var + 1e-5f);
    sc[c] = s; sh[c] = bt[c] - mn*s;
  }
  __syncthreads();
  int total8 = M*(C/8);
  for (int i = blockIdx.x*256+threadIdx.x; i < total8; i += gridDim.x*256){
    short8 v = ((const short8*)H)[i];
    int cb = (i*8) & (C-1);
    short8 o;
    #pragma unroll
    for (int j=0;j<8;j++) o[j] = f2bf(eluf(b2f(v[j])*sc[cb+j]+sh[cb+j]));
    ((short8*)O)[i] = o;
  }
}

__global__ __launch_bounds__(256) void bn_elu_split(const short* __restrict__ H,
    short* __restrict__ Od, short* __restrict__ Oc, int M, float invM,
    const float* __restrict__ ssum, const float* __restrict__ ssq,
    const float* __restrict__ gd, const float* __restrict__ btd,
    const float* __restrict__ gc, const float* __restrict__ btc){
  __shared__ float sc[256], sh[256];
  {
    int c = threadIdx.x;
    float mn  = ssum[c]*invM;
    float var = ssq[c]*invM - mn*mn;
    float gg = (c<128) ? gd[c] : gc[c-128];
    float bb = (c<128) ? btd[c] : btc[c-128];
    float s = gg*rsqrtf(var + 1e-5f);
    sc[c] = s; sh[c] = bb - mn*s;
  }
  __syncthreads();
  int total8 = M*32;
  for (int i = blockIdx.x*256+threadIdx.x; i < total8; i += gridDim.x*256){
    short8 v = ((const short8*)H)[i];
    int cb = (i*8) & 255;
    short8 o;
    #pragma unroll
    for (int j=0;j<8;j++) o[j] = f2bf(eluf(b2f(v[j])*sc[cb+j]+sh[cb+j]));
    int row = i>>5;
    short* O = (cb < 128) ? Od : Oc;
    *(short8*)&O[(size_t)row*128 + (cb&127)] = o;
  }
}

// ==================== CSR build ====================
__global__ __launch_bounds__(256) void scan1(const int* __restrict__ deg, int* __restrict__ offs,
                                             int* __restrict__ bsum, int n){
  __shared__ int sm[256];
  int tid = threadIdx.x;
  int base = blockIdx.x*1024 + tid*4;
  int v0 = base+0<n ? deg[base+0] : 0;
  int v1 = base+1<n ? deg[base+1] : 0;
  int v2 = base+2<n ? deg[base+2] : 0;
  int v3 = base+3<n ? deg[base+3] : 0;
  int ts = v0+v1+v2+v3;
  sm[tid] = ts;
  __syncthreads();
  #pragma unroll
  for (int d=1; d<256; d<<=1){
    int t = (tid>=d) ? sm[tid-d] : 0;
    __syncthreads();
    sm[tid] += t;
    __syncthreads();
  }
  int ex = sm[tid] - ts;
  if (base+0<n) offs[base+0] = ex;
  if (base+1<n) offs[base+1] = ex+v0;
  if (base+2<n) offs[base+2] = ex+v0+v1;
  if (base+3<n) offs[base+3] = ex+v0+v1+v2;
  if (tid==255) bsum[blockIdx.x] = sm[255];
}
__global__ __launch_bounds__(256) void scan3(int* __restrict__ offs, const int* __restrict__ bsum,
                      int* __restrict__ cursor, int n, int total){
  __shared__ int base_sm;
  int tgt = blockIdx.x >> 2;
  if (threadIdx.x < 64){
    int j = threadIdx.x;
    int v = (j < tgt) ? bsum[j] : 0;
    #pragma unroll
    for (int d=32; d; d>>=1) v += __shfl_xor(v, d);
    if (j == 0) base_sm = v;
  }
  __syncthreads();
  int i = blockIdx.x*256 + threadIdx.x;
  if (i < n){ int v = offs[i] + base_sm; offs[i]=v; cursor[i]=v; }
  if (i == 0) offs[n] = total;
}
__global__ void scatter_kernel(const int* __restrict__ s, const int* __restrict__ d, int E,
                               int* __restrict__ cursor, int* __restrict__ csr){
  int i = blockIdx.x*256 + threadIdx.x;
  if (i < E){ int pos = atomicAdd(&cursor[d[i]], 1); csr[pos] = s[i]; }
}

// ==================== GAT1 gather ====================
__global__ __launch_bounds__(256) void gat1_gather_bf(const int* __restrict__ offs, const int* __restrict__ csr,
    const short* __restrict__ hh, const float* __restrict__ ss, const float* __restrict__ sd,
    const float* __restrict__ bias, short* __restrict__ out, int n){
  int w = threadIdx.x >> 6, lane = threadIdx.x & 63;
  int dst = blockIdx.x*4 + w;
  if (dst >= n) return;
  float sd0 = sd[dst*3+0], sd1 = sd[dst*3+1], sd2 = sd[dst*3+2];
  float p0 = __expf(lrelu(ss[dst*3+0]+sd0));
  float p1 = __expf(lrelu(ss[dst*3+1]+sd1));
  float p2 = __expf(lrelu(ss[dst*3+2]+sd2));
  const short* hr = hh + (size_t)dst*192;
  float a0 = p0*b2f(hr[lane]), a1 = p1*b2f(hr[64+lane]), a2 = p2*b2f(hr[128+lane]);
  float d0 = p0, d1 = p1, d2 = p2;
  int p = offs[dst], pe = offs[dst+1];
  int n0=0,n1=0,n2=0,n3=0;
  if (p+4 <= pe){ n0=csr[p]; n1=csr[p+1]; n2=csr[p+2]; n3=csr[p+3]; }
  while (p+4 <= pe){
    int s0=n0, s1=n1, s2=n2, s3=n3;
    int pn = p+4;
    if (pn+4 <= pe){ n0=csr[pn]; n1=csr[pn+1]; n2=csr[pn+2]; n3=csr[pn+3]; }
    float e00=ss[s0*3+0], e01=ss[s0*3+1], e02=ss[s0*3+2];
    float e10=ss[s1*3+0], e11=ss[s1*3+1], e12=ss[s1*3+2];
    float e20=ss[s2*3+0], e21=ss[s2*3+1], e22=ss[s2*3+2];
    float e30=ss[s3*3+0], e31=ss[s3*3+1], e32=ss[s3*3+2];
    const short* r0 = hh + (size_t)s0*192;
    const short* r1 = hh + (size_t)s1*192;
    const short* r2 = hh + (size_t)s2*192;
    const short* r3 = hh + (size_t)s3*192;
    float v00=b2f(r0[lane]), v01=b2f(r0[64+lane]), v02=b2f(r0[128+lane]);
    float v10=b2f(r1[lane]), v11=b2f(r1[64+lane]), v12=b2f(r1[128+lane]);
    float v20=b2f(r2[lane]), v21=b2f(r2[64+lane]), v22=b2f(r2[128+lane]);
    float v30=b2f(r3[lane]), v31=b2f(r3[64+lane]), v32=b2f(r3[128+lane]);
    float q00=__expf(lrelu(e00+sd0)), q01=__expf(lrelu(e01+sd1)), q02=__expf(lrelu(e02+sd2));
    float q10=__expf(lrelu(e10+sd0)), q11=__expf(lrelu(e11+sd1)), q12=__expf(lrelu(e12+sd2));
    float q20=__expf(lrelu(e20+sd0)), q21=__expf(lrelu(e21+sd1)), q22=__expf(lrelu(e22+sd2));
    float q30=__expf(lrelu(e30+sd0)), q31=__expf(lrelu(e31+sd1)), q32=__expf(lrelu(e32+sd2));
    a0 += q00*v00 + q10*v10 + q20*v20 + q30*v30;
    a1 += q01*v01 + q11*v11 + q21*v21 + q31*v31;
    a2 += q02*v02 + q12*v12 + q22*v22 + q32*v32;
    d0 += q00+q10+q20+q30;
    d1 += q01+q11+q21+q31;
    d2 += q02+q12+q22+q32;
    p = pn;
  }
  for (; p < pe; ++p){
    int src = csr[p];
    float q0 = __expf(lrelu(ss[src*3+0]+sd0));
    float q1 = __expf(lrelu(ss[src*3+1]+sd1));
    float q2 = __expf(lrelu(ss[src*3+2]+sd2));
    const short* sr = hh + (size_t)src*192;
    a0 += q0*b2f(sr[lane]); a1 += q1*b2f(sr[64+lane]); a2 += q2*b2f(sr[128+lane]);
    d0 += q0; d1 += q1; d2 += q2;
  }
  float v0 = a0/d0 + bias[lane];
  float v1 = a1/d1 + bias[64+lane];
  float v2 = a2/d2 + bias[128+lane];
  short* orow = out + (size_t)dst*192;
  orow[lane]      = f2bf(v0 > 0.f ? v0 : 0.f);
  orow[64+lane]   = f2bf(v1 > 0.f ? v1 : 0.f);
  orow[128+lane]  = f2bf(v2 > 0.f ? v2 : 0.f);
}

// ==================== GAT2/3 gather (hh23 bf16 [N][64]) ====================
__global__ __launch_bounds__(256) void gat23_gather(const int* __restrict__ offs, const int* __restrict__ csr,
    const short* __restrict__ hh23,
    const float* __restrict__ s2s, const float* __restrict__ s2d,
    const float* __restrict__ s3s, const float* __restrict__ s3d,
    const float* __restrict__ b2, const float* __restrict__ b3,
    float* __restrict__ zs, float* __restrict__ mus, float* __restrict__ lvs,
    short* __restrict__ zbf, int n){
  int w = threadIdx.x >> 6, lane = threadIdx.x & 63;
  int dst = blockIdx.x*4 + w;
  if (dst >= n) return;
  bool lo = lane < 32;
  int c = lane & 31;
  bool valid = c < 30;
  float sdA = s2d[dst], sdB = s3d[dst];
  float sdx = lo ? sdA : sdB;
  const float* ssx = lo ? s2s : s3s;
  float p2 = __expf(lrelu(s2s[dst]+sdA));
  float p3 = __expf(lrelu(s3s[dst]+sdB));
  float val = valid ? b2f(hh23[(size_t)dst*64+lane]) : 0.f;
  float acc = (lo ? p2 : p3) * val;
  float den2 = p2, den3 = p3;
  int p = offs[dst], pe = offs[dst+1];
  int n0=0,n1=0,n2=0,n3=0;
  if (p+4 <= pe){ n0=csr[p]; n1=csr[p+1]; n2=csr[p+2]; n3=csr[p+3]; }
  while (p+4 <= pe){
    int s0=n0, s1=n1, s2i=n2, s3i=n3;
    int pn = p+4;
    if (pn+4 <= pe){ n0=csr[pn]; n1=csr[pn+1]; n2=csr[pn+2]; n3=csr[pn+3]; }
    float eA0=ssx[s0], eA1=ssx[s1], eA2=ssx[s2i], eA3=ssx[s3i];
    float f20=s2s[s0], f21=s2s[s1], f22=s2s[s2i], f23=s2s[s3i];
    float f30=s3s[s0], f31=s3s[s1], f32=s3s[s2i], f33=s3s[s3i];
    float v0 = valid ? b2f(hh23[(size_t)s0*64+lane]) : 0.f;
    float v1 = valid ? b2f(hh23[(size_t)s1*64+lane]) : 0.f;
    float v2 = valid ? b2f(hh23[(size_t)s2i*64+lane]) : 0.f;
    float v3 = valid ? b2f(hh23[(size_t)s3i*64+lane]) : 0.f;
    float qx0=__expf(lrelu(eA0+sdx)), qx1=__expf(lrelu(eA1+sdx));
    float qx2=__expf(lrelu(eA2+sdx)), qx3=__expf(lrelu(eA3+sdx));
    acc += qx0*v0 + qx1*v1 + qx2*v2 + qx3*v3;
    den2 += __expf(lrelu(f20+sdA)) + __expf(lrelu(f21+sdA)) + __expf(lrelu(f22+sdA)) + __expf(lrelu(f23+sdA));
    den3 += __expf(lrelu(f30+sdB)) + __expf(lrelu(f31+sdB)) + __expf(lrelu(f32+sdB)) + __expf(lrelu(f33+sdB));
    p = pn;
  }
  for (; p < pe; ++p){
    int src = csr[p];
    float q2 = __expf(lrelu(s2s[src]+sdA));
    float q3 = __expf(lrelu(s3s[src]+sdB));
    float v = valid ? b2f(hh23[(size_t)src*64+lane]) : 0.f;
    acc += (lo ? q2 : q3) * v;
    den2 += q2; den3 += q3;
  }
  if (lo){
    if (valid){
      float v = acc/den2 + b2[c];
      zs[(size_t)dst*30+c]  = v;
      mus[(size_t)dst*30+c] = v;
      zbf[(size_t)dst*32+c] = f2bf(v);
    } else {
      zbf[(size_t)dst*32+c] = 0;
    }
  } else if (valid){
    lvs[(size_t)dst*30+c] = acc/den3 + b3[c];
  }
}

// ==================== host ====================
static inline int cdiv(int a, int b){ return (a + b - 1) / b; }

extern "C" void kernel_launch(void* const* d_in, const int* in_sizes, int n_in,
                              void* d_out, int out_size, void* d_ws, size_t ws_size,
                              hipStream_t stream)
{
  const float* x        = (const float*)d_in[0];
  const int*   ei       = (const int*)  d_in[1];
  const float* enc_w1   = (const float*)d_in[2];
  const float* enc_g1   = (const float*)d_in[4];
  const float* enc_bt1  = (const float*)d_in[5];
  const float* enc_w2   = (const float*)d_in[6];
  const float* enc_g2   = (const float*)d_in[8];
  const float* enc_bt2  = (const float*)d_in[9];
  const float* gat1_w   = (const float*)d_in[10];
  const float* gat1_as  = (const float*)d_in[11];
  const float* gat1_ad  = (const float*)d_in[12];
  const float* gat1_b   = (const float*)d_in[13];
  const float* gat2_w   = (const float*)d_in[14];
  const float* gat2_as  = (const float*)d_in[15];
  const float* gat2_ad  = (const float*)d_in[16];
  const float* gat2_b   = (const float*)d_in[17];
  const float* gat3_w   = (const float*)d_in[18];
  const float* gat3_as  = (const float*)d_in[19];
  const float* gat3_ad  = (const float*)d_in[20];
  const float* gat3_b   = (const float*)d_in[21];
  const float* dec_w1   = (const float*)d_in[22];
  const float* dec_g1   = (const float*)d_in[24];
  const float* dec_bt1  = (const float*)d_in[25];
  const float* dec_w2   = (const float*)d_in[26];
  const float* dec_g2   = (const float*)d_in[28];
  const float* dec_bt2  = (const float*)d_in[29];
  const float* dec_w3   = (const float*)d_in[30];
  const float* dec_b3   = (const float*)d_in[31];
  const float* clu_w1   = (const float*)d_in[32];
  const float* clu_g1   = (const float*)d_in[34];
  const float* clu_bt1  = (const float*)d_in[35];
  const float* clu_w2   = (const float*)d_in[36];
  const float* clu_b2   = (const float*)d_in[37];

  const int N = in_sizes[0] / 1000;
  const int E = in_sizes[1] / 2;
  const int* e_src = ei;
  const int* e_dst = ei + E;
  const float invN = 1.f/(float)N;

  float* out  = (float*)d_out;
  float* pred = out;
  float* xrec = out + (size_t)N*10;
  float* zs   = xrec + (size_t)N*1000;
  float* mus  = zs  + (size_t)N*30;
  float* lvs  = mus + (size_t)N*30;

  char* ws = (char*)d_ws;
  size_t off = 0;
  auto alloc = [&](size_t bytes)->char*{
    char* p = ws + off;
    off = (off + bytes + 255) & ~(size_t)255;
    return p;
  };
  short* t_enc1  = (short*)alloc(256*1024*2);
  short* t_enc2  = (short*)alloc(128*256*2);
  short* t_gat1  = (short*)alloc(256*128*2);
  short* t_gat23 = (short*)alloc(64*192*2);
  short* t_dc1   = (short*)alloc(256*32*2);
  short* t_dec2  = (short*)alloc(256*128*2);
  short* t_dec3  = (short*)alloc(1024*256*2);
  short* t_clu2  = (short*)alloc(32*128*2);
  float* h1f  = (float*)alloc((size_t)N*256*4);
  short* h1b  = (short*)alloc((size_t)N*256*2);
  float* h2f  = (float*)alloc((size_t)N*128*4);
  short* h2b  = (short*)alloc((size_t)N*128*2);
  short* hh1b = (short*)alloc((size_t)N*192*2);
  short* h3b  = (short*)alloc((size_t)N*192*2);
  float* hh23f= (float*)alloc((size_t)N*64*4);
  short* zbf  = (short*)alloc((size_t)N*32*2);
  // single zeroed region: stats(2048) | ss1(3N) | sd1(3N) | deg(N+1)
  size_t zcnt = 2048 + (size_t)6*N + (N+1);
  float* stats= (float*)alloc(zcnt*4);
  float* ss1  = stats + 2048;
  float* sd1  = ss1 + (size_t)3*N;
  int*   deg  = (int*)(sd1 + (size_t)3*N);
  float* s2s  = (float*)alloc((size_t)N*4);
  float* s2d  = (float*)alloc((size_t)N*4);
  float* s3s  = (float*)alloc((size_t)N*4);
  float* s3d  = (float*)alloc((size_t)N*4);
  int*   offs = (int*)alloc((size_t)(N+1)*4);
  int*   curp = (int*)alloc((size_t)(N+1)*4);
  int*   bsum = (int*)alloc(256*4);
  int*   csr  = (int*)alloc((size_t)E*4);
  // aliases (lifetimes):
  short* h1pre  = (short*)h1f;       // dead after enc1 apply
  short* h2pre  = (short*)h2f;       // dead after enc2 apply
  short* hh23b  = (short*)hh23f;
  short* dc1pre = (short*)h2f;       // spans h2f+h2b (38.4MB >= 25.6MB); after gat1_gather
  short* d1b    = h3b;               // h3b dead after gat23 gemm
  short* c1b    = hh1b;              // hh1b dead after gat1_gather (19.2MB >= 12.8MB)
  short* d2pre  = (short*)h1f;
  short* d2b    = h1b;
  float* st_enc1 = stats, *st_enc2 = stats+512, *st_dc1 = stats+768, *st_dec2 = stats+1280;

  // --- weight prep + single zeroing ---
  WTab tab;
  tab.e[0]  = {enc_w1, t_enc1, 1000, 256, 1024, 256};
  tab.e[1]  = {enc_w2, t_enc2, 256, 128, 256, 128};
  tab.e[2]  = {gat1_w, t_gat1, 128, 192, 128, 256};
  tab.e[3]  = {gat2_w, t_gat23, 192, 30, 192, 32};
  tab.e[4]  = {gat3_w, t_gat23 + 32*192, 192, 30, 192, 32};
  tab.e[5]  = {dec_w1, t_dc1, 30, 128, 32, 128};
  tab.e[6]  = {clu_w1, t_dc1 + 128*32, 30, 128, 32, 128};
  tab.e[7]  = {dec_w2, t_dec2, 128, 256, 128, 256};
  tab.e[8]  = {dec_w3, t_dec3, 256, 1000, 256, 1024};
  tab.e[9]  = {clu_w2, t_clu2, 128, 10, 128, 32};
  wtrans_all<<<dim3(1024, 10), 256, 0, stream>>>(tab);
  hipMemsetAsync(stats, 0, zcnt*4, stream);

  // --- hist + CSR ---
  hist_kernel<<<cdiv(E,256), 256, 0, stream>>>(e_dst, E, deg);
  int nb = cdiv(N, 1024);
  scan1<<<nb, 256, 0, stream>>>(deg, offs, bsum, N);
  scan3<<<cdiv(N,256), 256, 0, stream>>>(offs, bsum, curp, N, E);
  scatter_kernel<<<cdiv(E,256), 256, 0, stream>>>(e_src, e_dst, E, curp, csr);

  const int MB = cdiv(N, 128);   // 391

  // --- encoder L1: f32-A GEMM (no cvt pass) ---
  gemm_f32a<<<MB*2, 256, 0, stream>>>(
      x, 1000, t_enc1, 1024, h1pre, 256, N, 256, 1000, 2, st_enc1, st_enc1+256);
  bn_elu_apply2<256><<<2048, 256, 0, stream>>>(h1pre, h1b, N, invN, st_enc1, st_enc1+256, enc_g1, enc_bt1);

  // --- encoder L2 ---
  gemm_g<128,true,true,false,false,false><<<MB, 256, 0, stream>>>(
      h1b, 256, t_enc2, 256, h2pre, 128, nullptr, N, 128, 256, 1,
      st_enc2, st_enc2+128, nullptr,nullptr,nullptr,nullptr, nullptr,nullptr,nullptr,nullptr);
  bn_elu_apply2<128><<<2048, 256, 0, stream>>>(h2pre, h2b, N, invN, st_enc2, st_enc2+128, enc_g2, enc_bt2);

  // --- GAT1 (scores folded; head = col-tile) ---
  gemm_g<64,true,false,false,false,true><<<MB*3, 256, 0, stream>>>(
      h2b, 128, t_gat1, 128, hh1b, 192, nullptr, N, 192, 128, 3,
      nullptr,nullptr, ss1,sd1,nullptr,nullptr, gat1_as,gat1_ad,nullptr,nullptr);
  gat1_gather_bf<<<cdiv(N,4), 256, 0, stream>>>(offs, csr, hh1b, ss1, sd1, gat1_b, h3b, N);

  // --- GAT2+GAT3 (combined weights; scores folded; bf16 out) ---
  gemm_g<64,true,false,false,true,false><<<MB, 256, 0, stream>>>(
      h3b, 192, t_gat23, 192, hh23b, 64, nullptr, N, 64, 192, 1,
      nullptr,nullptr, s2s,s2d,s3s,s3d, gat2_as,gat2_ad,gat3_as,gat3_ad);
  gat23_gather<<<cdiv(N,4), 256, 0, stream>>>(offs, csr, hh23b, s2s, s2d, s3s, s3d, gat2_b, gat3_b, zs, mus, lvs, zbf, N);

  // --- dec1 + clu1 combined ---
  gemm_g<128,true,true,false,false,false><<<MB*2, 256, 0, stream>>>(
      zbf, 32, t_dc1, 32, dc1pre, 256, nullptr, N, 256, 32, 2,
      st_dc1, st_dc1+256, nullptr,nullptr,nullptr,nullptr, nullptr,nullptr,nullptr,nullptr);
  bn_elu_split<<<2048, 256, 0, stream>>>(dc1pre, d1b, c1b, N, invN, st_dc1, st_dc1+256, dec_g1, dec_bt1, clu_g1, clu_bt1);

  // --- dec2 ---
  gemm_g<128,true,true,false,false,false><<<MB*2, 256, 0, stream>>>(
      d1b, 128, t_dec2, 128, d2pre, 256, nullptr, N, 256, 128, 2,
      st_dec2, st_dec2+256, nullptr,nullptr,nullptr,nullptr, nullptr,nullptr,nullptr,nullptr);
  bn_elu_apply2<256><<<2048, 256, 0, stream>>>(d2pre, d2b, N, invN, st_dec2, st_dec2+256, dec_g2, dec_bt2);

  // --- dec3 + clu2(softmax) in one dispatch ---
  gemm_dual<<<MB*8 + MB, 256, 0, stream>>>(
      d2b, 256, t_dec3, 256, xrec, 1000, dec_b3, 1000, 256,
      c1b, 128, t_clu2, 128, pred, clu_b2, 10, 128,
      N, MB*8);
}

// Round 13
// 598.867 us; speedup vs baseline: 1.3289x; 1.0048x over previous
//
#include <hip/hip_runtime.h>
#include <hip/hip_bf16.h>

typedef short short8 __attribute__((ext_vector_type(8)));
typedef short short4v __attribute__((ext_vector_type(4)));
typedef float f32x4 __attribute__((ext_vector_type(4)));

static __device__ __forceinline__ short f2bf(float f){
  __hip_bfloat16 h = __float2bfloat16(f);
  return __builtin_bit_cast(short, h);
}
static __device__ __forceinline__ float b2f(short s){
  unsigned int u = ((unsigned int)(unsigned short)s) << 16;
  return __builtin_bit_cast(float, u);
}
static __device__ __forceinline__ float lrelu(float x){ return x > 0.f ? x : 0.2f*x; }
static __device__ __forceinline__ float eluf(float x){ return x > 0.f ? x : (__expf(x)-1.f); }
static __device__ __forceinline__ int imin(int a,int b){ return a<b?a:b; }

typedef const __attribute__((address_space(1))) void as1_void;
typedef __attribute__((address_space(3))) void as3_void;
static __device__ __forceinline__ void gload16(const void* g, void* l){
  __builtin_amdgcn_global_load_lds((as1_void*)g, (as3_void*)l, 16, 0, 0);
}
template<int NN> __device__ __forceinline__ void wait_vm(){
  if constexpr (NN==0) asm volatile("s_waitcnt vmcnt(0)" ::: "memory");
  else if constexpr (NN==3) asm volatile("s_waitcnt vmcnt(3)" ::: "memory");
  else if constexpr (NN==4) asm volatile("s_waitcnt vmcnt(4)" ::: "memory");
  else if constexpr (NN==6) asm volatile("s_waitcnt vmcnt(6)" ::: "memory");
  else if constexpr (NN==8) asm volatile("s_waitcnt vmcnt(8)" ::: "memory");
  else if constexpr (NN==12) asm volatile("s_waitcnt vmcnt(12)" ::: "memory");
  else if constexpr (NN==16) asm volatile("s_waitcnt vmcnt(16)" ::: "memory");
  else asm volatile("s_waitcnt vmcnt(0)" ::: "memory");
}

static __device__ __forceinline__ int xcd_swz(int bid, int nwg){
  int q8 = nwg >> 3, r8 = nwg & 7;
  int xcd = bid & 7, pos = bid >> 3;
  return (xcd < r8 ? xcd*(q8+1) : r8*(q8+1) + (xcd-r8)*q8) + pos;
}

// ==================== GEMM core: ring-3, depth-2 counted vmcnt (validated R11) ====================
template<int BN, bool OBF16, bool CST, bool SMAX, bool G23S, bool G1S>
static __device__ __forceinline__ void gemm_core(int wg, short* lds,
    const short* __restrict__ A, int lda, const short* __restrict__ Bt, int ldb,
    void* __restrict__ Cv, int ldc, const float* __restrict__ bias,
    int M, int N, int K, int nbn,
    float* __restrict__ o_sum, float* __restrict__ o_sq,
    float* __restrict__ s2s, float* __restrict__ s2d,
    float* __restrict__ s3s, float* __restrict__ s3d,
    const float* __restrict__ a2s, const float* __restrict__ a2d,
    const float* __restrict__ a3s, const float* __restrict__ a3d)
{
  constexpr int BM = 128, BK = 32, GPR = 4;
  constexpr int WM = BM/2, WN = BN/2;
  constexpr int FM = WM/16, FN = WN/16;
  constexpr int AI = (BM*GPR)/(4*64);
  constexpr int BI_T = (BN*GPR)/64;
  constexpr bool BDUP = (BI_T < 4);
  constexpr int BI = BDUP ? BI_T : BI_T/4;
  constexpr int LPT = AI + BI;
  constexpr int TS = (BM+BN)*BK;

  const int tid = threadIdx.x, wid = tid>>6, lane = tid&63;
  const int wm = wid>>1, wn = wid&1;
  int bmt = wg / nbn, bnt = wg - bmt*nbn;
  const int bm = bmt*BM, bn = bnt*BN;
  const int lr = lane&15, lg = lane>>4;
  const int nt = (K + BK - 1)/BK;

  f32x4 acc[FM][FN] = {};

  auto STAGE = [&](int t){
    int buf = t % 3, k0 = t*BK;
    #pragma unroll
    for (int i=0;i<AI;i++){
      int ci = wid*AI + i;
      int c = ci*64 + lane;
      int row = c>>2, g = c&3;
      int gr = imin(bm+row, M-1);
      const short* src = A + (size_t)gr*lda + k0 + ((g ^ (row&3))<<3);
      gload16(src, &lds[buf*TS + ci*512]);
    }
    #pragma unroll
    for (int i=0;i<BI;i++){
      int bi = BDUP ? i : wid*BI + i;
      int c = bi*64 + lane;
      int row = c>>2, g = c&3;
      const short* src = Bt + (size_t)(bn+row)*ldb + k0 + ((g ^ (row&3))<<3);
      gload16(src, &lds[buf*TS + BM*BK + bi*512]);
    }
  };

  for (int s=0; s<2 && s<nt; ++s) STAGE(s);

  for (int t=0; t<nt; ++t){
    int newer = imin(nt, t+2) - t - 1;
    if (newer >= 1) wait_vm<LPT>();
    else wait_vm<0>();
    __builtin_amdgcn_s_barrier();
    __builtin_amdgcn_sched_barrier(0);
    if (t+2 < nt) STAGE(t+2);
    int buf = t % 3;
    short8 af[FM], bf[FN];
    #pragma unroll
    for (int m=0;m<FM;m++){
      int r = wm*WM + m*16 + lr;
      af[m] = *(short8*)&lds[buf*TS + r*BK + ((lg ^ (r&3))<<3)];
    }
    #pragma unroll
    for (int n=0;n<FN;n++){
      int r = wn*WN + n*16 + lr;
      bf[n] = *(short8*)&lds[buf*TS + BM*BK + r*BK + ((lg ^ (r&3))<<3)];
    }
    #pragma unroll
    for (int m=0;m<FM;m++)
      #pragma unroll
      for (int n=0;n<FN;n++)
        acc[m][n] = __builtin_amdgcn_mfma_f32_16x16x32_bf16(af[m], bf[n], acc[m][n], 0, 0, 0);
  }

  if (SMAX){
    #pragma unroll
    for (int m=0;m<FM;m++)
      #pragma unroll
      for (int q=0;q<4;q++){
        int row = bm + wm*WM + m*16 + lg*4 + q;
        float v = (lr < 10) ? (acc[m][0][q] + bias[lr]) : -3e38f;
        float mx = v;
        #pragma unroll
        for (int d=1; d<16; d<<=1) mx = fmaxf(mx, __shfl_xor(mx, d));
        float e = (lr < 10) ? __expf(v - mx) : 0.f;
        float sm = e;
        #pragma unroll
        for (int d=1; d<16; d<<=1) sm += __shfl_xor(sm, d);
        if (wn == 0 && lr < 10 && row < M)
          ((float*)Cv)[(size_t)row*10 + lr] = e/sm;
      }
    return;
  }

  #pragma unroll
  for (int m=0;m<FM;m++)
    #pragma unroll
    for (int n=0;n<FN;n++)
      #pragma unroll
      for (int q=0;q<4;q++){
        int row = bm + wm*WM + m*16 + lg*4 + q;
        int col = bn + wn*WN + n*16 + lr;
        if (row < M && col < N){
          float v = acc[m][n][q];
          if (bias) v += bias[col];
          if (OBF16) ((short*)Cv)[(size_t)row*ldc + col] = f2bf(v);
          else       ((float*)Cv)[(size_t)row*ldc + col] = v;
        }
      }

  if (G1S){
    int h = bnt;
    float a_s[FN], a_d[FN];
    #pragma unroll
    for (int n=0;n<FN;n++){
      int cl = wn*WN + n*16 + lr;
      a_s[n] = a2s[h*64 + cl];
      a_d[n] = a2d[h*64 + cl];
    }
    #pragma unroll
    for (int m=0;m<FM;m++)
      #pragma unroll
      for (int q=0;q<4;q++){
        int row = bm + wm*WM + m*16 + lg*4 + q;
        float ps = 0.f, pd = 0.f;
        #pragma unroll
        for (int n=0;n<FN;n++){ ps += acc[m][n][q]*a_s[n]; pd += acc[m][n][q]*a_d[n]; }
        #pragma unroll
        for (int d=1; d<16; d<<=1){ ps += __shfl_xor(ps, d); pd += __shfl_xor(pd, d); }
        if (lr == 0 && row < M){
          atomicAdd(&s2s[row*3+h], ps);
          atomicAdd(&s2d[row*3+h], pd);
        }
      }
  }

  if (G23S){
    float a_s[FN], a_d[FN];
    #pragma unroll
    for (int n=0;n<FN;n++){
      int cl = n*16 + lr;
      bool valid = cl < 30;
      a_s[n] = valid ? (wn ? a3s[cl] : a2s[cl]) : 0.f;
      a_d[n] = valid ? (wn ? a3d[cl] : a2d[cl]) : 0.f;
    }
    #pragma unroll
    for (int m=0;m<FM;m++)
      #pragma unroll
      for (int q=0;q<4;q++){
        int row = bm + wm*WM + m*16 + lg*4 + q;
        float ps = 0.f, pd = 0.f;
        #pragma unroll
        for (int n=0;n<FN;n++){ ps += acc[m][n][q]*a_s[n]; pd += acc[m][n][q]*a_d[n]; }
        #pragma unroll
        for (int d=1; d<16; d<<=1){ ps += __shfl_xor(ps, d); pd += __shfl_xor(pd, d); }
        if (lr == 0 && row < M){
          if (wn){ s3s[row] = ps; s3d[row] = pd; }
          else   { s2s[row] = ps; s2d[row] = pd; }
        }
      }
  }

  if (CST){
    #pragma unroll
    for (int n=0;n<FN;n++){
      float s = 0.f, q2 = 0.f;
      #pragma unroll
      for (int m=0;m<FM;m++)
        #pragma unroll
        for (int q=0;q<4;q++){
          int row = bm + wm*WM + m*16 + lg*4 + q;
          if (row < M){ float v = acc[m][n][q]; s += v; q2 += v*v; }
        }
      s  += __shfl_xor(s, 16);  s += __shfl_xor(s, 32);
      q2 += __shfl_xor(q2, 16); q2 += __shfl_xor(q2, 32);
      if (lg == 0){
        int col = bn + wn*WN + n*16 + lr;
        if (col < N){ atomicAdd(&o_sum[col], s); atomicAdd(&o_sq[col], q2); }
      }
    }
  }
}

template<int BN, bool OBF16, bool CST, bool SMAX, bool G23S, bool G1S>
__global__ __launch_bounds__(256) void gemm_g(
    const short* __restrict__ A, int lda, const short* __restrict__ Bt, int ldb,
    void* __restrict__ Cv, int ldc, const float* __restrict__ bias,
    int M, int N, int K, int nbn,
    float* __restrict__ o_sum, float* __restrict__ o_sq,
    float* __restrict__ s2s, float* __restrict__ s2d,
    float* __restrict__ s3s, float* __restrict__ s3d,
    const float* __restrict__ a2s, const float* __restrict__ a2d,
    const float* __restrict__ a3s, const float* __restrict__ a3d)
{
  __shared__ short lds[3*(128+BN)*32];
  int wg = xcd_swz(blockIdx.x, gridDim.x);
  gemm_core<BN,OBF16,CST,SMAX,G23S,G1S>(wg, lds, A, lda, Bt, ldb, Cv, ldc, bias,
      M, N, K, nbn, o_sum, o_sq, s2s, s2d, s3s, s3d, a2s, a2d, a3s, a3d);
}

// dec3 (plain, BN=128) + clu2 (SMAX, BN=32) in one dispatch
__global__ __launch_bounds__(256) void gemm_dual(
    const short* __restrict__ A1, int lda1, const short* __restrict__ B1, int ldb1,
    void* __restrict__ C1, int ldc1, const float* __restrict__ bias1, int N1, int K1,
    const short* __restrict__ A2, int lda2, const short* __restrict__ B2, int ldb2,
    void* __restrict__ C2, const float* __restrict__ bias2, int N2, int K2,
    int M, int split)
{
  __shared__ short lds[3*(128+128)*32];
  int wg = xcd_swz(blockIdx.x, gridDim.x);
  if (wg < split){
    gemm_core<128,false,false,false,false,false>(wg, lds, A1, lda1, B1, ldb1, C1, ldc1, bias1,
        M, N1, K1, 8, nullptr,nullptr, nullptr,nullptr,nullptr,nullptr, nullptr,nullptr,nullptr,nullptr);
  } else {
    gemm_core<32,false,false,true,false,false>(wg - split, lds, A2, lda2, B2, ldb2, C2, 10, bias2,
        M, N2, K2, 1, nullptr,nullptr, nullptr,nullptr,nullptr,nullptr, nullptr,nullptr,nullptr,nullptr);
  }
}

// ==================== gemm_pre: BK=64, ALL tiles prestaged (nt<=3), counted vmcnt ====================
// K == NT*64 exactly. A bf16 [M][lda]; Bt bf16 [NR][ldb] zero-padded.
template<int BN, int NT, bool OBF16, bool CST, bool G23S, bool G1S>
__global__ __launch_bounds__(256) void gemm_pre(
    const short* __restrict__ A, int lda, const short* __restrict__ Bt, int ldb,
    void* __restrict__ Cv, int ldc,
    int M, int N, int nbn,
    float* __restrict__ o_sum, float* __restrict__ o_sq,
    float* __restrict__ s2s, float* __restrict__ s2d,
    float* __restrict__ s3s, float* __restrict__ s3d,
    const float* __restrict__ a2s, const float* __restrict__ a2d,
    const float* __restrict__ a3s, const float* __restrict__ a3d)
{
  constexpr int BM = 128, BK = 64;
  constexpr int WM = 64, WN = BN/2;
  constexpr int FM = 4, FN = WN/16;
  constexpr int AI = 4;                   // A: BM*8 granules / 4 waves / 64 lanes
  constexpr int BI = (BN*8)/256;          // B granules per wave
  constexpr int LPT = AI + BI;
  constexpr int TS = (BM+BN)*BK;
  __shared__ short lds[NT*TS];

  const int tid = threadIdx.x, wid = tid>>6, lane = tid&63;
  const int wm = wid>>1, wn = wid&1;
  int wg = xcd_swz(blockIdx.x, gridDim.x);
  int bmt = wg / nbn, bnt = wg - bmt*nbn;
  const int bm = bmt*BM, bn = bnt*BN;
  const int lr = lane&15, lg = lane>>4;

  f32x4 acc[FM][FN] = {};

  // prestage ALL tiles
  #pragma unroll
  for (int s=0; s<NT; ++s){
    int k0 = s*BK;
    #pragma unroll
    for (int i=0;i<AI;i++){
      int ci = wid*AI + i;
      int c = ci*64 + lane;
      int row = c>>3, g = c&7;
      int gr = imin(bm+row, M-1);
      const short* src = A + (size_t)gr*lda + k0 + ((g ^ (row&7))<<3);
      gload16(src, &lds[s*TS + ci*512]);
    }
    #pragma unroll
    for (int i=0;i<BI;i++){
      int bi = wid*BI + i;
      int c = bi*64 + lane;
      int row = c>>3, g = c&7;
      const short* src = Bt + (size_t)(bn+row)*ldb + k0 + ((g ^ (row&7))<<3);
      gload16(src, &lds[s*TS + BM*BK + bi*512]);
    }
  }

  #pragma unroll
  for (int t=0; t<NT; ++t){
    if (t == NT-1) wait_vm<0>();
    else if (t == NT-2) wait_vm<LPT>();
    else wait_vm<2*LPT>();
    __builtin_amdgcn_s_barrier();
    __builtin_amdgcn_sched_barrier(0);
    #pragma unroll
    for (int kk=0; kk<2; ++kk){
      short8 af[FM], bf[FN];
      #pragma unroll
      for (int m=0;m<FM;m++){
        int r = wm*WM + m*16 + lr;
        af[m] = *(short8*)&lds[t*TS + r*BK + (((kk*4+lg) ^ (r&7))<<3)];
      }
      #pragma unroll
      for (int n=0;n<FN;n++){
        int r = wn*WN + n*16 + lr;
        bf[n] = *(short8*)&lds[t*TS + BM*BK + r*BK + (((kk*4+lg) ^ (r&7))<<3)];
      }
      #pragma unroll
      for (int m=0;m<FM;m++)
        #pragma unroll
        for (int n=0;n<FN;n++)
          acc[m][n] = __builtin_amdgcn_mfma_f32_16x16x32_bf16(af[m], bf[n], acc[m][n], 0, 0, 0);
    }
  }

  #pragma unroll
  for (int m=0;m<FM;m++)
    #pragma unroll
    for (int n=0;n<FN;n++)
      #pragma unroll
      for (int q=0;q<4;q++){
        int row = bm + wm*WM + m*16 + lg*4 + q;
        int col = bn + wn*WN + n*16 + lr;
        if (row < M && col < N){
          float v = acc[m][n][q];
          if (OBF16) ((short*)Cv)[(size_t)row*ldc + col] = f2bf(v);
          else       ((float*)Cv)[(size_t)row*ldc + col] = v;
        }
      }

  if (G1S){
    int h = bnt;
    float a_s[FN], a_d[FN];
    #pragma unroll
    for (int n=0;n<FN;n++){
      int cl = wn*WN + n*16 + lr;
      a_s[n] = a2s[h*64 + cl];
      a_d[n] = a2d[h*64 + cl];
    }
    #pragma unroll
    for (int m=0;m<FM;m++)
      #pragma unroll
      for (int q=0;q<4;q++){
        int row = bm + wm*WM + m*16 + lg*4 + q;
        float ps = 0.f, pd = 0.f;
        #pragma unroll
        for (int n=0;n<FN;n++){ ps += acc[m][n][q]*a_s[n]; pd += acc[m][n][q]*a_d[n]; }
        #pragma unroll
        for (int d=1; d<16; d<<=1){ ps += __shfl_xor(ps, d); pd += __shfl_xor(pd, d); }
        if (lr == 0 && row < M){
          atomicAdd(&s2s[row*3+h], ps);
          atomicAdd(&s2d[row*3+h], pd);
        }
      }
  }

  if (G23S){
    float a_s[FN], a_d[FN];
    #pragma unroll
    for (int n=0;n<FN;n++){
      int cl = n*16 + lr;
      bool valid = cl < 30;
      a_s[n] = valid ? (wn ? a3s[cl] : a2s[cl]) : 0.f;
      a_d[n] = valid ? (wn ? a3d[cl] : a2d[cl]) : 0.f;
    }
    #pragma unroll
    for (int m=0;m<FM;m++)
      #pragma unroll
      for (int q=0;q<4;q++){
        int row = bm + wm*WM + m*16 + lg*4 + q;
        float ps = 0.f, pd = 0.f;
        #pragma unroll
        for (int n=0;n<FN;n++){ ps += acc[m][n][q]*a_s[n]; pd += acc[m][n][q]*a_d[n]; }
        #pragma unroll
        for (int d=1; d<16; d<<=1){ ps += __shfl_xor(ps, d); pd += __shfl_xor(pd, d); }
        if (lr == 0 && row < M){
          if (wn){ s3s[row] = ps; s3d[row] = pd; }
          else   { s2s[row] = ps; s2d[row] = pd; }
        }
      }
  }

  if (CST){
    #pragma unroll
    for (int n=0;n<FN;n++){
      float s = 0.f, q2 = 0.f;
      #pragma unroll
      for (int m=0;m<FM;m++)
        #pragma unroll
        for (int q=0;q<4;q++){
          int row = bm + wm*WM + m*16 + lg*4 + q;
          if (row < M){ float v = acc[m][n][q]; s += v; q2 += v*v; }
        }
      s  += __shfl_xor(s, 16);  s += __shfl_xor(s, 32);
      q2 += __shfl_xor(q2, 16); q2 += __shfl_xor(q2, 32);
      if (lg == 0){
        int col = bn + wn*WN + n*16 + lr;
        if (col < N){ atomicAdd(&o_sum[col], s); atomicAdd(&o_sq[col], q2); }
      }
    }
  }
}

// ==================== enc1: f32-A GEMM (validated R12) ====================
__global__ __launch_bounds__(256) void gemm_f32a(
    const float* __restrict__ A, int lda, const short* __restrict__ Bt, int ldb,
    short* __restrict__ C, int ldc,
    int M, int N, int K, int nbn,
    float* __restrict__ o_sum, float* __restrict__ o_sq)
{
  constexpr int BM=128, BN=128, BK=32;
  constexpr int ATS = BM*64;
  constexpr int TSH = ATS + BN*32;
  __shared__ short lds[3*TSH];
  const int tid=threadIdx.x, wid=tid>>6, lane=tid&63;
  const int wm=wid>>1, wn=wid&1;
  int wg = xcd_swz(blockIdx.x, gridDim.x);
  int bmt = wg/nbn, bnt = wg - bmt*nbn;
  const int bm=bmt*BM, bn=bnt*BN;
  const int lr=lane&15, lg=lane>>4;
  const int nt=(K+BK-1)/BK;
  f32x4 acc[4][4]={};

  auto STAGE=[&](int t){
    int buf=t%3, k0=t*BK;
    #pragma unroll
    for (int i=0;i<4;i++){
      int ci = wid*4+i;
      int c = ci*64+lane;
      int row=c>>3, g=c&7;
      int gr=imin(bm+row, M-1);
      const float* src = A + (size_t)gr*lda + k0 + ((g ^ (row&7))<<2);
      gload16(src, &lds[buf*TSH + ci*512]);
    }
    #pragma unroll
    for (int i=0;i<2;i++){
      int bi = wid*2+i;
      int c = bi*64+lane;
      int row=c>>2, g=c&3;
      const short* src = Bt + (size_t)(bn+row)*ldb + k0 + ((g ^ (row&3))<<3);
      gload16(src, &lds[buf*TSH + ATS + bi*512]);
    }
  };

  STAGE(0); if (nt>1) STAGE(1);
  for (int t=0;t<nt;++t){
    int newer = imin(nt,t+2)-t-1;
    if (newer>=1) wait_vm<6>(); else wait_vm<0>();
    __builtin_amdgcn_s_barrier();
    __builtin_amdgcn_sched_barrier(0);
    if (t+2<nt) STAGE(t+2);
    int buf=t%3;
    short8 af[4], bf[4];
    #pragma unroll
    for (int m=0;m<4;m++){
      int r = wm*64 + m*16 + lr;
      int g0 = (2*lg) ^ (r&7), g1 = (2*lg+1) ^ (r&7);
      float4 fa = *(float4*)&lds[buf*TSH + r*64 + g0*8];
      float4 fb = *(float4*)&lds[buf*TSH + r*64 + g1*8];
      af[m][0]=f2bf(fa.x); af[m][1]=f2bf(fa.y); af[m][2]=f2bf(fa.z); af[m][3]=f2bf(fa.w);
      af[m][4]=f2bf(fb.x); af[m][5]=f2bf(fb.y); af[m][6]=f2bf(fb.z); af[m][7]=f2bf(fb.w);
    }
    #pragma unroll
    for (int n=0;n<4;n++){
      int r = wn*64 + n*16 + lr;
      bf[n] = *(short8*)&lds[buf*TSH + ATS + r*32 + ((lg ^ (r&3))<<3)];
    }
    #pragma unroll
    for (int m=0;m<4;m++)
      #pragma unroll
      for (int n=0;n<4;n++)
        acc[m][n] = __builtin_amdgcn_mfma_f32_16x16x32_bf16(af[m], bf[n], acc[m][n], 0, 0, 0);
  }

  #pragma unroll
  for (int m=0;m<4;m++)
    #pragma unroll
    for (int n=0;n<4;n++)
      #pragma unroll
      for (int q=0;q<4;q++){
        int row = bm + wm*64 + m*16 + lg*4 + q;
        int col = bn + wn*64 + n*16 + lr;
        if (row < M && col < N)
          C[(size_t)row*ldc + col] = f2bf(acc[m][n][q]);
      }
  #pragma unroll
  for (int n=0;n<4;n++){
    float s = 0.f, q2 = 0.f;
    #pragma unroll
    for (int m=0;m<4;m++)
      #pragma unroll
      for (int q=0;q<4;q++){
        int row = bm + wm*64 + m*16 + lg*4 + q;
        if (row < M){ float v = acc[m][n][q]; s += v; q2 += v*v; }
      }
    s  += __shfl_xor(s, 16);  s += __shfl_xor(s, 32);
    q2 += __shfl_xor(q2, 16); q2 += __shfl_xor(q2, 32);
    if (lg == 0){
      int col = bn + wn*64 + n*16 + lr;
      if (col < N){ atomicAdd(&o_sum[col], s); atomicAdd(&o_sq[col], q2); }
    }
  }
}

// ==================== weight transpose/convert + hist merged ====================
struct WEnt { const float* src; short* dst; int K, N, KP, NR; };
struct WTab { WEnt e[10]; };
__global__ __launch_bounds__(256) void wtrans_hist(WTab tab, const int* __restrict__ d, int E, int* __restrict__ deg){
  if (blockIdx.y == 10){
    int i = blockIdx.x*256 + threadIdx.x;
    if (i < E) atomicAdd(&deg[d[i]], 1);
    return;
  }
  WEnt w = tab.e[blockIdx.y];
  int gid = blockIdx.x*256 + threadIdx.x;
  if (gid >= w.NR * w.KP) return;
  int n = gid / w.KP, k = gid - n*w.KP;
  float v = (k < w.K && n < w.N) ? w.src[(size_t)k*w.N + n] : 0.f;
  w.dst[gid] = f2bf(v);
}

// ==================== BN (finalize folded) + ELU: bf16 in -> bf16 out ====================
template<int C>
__global__ __launch_bounds__(256) void bn_elu_apply2(const short* __restrict__ H, short* __restrict__ O,
    int M, float invM,
    const float* __restrict__ ssum, const float* __restrict__ ssq,
    const float* __restrict__ g, const float* __restrict__ bt){
  __shared__ float sc[C], sh[C];
  for (int c = threadIdx.x; c < C; c += 256){
    float mn  = ssum[c]*invM;
    float var = ssq[c]*invM - mn*mn;
    float s = g[c]*rsqrtf(var + 1e-5f);
    sc[c] = s; sh[c] = bt[c] - mn*s;
  }
  __syncthreads();
  int total8 = M*(C/8);
  for (int i = blockIdx.x*256+threadIdx.x; i < total8; i += gridDim.x*256){
    short8 v = ((const short8*)H)[i];
    int cb = (i*8) & (C-1);
    short8 o;
    #pragma unroll
    for (int j=0;j<8;j++) o[j] = f2bf(eluf(b2f(v[j])*sc[cb+j]+sh[cb+j]));
    ((short8*)O)[i] = o;
  }
}

__global__ __launch_bounds__(256) void bn_elu_split(const short* __restrict__ H,
    short* __restrict__ Od, short* __restrict__ Oc, int M, float invM,
    const float* __restrict__ ssum, const float* __restrict__ ssq,
    const float* __restrict__ gd, const float* __restrict__ btd,
    const float* __restrict__ gc, const float* __restrict__ btc){
  __shared__ float sc[256], sh[256];
  {
    int c = threadIdx.x;
    float mn  = ssum[c]*invM;
    float var = ssq[c]*invM - mn*mn;
    float gg = (c<128) ? gd[c] : gc[c-128];
    float bb = (c<128) ? btd[c] : btc[c-128];
    float s = gg*rsqrtf(var + 1e-5f);
    sc[c] = s; sh[c] = bb - mn*s;
  }
  __syncthreads();
  int total8 = M*32;
  for (int i = blockIdx.x*256+threadIdx.x; i < total8; i += gridDim.x*256){
    short8 v = ((const short8*)H)[i];
    int cb = (i*8) & 255;
    short8 o;
    #pragma unroll
    for (int j=0;j<8;j++) o[j] = f2bf(eluf(b2f(v[j])*sc[cb+j]+sh[cb+j]));
    int row = i>>5;
    short* O = (cb < 128) ? Od : Oc;
    *(short8*)&O[(size_t)row*128 + (cb&127)] = o;
  }
}

// ==================== CSR build ====================
__global__ __launch_bounds__(256) void scan1(const int* __restrict__ deg, int* __restrict__ offs,
                                             int* __restrict__ bsum, int n){
  __shared__ int sm[256];
  int tid = threadIdx.x;
  int base = blockIdx.x*1024 + tid*4;
  int v0 = base+0<n ? deg[base+0] : 0;
  int v1 = base+1<n ? deg[base+1] : 0;
  int v2 = base+2<n ? deg[base+2] : 0;
  int v3 = base+3<n ? deg[base+3] : 0;
  int ts = v0+v1+v2+v3;
  sm[tid] = ts;
  __syncthreads();
  #pragma unroll
  for (int d=1; d<256; d<<=1){
    int t = (tid>=d) ? sm[tid-d] : 0;
    __syncthreads();
    sm[tid] += t;
    __syncthreads();
  }
  int ex = sm[tid] - ts;
  if (base+0<n) offs[base+0] = ex;
  if (base+1<n) offs[base+1] = ex+v0;
  if (base+2<n) offs[base+2] = ex+v0+v1;
  if (base+3<n) offs[base+3] = ex+v0+v1+v2;
  if (tid==255) bsum[blockIdx.x] = sm[255];
}
__global__ __launch_bounds__(256) void scan3(int* __restrict__ offs, const int* __restrict__ bsum,
                      int* __restrict__ cursor, int n, int total){
  __shared__ int base_sm;
  int tgt = blockIdx.x >> 2;
  if (threadIdx.x < 64){
    int j = threadIdx.x;
    int v = (j < tgt) ? bsum[j] : 0;
    #pragma unroll
    for (int d=32; d; d>>=1) v += __shfl_xor(v, d);
    if (j == 0) base_sm = v;
  }
  __syncthreads();
  int i = blockIdx.x*256 + threadIdx.x;
  if (i < n){ int v = offs[i] + base_sm; offs[i]=v; cursor[i]=v; }
  if (i == 0) offs[n] = total;
}
__global__ void scatter_kernel(const int* __restrict__ s, const int* __restrict__ d, int E,
                               int* __restrict__ cursor, int* __restrict__ csr){
  int i = blockIdx.x*256 + threadIdx.x;
  if (i < E){ int pos = atomicAdd(&cursor[d[i]], 1); csr[pos] = s[i]; }
}

// ==================== GAT1 gather ====================
__global__ __launch_bounds__(256) void gat1_gather_bf(const int* __restrict__ offs, const int* __restrict__ csr,
    const short* __restrict__ hh, const float* __restrict__ ss, const float* __restrict__ sd,
    const float* __restrict__ bias, short* __restrict__ out, int n){
  int w = threadIdx.x >> 6, lane = threadIdx.x & 63;
  int dst = blockIdx.x*4 + w;
  if (dst >= n) return;
  float sd0 = sd[dst*3+0], sd1 = sd[dst*3+1], sd2 = sd[dst*3+2];
  float p0 = __expf(lrelu(ss[dst*3+0]+sd0));
  float p1 = __expf(lrelu(ss[dst*3+1]+sd1));
  float p2 = __expf(lrelu(ss[dst*3+2]+sd2));
  const short* hr = hh + (size_t)dst*192;
  float a0 = p0*b2f(hr[lane]), a1 = p1*b2f(hr[64+lane]), a2 = p2*b2f(hr[128+lane]);
  float d0 = p0, d1 = p1, d2 = p2;
  int p = offs[dst], pe = offs[dst+1];
  int n0=0,n1=0,n2=0,n3=0;
  if (p+4 <= pe){ n0=csr[p]; n1=csr[p+1]; n2=csr[p+2]; n3=csr[p+3]; }
  while (p+4 <= pe){
    int s0=n0, s1=n1, s2=n2, s3=n3;
    int pn = p+4;
    if (pn+4 <= pe){ n0=csr[pn]; n1=csr[pn+1]; n2=csr[pn+2]; n3=csr[pn+3]; }
    float e00=ss[s0*3+0], e01=ss[s0*3+1], e02=ss[s0*3+2];
    float e10=ss[s1*3+0], e11=ss[s1*3+1], e12=ss[s1*3+2];
    float e20=ss[s2*3+0], e21=ss[s2*3+1], e22=ss[s2*3+2];
    float e30=ss[s3*3+0], e31=ss[s3*3+1], e32=ss[s3*3+2];
    const short* r0 = hh + (size_t)s0*192;
    const short* r1 = hh + (size_t)s1*192;
    const short* r2 = hh + (size_t)s2*192;
    const short* r3 = hh + (size_t)s3*192;
    float v00=b2f(r0[lane]), v01=b2f(r0[64+lane]), v02=b2f(r0[128+lane]);
    float v10=b2f(r1[lane]), v11=b2f(r1[64+lane]), v12=b2f(r1[128+lane]);
    float v20=b2f(r2[lane]), v21=b2f(r2[64+lane]), v22=b2f(r2[128+lane]);
    float v30=b2f(r3[lane]), v31=b2f(r3[64+lane]), v32=b2f(r3[128+lane]);
    float q00=__expf(lrelu(e00+sd0)), q01=__expf(lrelu(e01+sd1)), q02=__expf(lrelu(e02+sd2));
    float q10=__expf(lrelu(e10+sd0)), q11=__expf(lrelu(e11+sd1)), q12=__expf(lrelu(e12+sd2));
    float q20=__expf(lrelu(e20+sd0)), q21=__expf(lrelu(e21+sd1)), q22=__expf(lrelu(e22+sd2));
    float q30=__expf(lrelu(e30+sd0)), q31=__expf(lrelu(e31+sd1)), q32=__expf(lrelu(e32+sd2));
    a0 += q00*v00 + q10*v10 + q20*v20 + q30*v30;
    a1 += q01*v01 + q11*v11 + q21*v21 + q31*v31;
    a2 += q02*v02 + q12*v12 + q22*v22 + q32*v32;
    d0 += q00+q10+q20+q30;
    d1 += q01+q11+q21+q31;
    d2 += q02+q12+q22+q32;
    p = pn;
  }
  for (; p < pe; ++p){
    int src = csr[p];
    float q0 = __expf(lrelu(ss[src*3+0]+sd0));
    float q1 = __expf(lrelu(ss[src*3+1]+sd1));
    float q2 = __expf(lrelu(ss[src*3+2]+sd2));
    const short* sr = hh + (size_t)src*192;
    a0 += q0*b2f(sr[lane]); a1 += q1*b2f(sr[64+lane]); a2 += q2*b2f(sr[128+lane]);
    d0 += q0; d1 += q1; d2 += q2;
  }
  float v0 = a0/d0 + bias[lane];
  float v1 = a1/d1 + bias[64+lane];
  float v2 = a2/d2 + bias[128+lane];
  short* orow = out + (size_t)dst*192;
  orow[lane]      = f2bf(v0 > 0.f ? v0 : 0.f);
  orow[64+lane]   = f2bf(v1 > 0.f ? v1 : 0.f);
  orow[128+lane]  = f2bf(v2 > 0.f ? v2 : 0.f);
}

// ==================== GAT2/3 gather (hh23 bf16 [N][64]) ====================
__global__ __launch_bounds__(256) void gat23_gather(const int* __restrict__ offs, const int* __restrict__ csr,
    const short* __restrict__ hh23,
    const float* __restrict__ s2s, const float* __restrict__ s2d,
    const float* __restrict__ s3s, const float* __restrict__ s3d,
    const float* __restrict__ b2, const float* __restrict__ b3,
    float* __restrict__ zs, float* __restrict__ mus, float* __restrict__ lvs,
    short* __restrict__ zbf, int n){
  int w = threadIdx.x >> 6, lane = threadIdx.x & 63;
  int dst = blockIdx.x*4 + w;
  if (dst >= n) return;
  bool lo = lane < 32;
  int c = lane & 31;
  bool valid = c < 30;
  float sdA = s2d[dst], sdB = s3d[dst];
  float sdx = lo ? sdA : sdB;
  const float* ssx = lo ? s2s : s3s;
  float p2 = __expf(lrelu(s2s[dst]+sdA));
  float p3 = __expf(lrelu(s3s[dst]+sdB));
  float val = valid ? b2f(hh23[(size_t)dst*64+lane]) : 0.f;
  float acc = (lo ? p2 : p3) * val;
  float den2 = p2, den3 = p3;
  int p = offs[dst], pe = offs[dst+1];
  int n0=0,n1=0,n2=0,n3=0;
  if (p+4 <= pe){ n0=csr[p]; n1=csr[p+1]; n2=csr[p+2]; n3=csr[p+3]; }
  while (p+4 <= pe){
    int s0=n0, s1=n1, s2i=n2, s3i=n3;
    int pn = p+4;
    if (pn+4 <= pe){ n0=csr[pn]; n1=csr[pn+1]; n2=csr[pn+2]; n3=csr[pn+3]; }
    float eA0=ssx[s0], eA1=ssx[s1], eA2=ssx[s2i], eA3=ssx[s3i];
    float f20=s2s[s0], f21=s2s[s1], f22=s2s[s2i], f23=s2s[s3i];
    float f30=s3s[s0], f31=s3s[s1], f32=s3s[s2i], f33=s3s[s3i];
    float v0 = valid ? b2f(hh23[(size_t)s0*64+lane]) : 0.f;
    float v1 = valid ? b2f(hh23[(size_t)s1*64+lane]) : 0.f;
    float v2 = valid ? b2f(hh23[(size_t)s2i*64+lane]) : 0.f;
    float v3 = valid ? b2f(hh23[(size_t)s3i*64+lane]) : 0.f;
    float qx0=__expf(lrelu(eA0+sdx)), qx1=__expf(lrelu(eA1+sdx));
    float qx2=__expf(lrelu(eA2+sdx)), qx3=__expf(lrelu(eA3+sdx));
    acc += qx0*v0 + qx1*v1 + qx2*v2 + qx3*v3;
    den2 += __expf(lrelu(f20+sdA)) + __expf(lrelu(f21+sdA)) + __expf(lrelu(f22+sdA)) + __expf(lrelu(f23+sdA));
    den3 += __expf(lrelu(f30+sdB)) + __expf(lrelu(f31+sdB)) + __expf(lrelu(f32+sdB)) + __expf(lrelu(f33+sdB));
    p = pn;
  }
  for (; p < pe; ++p){
    int src = csr[p];
    float q2 = __expf(lrelu(s2s[src]+sdA));
    float q3 = __expf(lrelu(s3s[src]+sdB));
    float v = valid ? b2f(hh23[(size_t)src*64+lane]) : 0.f;
    acc += (lo ? q2 : q3) * v;
    den2 += q2; den3 += q3;
  }
  if (lo){
    if (valid){
      float v = acc/den2 + b2[c];
      zs[(size_t)dst*30+c]  = v;
      mus[(size_t)dst*30+c] = v;
      zbf[(size_t)dst*32+c] = f2bf(v);
    } else {
      zbf[(size_t)dst*32+c] = 0;
    }
  } else if (valid){
    lvs[(size_t)dst*30+c] = acc/den3 + b3[c];
  }
}

// ==================== host ====================
static inline int cdiv(int a, int b){ return (a + b - 1) / b; }

extern "C" void kernel_launch(void* const* d_in, const int* in_sizes, int n_in,
                              void* d_out, int out_size, void* d_ws, size_t ws_size,
                              hipStream_t stream)
{
  const float* x        = (const float*)d_in[0];
  const int*   ei       = (const int*)  d_in[1];
  const float* enc_w1   = (const float*)d_in[2];
  const float* enc_g1   = (const float*)d_in[4];
  const float* enc_bt1  = (const float*)d_in[5];
  const float* enc_w2   = (const float*)d_in[6];
  const float* enc_g2   = (const float*)d_in[8];
  const float* enc_bt2  = (const float*)d_in[9];
  const float* gat1_w   = (const float*)d_in[10];
  const float* gat1_as  = (const float*)d_in[11];
  const float* gat1_ad  = (const float*)d_in[12];
  const float* gat1_b   = (const float*)d_in[13];
  const float* gat2_w   = (const float*)d_in[14];
  const float* gat2_as  = (const float*)d_in[15];
  const float* gat2_ad  = (const float*)d_in[16];
  const float* gat2_b   = (const float*)d_in[17];
  const float* gat3_w   = (const float*)d_in[18];
  const float* gat3_as  = (const float*)d_in[19];
  const float* gat3_ad  = (const float*)d_in[20];
  const float* gat3_b   = (const float*)d_in[21];
  const float* dec_w1   = (const float*)d_in[22];
  const float* dec_g1   = (const float*)d_in[24];
  const float* dec_bt1  = (const float*)d_in[25];
  const float* dec_w2   = (const float*)d_in[26];
  const float* dec_g2   = (const float*)d_in[28];
  const float* dec_bt2  = (const float*)d_in[29];
  const float* dec_w3   = (const float*)d_in[30];
  const float* dec_b3   = (const float*)d_in[31];
  const float* clu_w1   = (const float*)d_in[32];
  const float* clu_g1   = (const float*)d_in[34];
  const float* clu_bt1  = (const float*)d_in[35];
  const float* clu_w2   = (const float*)d_in[36];
  const float* clu_b2   = (const float*)d_in[37];

  const int N = in_sizes[0] / 1000;
  const int E = in_sizes[1] / 2;
  const int* e_src = ei;
  const int* e_dst = ei + E;
  const float invN = 1.f/(float)N;

  float* out  = (float*)d_out;
  float* pred = out;
  float* xrec = out + (size_t)N*10;
  float* zs   = xrec + (size_t)N*1000;
  float* mus  = zs  + (size_t)N*30;
  float* lvs  = mus + (size_t)N*30;

  char* ws = (char*)d_ws;
  size_t off = 0;
  auto alloc = [&](size_t bytes)->char*{
    char* p = ws + off;
    off = (off + bytes + 255) & ~(size_t)255;
    return p;
  };
  short* t_enc1  = (short*)alloc(256*1024*2);
  short* t_enc2  = (short*)alloc(128*256*2);
  short* t_gat1  = (short*)alloc(256*128*2);
  short* t_gat23 = (short*)alloc(64*192*2);
  short* t_dc1   = (short*)alloc(256*32*2);
  short* t_dec2  = (short*)alloc(256*128*2);
  short* t_dec3  = (short*)alloc(1024*256*2);
  short* t_clu2  = (short*)alloc(32*128*2);
  float* h1f  = (float*)alloc((size_t)N*256*4);
  short* h1b  = (short*)alloc((size_t)N*256*2);
  float* h2f  = (float*)alloc((size_t)N*128*4);
  short* h2b  = (short*)alloc((size_t)N*128*2);
  short* hh1b = (short*)alloc((size_t)N*192*2);
  short* h3b  = (short*)alloc((size_t)N*192*2);
  float* hh23f= (float*)alloc((size_t)N*64*4);
  short* zbf  = (short*)alloc((size_t)N*32*2);
  size_t zcnt = 2048 + (size_t)6*N + (N+1);
  float* stats= (float*)alloc(zcnt*4);
  float* ss1  = stats + 2048;
  float* sd1  = ss1 + (size_t)3*N;
  int*   deg  = (int*)(sd1 + (size_t)3*N);
  float* s2s  = (float*)alloc((size_t)N*4);
  float* s2d  = (float*)alloc((size_t)N*4);
  float* s3s  = (float*)alloc((size_t)N*4);
  float* s3d  = (float*)alloc((size_t)N*4);
  int*   offs = (int*)alloc((size_t)(N+1)*4);
  int*   curp = (int*)alloc((size_t)(N+1)*4);
  int*   bsum = (int*)alloc(256*4);
  int*   csr  = (int*)alloc((size_t)E*4);
  short* h1pre  = (short*)h1f;
  short* h2pre  = (short*)h2f;
  short* hh23b  = (short*)hh23f;
  short* dc1pre = (short*)h2f;
  short* d1b    = h3b;
  short* c1b    = hh1b;
  short* d2pre  = (short*)h1f;
  short* d2b    = h1b;
  float* st_enc1 = stats, *st_enc2 = stats+512, *st_dc1 = stats+768, *st_dec2 = stats+1280;

  // --- weight prep + hist (merged) + single zeroing ---
  WTab tab;
  tab.e[0]  = {enc_w1, t_enc1, 1000, 256, 1024, 256};
  tab.e[1]  = {enc_w2, t_enc2, 256, 128, 256, 128};
  tab.e[2]  = {gat1_w, t_gat1, 128, 192, 128, 256};
  tab.e[3]  = {gat2_w, t_gat23, 192, 30, 192, 32};
  tab.e[4]  = {gat3_w, t_gat23 + 32*192, 192, 30, 192, 32};
  tab.e[5]  = {dec_w1, t_dc1, 30, 128, 32, 128};
  tab.e[6]  = {clu_w1, t_dc1 + 128*32, 30, 128, 32, 128};
  tab.e[7]  = {dec_w2, t_dec2, 128, 256, 128, 256};
  tab.e[8]  = {dec_w3, t_dec3, 256, 1000, 256, 1024};
  tab.e[9]  = {clu_w2, t_clu2, 128, 10, 128, 32};
  hipMemsetAsync(stats, 0, zcnt*4, stream);
  wtrans_hist<<<dim3(cdiv(E,256), 11), 256, 0, stream>>>(tab, e_dst, E, deg);

  // --- CSR scan + scatter ---
  int nb = cdiv(N, 1024);
  scan1<<<nb, 256, 0, stream>>>(deg, offs, bsum, N);
  scan3<<<cdiv(N,256), 256, 0, stream>>>(offs, bsum, curp, N, E);
  scatter_kernel<<<cdiv(E,256), 256, 0, stream>>>(e_src, e_dst, E, curp, csr);

  const int MB = cdiv(N, 128);   // 391

  // --- encoder L1: f32-A GEMM ---
  gemm_f32a<<<MB*2, 256, 0, stream>>>(
      x, 1000, t_enc1, 1024, h1pre, 256, N, 256, 1000, 2, st_enc1, st_enc1+256);
  bn_elu_apply2<256><<<2048, 256, 0, stream>>>(h1pre, h1b, N, invN, st_enc1, st_enc1+256, enc_g1, enc_bt1);

  // --- encoder L2 ---
  gemm_g<128,true,true,false,false,false><<<MB, 256, 0, stream>>>(
      h1b, 256, t_enc2, 256, h2pre, 128, nullptr, N, 128, 256, 1,
      st_enc2, st_enc2+128, nullptr,nullptr,nullptr,nullptr, nullptr,nullptr,nullptr,nullptr);
  bn_elu_apply2<128><<<2048, 256, 0, stream>>>(h2pre, h2b, N, invN, st_enc2, st_enc2+128, enc_g2, enc_bt2);

  // --- GAT1: prestaged BK=64, nt=2 (scores folded) ---
  gemm_pre<64,2,true,false,false,true><<<MB*3, 256, 0, stream>>>(
      h2b, 128, t_gat1, 128, hh1b, 192, N, 192, 3,
      nullptr,nullptr, ss1,sd1,nullptr,nullptr, gat1_as,gat1_ad,nullptr,nullptr);
  gat1_gather_bf<<<cdiv(N,4), 256, 0, stream>>>(offs, csr, hh1b, ss1, sd1, gat1_b, h3b, N);

  // --- GAT2+GAT3: prestaged BK=64, nt=3 (scores folded) ---
  gemm_pre<64,3,true,false,true,false><<<MB, 256, 0, stream>>>(
      h3b, 192, t_gat23, 192, hh23b, 64, N, 64, 1,
      nullptr,nullptr, s2s,s2d,s3s,s3d, gat2_as,gat2_ad,gat3_as,gat3_ad);
  gat23_gather<<<cdiv(N,4), 256, 0, stream>>>(offs, csr, hh23b, s2s, s2d, s3s, s3d, gat2_b, gat3_b, zs, mus, lvs, zbf, N);

  // --- dec1 + clu1 combined (K=32, single-step already) ---
  gemm_g<128,true,true,false,false,false><<<MB*2, 256, 0, stream>>>(
      zbf, 32, t_dc1, 32, dc1pre, 256, nullptr, N, 256, 32, 2,
      st_dc1, st_dc1+256, nullptr,nullptr,nullptr,nullptr, nullptr,nullptr,nullptr,nullptr);
  bn_elu_split<<<2048, 256, 0, stream>>>(dc1pre, d1b, c1b, N, invN, st_dc1, st_dc1+256, dec_g1, dec_bt1, clu_g1, clu_bt1);

  // --- dec2: prestaged BK=64, nt=2 ---
  gemm_pre<128,2,true,true,false,false><<<MB*2, 256, 0, stream>>>(
      d1b, 128, t_dec2, 128, d2pre, 256, N, 256, 2,
      st_dec2, st_dec2+256, nullptr,nullptr,nullptr,nullptr, nullptr,nullptr,nullptr,nullptr);
  bn_elu_apply2<256><<<2048, 256, 0, stream>>>(d2pre, d2b, N, invN, st_dec2, st_dec2+256, dec_g2, dec_bt2);

  // --- dec3 + clu2(softmax) in one dispatch ---
  gemm_dual<<<MB*8 + MB, 256, 0, stream>>>(
      d2b, 256, t_dec3, 256, xrec, 1000, dec_b3, 1000, 256,
      c1b, 128, t_clu2, 128, pred, clu_b2, 10, 128,
      N, MB*8);
}